// Round 4
// baseline (6723.549 us; speedup 1.0000x reference)
//
#include <hip/hip_runtime.h>

#define NN 128000
#define EE 1024000
#define HH 128
#define GG 512
#define SMAX 1000
#define NCHUNK 500   // 500 * 256 = 128000

typedef unsigned int u32;
typedef unsigned short u16;

// ---------------- workspace layout (floats, then ints) ----------------
// ws budget measured round 3: 256 MiB. This layout: 213.3 MiB.
// All segment offsets are multiples of 4 float-units (16B) for vector loads.
constexpr size_t NH     = (size_t)NN*HH;              // 16,384,000
constexpr size_t F_H    = 0;                          // h (persist, f32)
constexpr size_t F_A    = NH;                         // work A: q / v
constexpr size_t F_B    = 2*NH;                       // work B: k / skip+agg
// overlays on A/B after convs are done:
//   gi bf16   : N*384 u16 = 24,576,000 float-units at F_A
//   node_out  : N*128 u16 =  8,192,000 float-units at F_NODE (tail of B)
constexpr size_t F_NODE = F_A + (size_t)NN*192;       // 40,960,000
constexpr size_t F_ELOG = 3*NH;                       // E edge logits
constexpr size_t F_RMAX = F_ELOG + EE;                // N per-dst max
constexpr size_t F_CN   = F_RMAX + NN;                // 4*128 normalized centers
constexpr size_t F_CW   = F_CN   + 512;               // 128*384 projW@Wih^T
constexpr size_t F_PEW  = F_CW   + 128*384;           // 1000*384 (pe+projb)@Wih^T + bih
constexpr size_t F_PEB  = F_PEW  + 1000*384;          // 1000*128 pe + projb
constexpr size_t F_END  = F_PEB  + 1000*128;          // 50,865,664

constexpr size_t I_ROWP = 0;                          // N+8 CSR row ptr
constexpr size_t I_CUR  = I_ROWP + NN + 8;
constexpr size_t I_COL  = I_CUR  + NN;                // E
constexpr size_t I_GRP  = I_COL  + EE;
constexpr size_t I_INV  = I_GRP  + NN;
constexpr size_t I_POS  = I_INV  + NN;
constexpr size_t I_GN   = I_POS  + NN;                // 512*1000
constexpr size_t I_CNT  = I_GN   + (size_t)GG*SMAX;
constexpr size_t I_CH   = I_CNT  + GG;                // 500*512
constexpr size_t I_BS   = I_CH   + (size_t)NCHUNK*GG;
constexpr size_t I_WT   = I_BS   + 512;               // 64*384 packed bf16 Whh^T
constexpr size_t I_END  = I_WT   + 64*384;            // 2,457,608

constexpr size_t WS_NEEDED = F_END*4 + I_END*4;       // 213,293,088 B

__device__ inline float wredf(float v){
  #pragma unroll
  for (int o = 32; o; o >>= 1) v += __shfl_xor(v, o);
  return v;
}
__device__ inline u32 bf16rne(float f){
  u32 u = __float_as_uint(f);
  return (u + 0x7fffu + ((u >> 16) & 1u)) >> 16;
}
__device__ inline float bf2f(u16 u){
  return __uint_as_float(((u32)u) << 16);
}

// ---------------- ws-size diagnostic sentinel ----------------
__global__ void k_sentinel(float* __restrict__ out, int n, float val){
  int i = blockIdx.x * 256 + threadIdx.x;
  if (i < n) out[i] = val;
}

// ---------------- CSR build ----------------
__global__ void k_zero(int* __restrict__ p){
  p[blockIdx.x * 256 + threadIdx.x] = 0;
}
__global__ void k_hist(const int* __restrict__ dst, int* __restrict__ deg){
  int e = blockIdx.x * 256 + threadIdx.x;
  atomicAdd(&deg[dst[e]], 1);
}
__global__ void k_s1(const int* __restrict__ deg, int* __restrict__ bsum){
  __shared__ int red[256];
  int t = threadIdx.x;
  red[t] = deg[blockIdx.x * 256 + t];
  __syncthreads();
  for (int s = 128; s; s >>= 1){ if (t < s) red[t] += red[t + s]; __syncthreads(); }
  if (!t) bsum[blockIdx.x] = red[0];
}
__global__ void k_s2(int* __restrict__ bsum){
  __shared__ int arr[512];
  int t = threadIdx.x;
  int v0 = (t < NCHUNK) ? bsum[t] : 0;
  arr[t] = v0; __syncthreads();
  for (int off = 1; off < 512; off <<= 1){
    int v = (t >= off) ? arr[t - off] : 0;
    __syncthreads();
    arr[t] += v;
    __syncthreads();
  }
  if (t < NCHUNK) bsum[t] = arr[t] - v0;   // exclusive
}
__global__ void k_s3(const int* __restrict__ bsum, int* __restrict__ row_ptr,
                     int* __restrict__ cursor){
  __shared__ int arr[256];
  int t = threadIdx.x;
  int i = blockIdx.x * 256 + t;
  int v0 = cursor[i];                      // cursor currently holds deg
  arr[t] = v0; __syncthreads();
  for (int off = 1; off < 256; off <<= 1){
    int v = (t >= off) ? arr[t - off] : 0;
    __syncthreads();
    arr[t] += v;
    __syncthreads();
  }
  int exc = arr[t] - v0 + bsum[blockIdx.x];
  row_ptr[i] = exc;
  cursor[i]  = exc;
  if (i == 0) row_ptr[NN] = EE;
}
__global__ void k_scatter(const int* __restrict__ src, const int* __restrict__ dst,
                          int* __restrict__ cursor, int* __restrict__ col){
  int e = blockIdx.x * 256 + threadIdx.x;
  int idx = atomicAdd(&cursor[dst[e]], 1);
  col[idx] = src[e];
}

// ---------------- centers: normalize + distance ----------------
__global__ void k_setup(const float* __restrict__ centers, float* __restrict__ cn,
                        float* __restrict__ dist_out){
  __shared__ float red[128];
  int t = threadIdx.x;
  for (int l = 0; l < 4; ++l){
    float v = centers[l*128 + t];
    red[t] = v * v; __syncthreads();
    for (int s = 64; s; s >>= 1){ if (t < s) red[t] += red[t + s]; __syncthreads(); }
    float nrm = sqrtf(red[0]);
    __syncthreads();
    cn[l*128 + t] = v / fmaxf(nrm, 1e-8f);
  }
  const int iu0[6] = {0,0,0,1,1,2}, iu1[6] = {1,2,3,2,3,3};
  __shared__ float dv[6];
  for (int p = 0; p < 6; ++p){
    float d = centers[iu0[p]*128 + t] - centers[iu1[p]*128 + t];
    red[t] = d * d; __syncthreads();
    for (int s = 64; s; s >>= 1){ if (t < s) red[t] += red[t + s]; __syncthreads(); }
    if (!t) dv[p] = sqrtf(red[0]);
    __syncthreads();
  }
  if (!t){
    float mean = 0.f;
    for (int p = 0; p < 6; ++p) mean += dv[p];
    mean /= 6.f;
    float var = 0.f;
    for (int p = 0; p < 6; ++p){ float d = dv[p] - mean; var += d * d; }
    var /= 5.f;                              // ddof=1
    dist_out[0] = -var;
  }
}

// ---------------- pos-enc tables ----------------
__global__ void k_pe(const float* __restrict__ projb, float* __restrict__ peb){
  int p = blockIdx.x, t = threadIdx.x;     // 1000 x 128
  float ex  = (float)(t >> 1) * (-2.0f * 9.210340371976184f / 128.0f);
  float ang = (float)p * expf(ex);
  float v = (t & 1) ? cosf(ang) : sinf(ang);
  peb[p*128 + t] = v + projb[t];
}
__global__ void k_pew(const float* __restrict__ peb, const float* __restrict__ Wih,
                      const float* __restrict__ bih, float* __restrict__ pew){
  int p = blockIdx.x;                       // 1000
  int j = blockIdx.y * 128 + threadIdx.x;   // 384
  const float* pb = peb + p*128;
  const float* wr = Wih + (size_t)j*128;
  float acc = bih[j];
  #pragma unroll 4
  for (int m = 0; m < 128; ++m) acc += pb[m] * wr[m];
  pew[(size_t)p*384 + j] = acc;
}
__global__ void k_combw(const float* __restrict__ projW, const float* __restrict__ Wih,
                        float* __restrict__ cw){
  int kk = blockIdx.x;                      // 128
  int j  = blockIdx.y * 128 + threadIdx.x;  // 384
  const float* pr = projW + (size_t)kk*128;
  const float* wr = Wih + (size_t)j*128;
  float acc = 0.f;
  #pragma unroll 4
  for (int m = 0; m < 128; ++m) acc += pr[m] * wr[m];
  cw[(size_t)kk*384 + j] = acc;
}
__global__ void k_packwhh(const float* __restrict__ Whh, u32* __restrict__ wt){
  int kp = blockIdx.x;                      // 64
  int j  = blockIdx.y * 128 + threadIdx.x;  // 384
  float a = Whh[(size_t)j*128 + 2*kp];
  float b = Whh[(size_t)j*128 + 2*kp + 1];
  wt[(size_t)kp*384 + j] = (bf16rne(b) << 16) | bf16rne(a);
}

// ---------------- tiled f32 GEMM: 32-row tiles, K staged in 2 halves ----------------
// LDS = 32KB (Wl) + 16.9KB (Xl) = 48.9KB. Optional bf16 output (outb != null).
__global__ __launch_bounds__(256) void k_gemm(
    const float* __restrict__ X, const float* __restrict__ W, int ldw,
    const float* __restrict__ bias, const float* __restrict__ pew,
    const int* __restrict__ pos, float* __restrict__ out,
    u16* __restrict__ outb, int ldo){
  __shared__ __align__(16) float Wl[64*128];
  __shared__ __align__(16) float Xl[32*132];
  int tid = threadIdx.x;
  int rb = blockIdx.x * 32;
  int cb = blockIdx.y * 128;
  for (int idx = tid; idx < 32*32; idx += 256){
    int r = idx >> 5, c4 = idx & 31;
    *(float4*)&Xl[r*132 + c4*4] = *(const float4*)&X[(size_t)(rb + r)*128 + c4*4];
  }
  int rg = tid >> 4, cg = tid & 15;
  float acc[2][8];
  #pragma unroll
  for (int a = 0; a < 2; ++a)
    #pragma unroll
    for (int b = 0; b < 8; ++b) acc[a][b] = 0.f;
  for (int half = 0; half < 2; ++half){
    __syncthreads();   // Xl staged (half 0) / previous compute done (half 1)
    for (int idx = tid; idx < 64*32; idx += 256){
      int kk = idx >> 5, c4 = idx & 31;
      *(float4*)&Wl[kk*128 + c4*4] =
          *(const float4*)&W[(size_t)(half*64 + kk)*ldw + cb + c4*4];
    }
    __syncthreads();
    #pragma unroll 4
    for (int kk = 0; kk < 64; ++kk){
      float4 wa = *(const float4*)&Wl[kk*128 + cg*8];
      float4 wb = *(const float4*)&Wl[kk*128 + cg*8 + 4];
      #pragma unroll
      for (int rr = 0; rr < 2; ++rr){
        float xv = Xl[(rg*2 + rr)*132 + half*64 + kk];
        acc[rr][0] += xv * wa.x; acc[rr][1] += xv * wa.y;
        acc[rr][2] += xv * wa.z; acc[rr][3] += xv * wa.w;
        acc[rr][4] += xv * wb.x; acc[rr][5] += xv * wb.y;
        acc[rr][6] += xv * wb.z; acc[rr][7] += xv * wb.w;
      }
    }
  }
  #pragma unroll
  for (int rr = 0; rr < 2; ++rr){
    int r = rb + rg*2 + rr;
    float bv[8];
    if (pos){
      const float* pw = pew + (size_t)pos[r]*384 + cb + cg*8;
      #pragma unroll
      for (int j = 0; j < 8; ++j) bv[j] = pw[j];
    } else {
      #pragma unroll
      for (int j = 0; j < 8; ++j) bv[j] = bias[cb + cg*8 + j];
    }
    if (outb){
      u16* op = outb + (size_t)r*ldo + cb + cg*8;
      #pragma unroll
      for (int j = 0; j < 8; ++j) op[j] = (u16)bf16rne(acc[rr][j] + bv[j]);
    } else {
      float* op = out + (size_t)r*ldo + cb + cg*8;
      #pragma unroll
      for (int j = 0; j < 8; ++j) op[j] = acc[rr][j] + bv[j];
    }
  }
}

// ---------------- edge phase 1: logits + per-dst max (one wave per dst) ----------------
__global__ __launch_bounds__(64) void k_logits(
    const float* __restrict__ q, const float* __restrict__ k,
    const int* __restrict__ row_ptr, const int* __restrict__ col,
    float* __restrict__ elog, float* __restrict__ rmax){
  int d = blockIdx.x;
  int lane = threadIdx.x;
  int e0 = row_ptr[d], e1 = row_ptr[d+1];
  if (e0 == e1) return;
  float q0 = q[(size_t)d*128 + 2*lane], q1 = q[(size_t)d*128 + 2*lane + 1];
  float m = -INFINITY;
  for (int e = e0; e < e1; ++e){
    int s = col[e];
    float p = q0 * k[(size_t)s*128 + 2*lane] + q1 * k[(size_t)s*128 + 2*lane + 1];
    p = wredf(p) * 0.08838834764831845f;   // 1/sqrt(128)
    if (lane == 0) elog[e] = p;
    m = fmaxf(m, p);
  }
  if (lane == 0) rmax[d] = m;
}

// ---------------- edge phase 2: softmax-weighted aggregation ----------------
__global__ __launch_bounds__(64) void k_agg(
    const float* __restrict__ v, const int* __restrict__ row_ptr,
    const int* __restrict__ col, const float* __restrict__ elog,
    const float* __restrict__ rmax, float* __restrict__ h2){
  int d = blockIdx.x;
  int lane = threadIdx.x;
  int e0 = row_ptr[d], e1 = row_ptr[d+1];
  if (e0 == e1) return;                    // h2 keeps skip value
  float m = rmax[d];
  float ssum = 0.f, a0 = 0.f, a1 = 0.f;
  for (int e = e0; e < e1; ++e){
    int s = col[e];
    float el = expf(elog[e] - m);
    ssum += el;
    a0 += el * v[(size_t)s*128 + 2*lane];
    a1 += el * v[(size_t)s*128 + 2*lane + 1];
  }
  float inv = 1.f / ssum;
  h2[(size_t)d*128 + 2*lane]     += a0 * inv;
  h2[(size_t)d*128 + 2*lane + 1] += a1 * inv;
}

// ---------------- relu(layernorm) per row ----------------
__global__ __launch_bounds__(256) void k_lnrelu(
    const float* __restrict__ in, const float* __restrict__ g,
    const float* __restrict__ b, float* __restrict__ outp){
  int node = blockIdx.x * 4 + (threadIdx.x >> 6);
  int lane = threadIdx.x & 63;
  float x0 = in[(size_t)node*128 + 2*lane], x1 = in[(size_t)node*128 + 2*lane + 1];
  float s = wredf(x0 + x1);
  float qq = wredf(x0*x0 + x1*x1);
  float mu = s * 0.0078125f;
  float var = qq * 0.0078125f - mu*mu;
  float rstd = rsqrtf(var + 1e-5f);
  float y0 = (x0 - mu)*rstd*g[2*lane]   + b[2*lane];
  float y1 = (x1 - mu)*rstd*g[2*lane+1] + b[2*lane+1];
  outp[(size_t)node*128 + 2*lane]     = fmaxf(y0, 0.f);
  outp[(size_t)node*128 + 2*lane + 1] = fmaxf(y1, 0.f);
}

// ---------------- cluster assignment ----------------
__global__ __launch_bounds__(256) void k_classify(
    const float* __restrict__ h, const float* __restrict__ cn,
    const int* __restrict__ batch, const int* __restrict__ callsq,
    int* __restrict__ grp, int* __restrict__ inv){
  int node = blockIdx.x * 4 + (threadIdx.x >> 6);
  int lane = threadIdx.x & 63;
  float h0 = h[(size_t)node*128 + 2*lane], h1 = h[(size_t)node*128 + 2*lane + 1];
  float p0 = h0*cn[      2*lane] + h1*cn[      2*lane+1];
  float p1 = h0*cn[128 + 2*lane] + h1*cn[128 + 2*lane+1];
  float p2 = h0*cn[256 + 2*lane] + h1*cn[256 + 2*lane+1];
  float p3 = h0*cn[384 + 2*lane] + h1*cn[384 + 2*lane+1];
  p0 = wredf(p0); p1 = wredf(p1); p2 = wredf(p2); p3 = wredf(p3);
  if (lane == 0){
    float best = p0; int bi = 0;
    if (p1 > best){ best = p1; bi = 1; }
    if (p2 > best){ best = p2; bi = 2; }
    if (p3 > best){ best = p3; bi = 3; }
    grp[node] = batch[node]*4 + bi;
    inv[callsq[node]] = node;
  }
}

// ---------------- grouping: chunked multisplit ----------------
__global__ __launch_bounds__(256) void k_g1(const int* __restrict__ inv,
                                            const int* __restrict__ grp,
                                            int* __restrict__ ch){
  __shared__ int hist[GG];
  int c = blockIdx.x, t = threadIdx.x;
  hist[t] = 0; hist[t + 256] = 0;
  __syncthreads();
  int g = grp[inv[c*256 + t]];
  atomicAdd(&hist[g], 1);
  __syncthreads();
  ch[c*GG + t] = hist[t];
  ch[c*GG + 256 + t] = hist[256 + t];
}
__global__ void k_g2(int* __restrict__ ch, int* __restrict__ cnt){
  int g = threadIdx.x;   // 512
  int run = 0;
  for (int c = 0; c < NCHUNK; ++c){
    int idx = c*GG + g;
    int t = ch[idx];
    ch[idx] = run;
    run += t;
  }
  cnt[g] = run;
}
__global__ __launch_bounds__(256) void k_g3(
    const int* __restrict__ inv, const int* __restrict__ grp,
    const int* __restrict__ ch, int* __restrict__ pos, int* __restrict__ gn){
  __shared__ int hist[GG];
  int c = blockIdx.x, t = threadIdx.x;
  hist[t] = 0; hist[t + 256] = 0;
  __syncthreads();
  int node = inv[c*256 + t];
  int g = grp[node];
  int lane = t & 63, w = t >> 6;
  int before = 0, total = 0;
  for (int j = 0; j < 64; ++j){
    int gj = __shfl(g, j);
    if (gj == g){ total++; if (j < lane) before++; }
  }
  int base = 0;
  for (int wv = 0; wv < 4; ++wv){
    if (w == wv){
      base = hist[g];
      if (before == total - 1) hist[g] = base + total;  // last lane of its g
    }
    __syncthreads();
  }
  int p = ch[c*GG + g] + base + before;
  pos[node] = p;
  gn[(size_t)g*SMAX + p] = node;
}

// ---------------- GRU: 2 groups per block, Whh^T bf16 in LDS, gi bf16 ----------------
__global__ __launch_bounds__(256) void k_gru(
    const u16* __restrict__ gi, const u32* __restrict__ wt,
    const float* __restrict__ bhh, const float* __restrict__ sg,
    const float* __restrict__ sb, const int* __restrict__ gn,
    const int* __restrict__ cnt, u16* __restrict__ node_out){
  __shared__ __align__(16) u32 Wl[64*384];   // 96 KB
  __shared__ __align__(16) float hbuf[2][128];
  __shared__ float redS[4], redQ[4];
  int tid = threadIdx.x;
  int sub = tid >> 7, t = tid & 127;
  int wv = t >> 6, lane = t & 63;
  int g = blockIdx.x * 2 + sub;
  int c0 = cnt[blockIdx.x*2], c1 = cnt[blockIdx.x*2 + 1];
  c0 = (c0 <= 1) ? 0 : c0;
  c1 = (c1 <= 1) ? 0 : c1;
  int nsteps = max(c0, c1);
  if (nsteps == 0) return;
  int my = sub ? c1 : c0;
  for (int idx = tid; idx < 6144; idx += 256)
    ((uint4*)Wl)[idx] = ((const uint4*)wt)[idx];
  hbuf[sub][t] = 0.f;
  __syncthreads();
  float br = bhh[t], bz = bhh[128 + t], bn = bhh[256 + t];
  float gmul = sg[t], gadd = sb[t];
  const int* gnr = gn + (size_t)g*SMAX;
  for (int p = 0; p < nsteps; ++p){
    int node = (my > 0) ? gnr[min(p, my - 1)] : 0;
    const u16* gir = gi + (size_t)node*384;
    float xr = bf2f(gir[t]), xz = bf2f(gir[128 + t]), xn = bf2f(gir[256 + t]);
    float ar = br, az = bz, an = bn;
    #pragma unroll 8
    for (int kp = 0; kp < 64; ++kp){
      float2 hv = *(const float2*)&hbuf[sub][kp*2];
      u32 wr = Wl[kp*384 + t];
      u32 wz = Wl[kp*384 + 128 + t];
      u32 wn = Wl[kp*384 + 256 + t];
      ar += hv.x * __uint_as_float(wr << 16) + hv.y * __uint_as_float(wr & 0xffff0000u);
      az += hv.x * __uint_as_float(wz << 16) + hv.y * __uint_as_float(wz & 0xffff0000u);
      an += hv.x * __uint_as_float(wn << 16) + hv.y * __uint_as_float(wn & 0xffff0000u);
    }
    float hold = hbuf[sub][t];
    float r = 1.f / (1.f + expf(-(xr + ar)));
    float z = 1.f / (1.f + expf(-(xz + az)));
    float n = tanhf(xn + r * an);
    float hnew = (1.f - z) * n + z * hold;
    __syncthreads();                        // B1: all hbuf reads done
    hbuf[sub][t] = hnew;
    float s = hnew, qq = hnew * hnew;
    #pragma unroll
    for (int o = 32; o; o >>= 1){ s += __shfl_xor(s, o); qq += __shfl_xor(qq, o); }
    if (lane == 0){ redS[sub*2 + wv] = s; redQ[sub*2 + wv] = qq; }
    __syncthreads();                        // B2: hbuf + reductions visible
    if (p < my){
      float mu  = (redS[sub*2] + redS[sub*2 + 1]) * 0.0078125f;
      float var = (redQ[sub*2] + redQ[sub*2 + 1]) * 0.0078125f - mu*mu;
      float rstd = rsqrtf(var + 1e-5f);
      float o = (hnew - mu) * rstd * gmul + gadd;
      node_out[(size_t)node*128 + t] = (u16)bf16rne(fmaxf(o, 0.f));
    }
  }
}

// ---------------- head: gelu(lin1) -> sigmoid(lin2) ----------------
__global__ __launch_bounds__(256) void k_head(
    const float* __restrict__ h, const u16* __restrict__ node_out,
    const int* __restrict__ grp, const int* __restrict__ cnt,
    const float* __restrict__ l1W, const float* __restrict__ l1b,
    const float* __restrict__ l2W, const float* __restrict__ l2b,
    float* __restrict__ out){
  int node = blockIdx.x * 4 + (threadIdx.x >> 6);
  int lane = threadIdx.x & 63;
  bool single = (cnt[grp[node]] == 1);
  float x0, x1;
  if (single){
    x0 = h[(size_t)node*128 + 2*lane];
    x1 = h[(size_t)node*128 + 2*lane + 1];
  } else {
    x0 = bf2f(node_out[(size_t)node*128 + 2*lane]);
    x1 = bf2f(node_out[(size_t)node*128 + 2*lane + 1]);
  }
  float acc[8];
  #pragma unroll
  for (int j = 0; j < 8; ++j)
    acc[j] = x0 * l1W[(2*lane)*8 + j] + x1 * l1W[(2*lane + 1)*8 + j];
  #pragma unroll
  for (int o = 32; o; o >>= 1)
    #pragma unroll
    for (int j = 0; j < 8; ++j) acc[j] += __shfl_xor(acc[j], o);
  if (lane == 0){
    float zz = l2b[0];
    #pragma unroll
    for (int j = 0; j < 8; ++j){
      float xx = acc[j] + l1b[j];
      float ge = 0.5f * xx * (1.f + erff(xx * 0.7071067811865476f));
      zz += ge * l2W[j];
    }
    out[node] = 1.f / (1.f + expf(-zz));
  }
}

extern "C" void kernel_launch(void* const* d_in, const int* in_sizes, int n_in,
                              void* d_out, int out_size, void* d_ws, size_t ws_size,
                              hipStream_t stream){
  float* out = (float*)d_out;

  // ---- ws-size guard: encode ws MB into output instead of faulting ----
  if (ws_size < WS_NEEDED){
    float code = -(float)(ws_size >> 20);
    k_sentinel<<<(out_size + 255)/256, 256, 0, stream>>>(out, out_size, code);
    return;
  }

  const float* x       = (const float*)d_in[0];
  const int*   tei     = (const int*)d_in[1];
  const int*   callsq  = (const int*)d_in[2];
  const int*   batch   = (const int*)d_in[3];
  const float* Wq      = (const float*)d_in[4];
  const float* bq      = (const float*)d_in[5];
  const float* Wk      = (const float*)d_in[6];
  const float* bk      = (const float*)d_in[7];
  const float* Wv      = (const float*)d_in[8];
  const float* bv      = (const float*)d_in[9];
  const float* Wsk     = (const float*)d_in[10];
  const float* bsk     = (const float*)d_in[11];
  const float* lng     = (const float*)d_in[12];
  const float* lnb     = (const float*)d_in[13];
  const float* centers = (const float*)d_in[14];
  const float* projW   = (const float*)d_in[15];
  const float* projb   = (const float*)d_in[16];
  const float* Wih     = (const float*)d_in[17];
  const float* Whh     = (const float*)d_in[18];
  const float* bih     = (const float*)d_in[19];
  const float* bhh     = (const float*)d_in[20];
  const float* sqg     = (const float*)d_in[21];
  const float* sqb     = (const float*)d_in[22];
  const float* l1W     = (const float*)d_in[23];
  const float* l1b     = (const float*)d_in[24];
  const float* l2W     = (const float*)d_in[25];
  const float* l2b     = (const float*)d_in[26];

  float* wf = (float*)d_ws;
  float* f_h    = wf + F_H;
  float* f_a    = wf + F_A;
  float* f_b    = wf + F_B;
  float* f_elog = wf + F_ELOG;
  float* f_rmax = wf + F_RMAX;
  float* f_cn   = wf + F_CN;
  float* f_cw   = wf + F_CW;
  float* f_pew  = wf + F_PEW;
  float* f_peb  = wf + F_PEB;
  u16*   gi_bf  = (u16*)(wf + F_A);      // N x 384 bf16 (overlay, post-conv)
  u16*   no_bf  = (u16*)(wf + F_NODE);   // N x 128 bf16 node_out (overlay)
  int* wi = (int*)(wf + F_END);
  int* i_rowp = wi + I_ROWP;
  int* i_cur  = wi + I_CUR;
  int* i_col  = wi + I_COL;
  int* i_grp  = wi + I_GRP;
  int* i_inv  = wi + I_INV;
  int* i_pos  = wi + I_POS;
  int* i_gn   = wi + I_GN;
  int* i_cnt  = wi + I_CNT;
  int* i_ch   = wi + I_CH;
  int* i_bs   = wi + I_BS;
  u32* i_wt   = (u32*)(wi + I_WT);

  const int* esrc = tei;
  const int* edst = tei + EE;

  // CSR build
  k_zero<<<NN/256, 256, 0, stream>>>(i_cur);
  k_hist<<<EE/256, 256, 0, stream>>>(edst, i_cur);
  k_s1<<<NCHUNK, 256, 0, stream>>>(i_cur, i_bs);
  k_s2<<<1, 512, 0, stream>>>(i_bs);
  k_s3<<<NCHUNK, 256, 0, stream>>>(i_bs, i_rowp, i_cur);
  k_scatter<<<EE/256, 256, 0, stream>>>(esrc, edst, i_cur, i_col);

  // centers, PE tables, combined weights, packed Whh^T
  k_setup<<<1, 128, 0, stream>>>(centers, f_cn, out + NN);
  k_pe<<<1000, 128, 0, stream>>>(projb, f_peb);
  k_pew<<<dim3(1000, 3), 128, 0, stream>>>(f_peb, Wih, bih, f_pew);
  k_combw<<<dim3(128, 3), 128, 0, stream>>>(projW, Wih, f_cw);
  k_packwhh<<<dim3(64, 3), 128, 0, stream>>>(Whh, i_wt);

  // 3x TransformerConv + relu(LN); A/B ping-pong keeps peak mem at 2 buffers
  for (int i = 0; i < 3; ++i){
    const float* xin = i ? f_h : x;
    size_t wo = (size_t)i * 128 * 128, bo = (size_t)i * 128;
    k_gemm<<<dim3(NN/32, 1), 256, 0, stream>>>(xin, Wq + wo, 128, bq + bo, nullptr, nullptr, f_a, nullptr, 128);
    k_gemm<<<dim3(NN/32, 1), 256, 0, stream>>>(xin, Wk + wo, 128, bk + bo, nullptr, nullptr, f_b, nullptr, 128);
    k_logits<<<NN, 64, 0, stream>>>(f_a, f_b, i_rowp, i_col, f_elog, f_rmax);
    k_gemm<<<dim3(NN/32, 1), 256, 0, stream>>>(xin, Wv + wo, 128, bv + bo, nullptr, nullptr, f_a, nullptr, 128);
    k_gemm<<<dim3(NN/32, 1), 256, 0, stream>>>(xin, Wsk + wo, 128, bsk + bo, nullptr, nullptr, f_b, nullptr, 128);
    k_agg<<<NN, 64, 0, stream>>>(f_a, i_rowp, i_col, f_elog, f_rmax, f_b);
    k_lnrelu<<<NN/4, 256, 0, stream>>>(f_b, lng + bo, lnb + bo, f_h);
  }

  // cluster assignment + grouping
  k_classify<<<NN/4, 256, 0, stream>>>(f_h, f_cn, batch, callsq, i_grp, i_inv);
  k_g1<<<NCHUNK, 256, 0, stream>>>(i_inv, i_grp, i_ch);
  k_g2<<<1, 512, 0, stream>>>(i_ch, i_cnt);
  k_g3<<<NCHUNK, 256, 0, stream>>>(i_inv, i_grp, i_ch, i_pos, i_gn);

  // gi = h @ (projW@Wih^T) + PEW[pos]  -> bf16 overlay on A (+ part of B)
  k_gemm<<<dim3(NN/32, 3), 256, 0, stream>>>(f_h, f_cw, 384, nullptr, f_pew, i_pos, nullptr, gi_bf, 384);

  // GRU + LN + ReLU -> node_out (bf16, tail of B)
  k_gru<<<GG/2, 256, 0, stream>>>(gi_bf, i_wt, bhh, sqg, sqb, i_gn, i_cnt, no_bf);

  // head
  k_head<<<NN/4, 256, 0, stream>>>(f_h, no_bf, i_grp, i_cnt, l1W, l1b, l2W, l2b, out);
}

// Round 5
// 5743.022 us; speedup vs baseline: 1.1707x; 1.1707x over previous
//
#include <hip/hip_runtime.h>

#define NN 128000
#define EE 1024000
#define HH 128
#define GG 512
#define SMAX 1000
#define NCHUNK 500   // 500 * 256 = 128000

typedef unsigned int u32;
typedef unsigned short u16;

// ---------------- workspace layout (floats, then ints) ----------------
// ws budget measured round 3: 256 MiB. This layout: 213.3 MiB.
constexpr size_t NH     = (size_t)NN*HH;              // 16,384,000
constexpr size_t F_H    = 0;                          // h (persist, f32)
constexpr size_t F_A    = NH;                         // work A: q / v
constexpr size_t F_B    = 2*NH;                       // work B: k / skip+agg
constexpr size_t F_NODE = F_A + (size_t)NN*192;       // bf16 node_out overlay
constexpr size_t F_ELOG = 3*NH;                       // E edge logits
constexpr size_t F_RMAX = F_ELOG + EE;                // N per-dst max
constexpr size_t F_CN   = F_RMAX + NN;                // 4*128 normalized centers
constexpr size_t F_CW   = F_CN   + 512;               // 128*384 projW@Wih^T
constexpr size_t F_PEW  = F_CW   + 128*384;           // 1000*384 (pe+projb)@Wih^T + bih
constexpr size_t F_PEB  = F_PEW  + 1000*384;          // 1000*128 pe + projb
constexpr size_t F_END  = F_PEB  + 1000*128;

constexpr size_t I_ROWP = 0;                          // N+8 CSR row ptr
constexpr size_t I_CUR  = I_ROWP + NN + 8;
constexpr size_t I_COL  = I_CUR  + NN;                // E
constexpr size_t I_GRP  = I_COL  + EE;
constexpr size_t I_INV  = I_GRP  + NN;
constexpr size_t I_POS  = I_INV  + NN;
constexpr size_t I_GN   = I_POS  + NN;                // 512*1000
constexpr size_t I_CNT  = I_GN   + (size_t)GG*SMAX;
constexpr size_t I_CH   = I_CNT  + GG;                // 500*512
constexpr size_t I_BS   = I_CH   + (size_t)NCHUNK*GG;
constexpr size_t I_WT   = I_BS   + 512;               // 64*384 packed f16 Whh^T rows
constexpr size_t I_END  = I_WT   + 64*384;

constexpr size_t WS_NEEDED = F_END*4 + I_END*4;       // 213,293,088 B

__device__ inline float wredf(float v){
  #pragma unroll
  for (int o = 32; o; o >>= 1) v += __shfl_xor(v, o);
  return v;
}
__device__ inline u32 bf16rne(float f){
  u32 u = __float_as_uint(f);
  return (u + 0x7fffu + ((u >> 16) & 1u)) >> 16;
}
__device__ inline float bf2f(u16 u){
  return __uint_as_float(((u32)u) << 16);
}

typedef _Float16 h2_t __attribute__((ext_vector_type(2)));
__device__ inline float dot2f(u32 w, u32 h, float acc){
#if __has_builtin(__builtin_amdgcn_fdot2)
  return __builtin_amdgcn_fdot2(__builtin_bit_cast(h2_t, w),
                                __builtin_bit_cast(h2_t, h), acc, false);
#else
  float r;
  asm("v_dot2_f32_f16 %0, %1, %2, %3" : "=v"(r) : "v"(w), "v"(h), "v"(acc));
  return r;
#endif
}

// ---------------- ws-size diagnostic sentinel ----------------
__global__ void k_sentinel(float* __restrict__ out, int n, float val){
  int i = blockIdx.x * 256 + threadIdx.x;
  if (i < n) out[i] = val;
}

// ---------------- CSR build ----------------
__global__ void k_zero(int* __restrict__ p){
  p[blockIdx.x * 256 + threadIdx.x] = 0;
}
__global__ void k_hist(const int* __restrict__ dst, int* __restrict__ deg){
  int e = blockIdx.x * 256 + threadIdx.x;
  atomicAdd(&deg[dst[e]], 1);
}
__global__ void k_s1(const int* __restrict__ deg, int* __restrict__ bsum){
  __shared__ int red[256];
  int t = threadIdx.x;
  red[t] = deg[blockIdx.x * 256 + t];
  __syncthreads();
  for (int s = 128; s; s >>= 1){ if (t < s) red[t] += red[t + s]; __syncthreads(); }
  if (!t) bsum[blockIdx.x] = red[0];
}
__global__ void k_s2(int* __restrict__ bsum){
  __shared__ int arr[512];
  int t = threadIdx.x;
  int v0 = (t < NCHUNK) ? bsum[t] : 0;
  arr[t] = v0; __syncthreads();
  for (int off = 1; off < 512; off <<= 1){
    int v = (t >= off) ? arr[t - off] : 0;
    __syncthreads();
    arr[t] += v;
    __syncthreads();
  }
  if (t < NCHUNK) bsum[t] = arr[t] - v0;   // exclusive
}
__global__ void k_s3(const int* __restrict__ bsum, int* __restrict__ row_ptr,
                     int* __restrict__ cursor){
  __shared__ int arr[256];
  int t = threadIdx.x;
  int i = blockIdx.x * 256 + t;
  int v0 = cursor[i];                      // cursor currently holds deg
  arr[t] = v0; __syncthreads();
  for (int off = 1; off < 256; off <<= 1){
    int v = (t >= off) ? arr[t - off] : 0;
    __syncthreads();
    arr[t] += v;
    __syncthreads();
  }
  int exc = arr[t] - v0 + bsum[blockIdx.x];
  row_ptr[i] = exc;
  cursor[i]  = exc;
  if (i == 0) row_ptr[NN] = EE;
}
__global__ void k_scatter(const int* __restrict__ src, const int* __restrict__ dst,
                          int* __restrict__ cursor, int* __restrict__ col){
  int e = blockIdx.x * 256 + threadIdx.x;
  int idx = atomicAdd(&cursor[dst[e]], 1);
  col[idx] = src[e];
}

// ---------------- centers: normalize + distance ----------------
__global__ void k_setup(const float* __restrict__ centers, float* __restrict__ cn,
                        float* __restrict__ dist_out){
  __shared__ float red[128];
  int t = threadIdx.x;
  for (int l = 0; l < 4; ++l){
    float v = centers[l*128 + t];
    red[t] = v * v; __syncthreads();
    for (int s = 64; s; s >>= 1){ if (t < s) red[t] += red[t + s]; __syncthreads(); }
    float nrm = sqrtf(red[0]);
    __syncthreads();
    cn[l*128 + t] = v / fmaxf(nrm, 1e-8f);
  }
  const int iu0[6] = {0,0,0,1,1,2}, iu1[6] = {1,2,3,2,3,3};
  __shared__ float dv[6];
  for (int p = 0; p < 6; ++p){
    float d = centers[iu0[p]*128 + t] - centers[iu1[p]*128 + t];
    red[t] = d * d; __syncthreads();
    for (int s = 64; s; s >>= 1){ if (t < s) red[t] += red[t + s]; __syncthreads(); }
    if (!t) dv[p] = sqrtf(red[0]);
    __syncthreads();
  }
  if (!t){
    float mean = 0.f;
    for (int p = 0; p < 6; ++p) mean += dv[p];
    mean /= 6.f;
    float var = 0.f;
    for (int p = 0; p < 6; ++p){ float d = dv[p] - mean; var += d * d; }
    var /= 5.f;                              // ddof=1
    dist_out[0] = -var;
  }
}

// ---------------- pos-enc tables ----------------
__global__ void k_pe(const float* __restrict__ projb, float* __restrict__ peb){
  int p = blockIdx.x, t = threadIdx.x;     // 1000 x 128
  float ex  = (float)(t >> 1) * (-2.0f * 9.210340371976184f / 128.0f);
  float ang = (float)p * expf(ex);
  float v = (t & 1) ? cosf(ang) : sinf(ang);
  peb[p*128 + t] = v + projb[t];
}
__global__ void k_pew(const float* __restrict__ peb, const float* __restrict__ Wih,
                      const float* __restrict__ bih, float* __restrict__ pew){
  int p = blockIdx.x;                       // 1000
  int j = blockIdx.y * 128 + threadIdx.x;   // 384
  const float* pb = peb + p*128;
  const float* wr = Wih + (size_t)j*128;
  float acc = bih[j];
  #pragma unroll 4
  for (int m = 0; m < 128; ++m) acc += pb[m] * wr[m];
  pew[(size_t)p*384 + j] = acc;
}
__global__ void k_combw(const float* __restrict__ projW, const float* __restrict__ Wih,
                        float* __restrict__ cw){
  int kk = blockIdx.x;                      // 128
  int j  = blockIdx.y * 128 + threadIdx.x;  // 384
  const float* pr = projW + (size_t)kk*128;
  const float* wr = Wih + (size_t)j*128;
  float acc = 0.f;
  #pragma unroll 4
  for (int m = 0; m < 128; ++m) acc += pr[m] * wr[m];
  cw[(size_t)kk*384 + j] = acc;
}
// pack Whh rows as f16x2 along k: wt[j*64 + kp] = (f16(W[j][2kp+1])<<16)|f16(W[j][2kp])
__global__ void k_packwhh16(const float* __restrict__ Whh, u32* __restrict__ wt){
  int kp = blockIdx.x;                      // 64
  int j  = blockIdx.y * 128 + threadIdx.x;  // 384
  _Float16 a = (_Float16)Whh[(size_t)j*128 + 2*kp];
  _Float16 b = (_Float16)Whh[(size_t)j*128 + 2*kp + 1];
  u32 lo = (u32)__builtin_bit_cast(u16, a);
  u32 hi = (u32)__builtin_bit_cast(u16, b);
  wt[(size_t)j*64 + kp] = (hi << 16) | lo;
}

// ---------------- tiled f32 GEMM: 32-row tiles, K staged in 2 halves ----------------
__global__ __launch_bounds__(256) void k_gemm(
    const float* __restrict__ X, const float* __restrict__ W, int ldw,
    const float* __restrict__ bias, const float* __restrict__ pew,
    const int* __restrict__ pos, float* __restrict__ out,
    u16* __restrict__ outb, int ldo){
  __shared__ __align__(16) float Wl[64*128];
  __shared__ __align__(16) float Xl[32*132];
  int tid = threadIdx.x;
  int rb = blockIdx.x * 32;
  int cb = blockIdx.y * 128;
  for (int idx = tid; idx < 32*32; idx += 256){
    int r = idx >> 5, c4 = idx & 31;
    *(float4*)&Xl[r*132 + c4*4] = *(const float4*)&X[(size_t)(rb + r)*128 + c4*4];
  }
  int rg = tid >> 4, cg = tid & 15;
  float acc[2][8];
  #pragma unroll
  for (int a = 0; a < 2; ++a)
    #pragma unroll
    for (int b = 0; b < 8; ++b) acc[a][b] = 0.f;
  for (int half = 0; half < 2; ++half){
    __syncthreads();
    for (int idx = tid; idx < 64*32; idx += 256){
      int kk = idx >> 5, c4 = idx & 31;
      *(float4*)&Wl[kk*128 + c4*4] =
          *(const float4*)&W[(size_t)(half*64 + kk)*ldw + cb + c4*4];
    }
    __syncthreads();
    #pragma unroll 4
    for (int kk = 0; kk < 64; ++kk){
      float4 wa = *(const float4*)&Wl[kk*128 + cg*8];
      float4 wb = *(const float4*)&Wl[kk*128 + cg*8 + 4];
      #pragma unroll
      for (int rr = 0; rr < 2; ++rr){
        float xv = Xl[(rg*2 + rr)*132 + half*64 + kk];
        acc[rr][0] += xv * wa.x; acc[rr][1] += xv * wa.y;
        acc[rr][2] += xv * wa.z; acc[rr][3] += xv * wa.w;
        acc[rr][4] += xv * wb.x; acc[rr][5] += xv * wb.y;
        acc[rr][6] += xv * wb.z; acc[rr][7] += xv * wb.w;
      }
    }
  }
  #pragma unroll
  for (int rr = 0; rr < 2; ++rr){
    int r = rb + rg*2 + rr;
    float bv[8];
    if (pos){
      const float* pw = pew + (size_t)pos[r]*384 + cb + cg*8;
      #pragma unroll
      for (int j = 0; j < 8; ++j) bv[j] = pw[j];
    } else {
      #pragma unroll
      for (int j = 0; j < 8; ++j) bv[j] = bias[cb + cg*8 + j];
    }
    if (outb){
      u16* op = outb + (size_t)r*ldo + cb + cg*8;
      #pragma unroll
      for (int j = 0; j < 8; ++j) op[j] = (u16)bf16rne(acc[rr][j] + bv[j]);
    } else {
      float* op = out + (size_t)r*ldo + cb + cg*8;
      #pragma unroll
      for (int j = 0; j < 8; ++j) op[j] = acc[rr][j] + bv[j];
    }
  }
}

// ---------------- edge phase 1: logits + per-dst max (4 dst per block) ----------------
__global__ __launch_bounds__(256) void k_logits(
    const float* __restrict__ q, const float* __restrict__ k,
    const int* __restrict__ row_ptr, const int* __restrict__ col,
    float* __restrict__ elog, float* __restrict__ rmax){
  int d = blockIdx.x * 4 + (threadIdx.x >> 6);
  int lane = threadIdx.x & 63;
  int e0 = row_ptr[d], e1 = row_ptr[d+1];
  if (e0 == e1) return;
  float2 qv = *(const float2*)&q[(size_t)d*128 + 2*lane];
  float m = -INFINITY;
  for (int e = e0; e < e1; ++e){
    int s = col[e];
    float2 kv = *(const float2*)&k[(size_t)s*128 + 2*lane];
    float p = qv.x * kv.x + qv.y * kv.y;
    p = wredf(p) * 0.08838834764831845f;   // 1/sqrt(128)
    if (lane == 0) elog[e] = p;
    m = fmaxf(m, p);
  }
  if (lane == 0) rmax[d] = m;
}

// ---------------- edge phase 2: softmax-weighted aggregation ----------------
__global__ __launch_bounds__(256) void k_agg(
    const float* __restrict__ v, const int* __restrict__ row_ptr,
    const int* __restrict__ col, const float* __restrict__ elog,
    const float* __restrict__ rmax, float* __restrict__ h2){
  int d = blockIdx.x * 4 + (threadIdx.x >> 6);
  int lane = threadIdx.x & 63;
  int e0 = row_ptr[d], e1 = row_ptr[d+1];
  if (e0 == e1) return;                    // h2 keeps skip value
  float m = rmax[d];
  float ssum = 0.f, a0 = 0.f, a1 = 0.f;
  for (int e = e0; e < e1; ++e){
    int s = col[e];
    float el = expf(elog[e] - m);
    float2 vv = *(const float2*)&v[(size_t)s*128 + 2*lane];
    ssum += el;
    a0 += el * vv.x;
    a1 += el * vv.y;
  }
  float inv = 1.f / ssum;
  float2 hv = *(float2*)&h2[(size_t)d*128 + 2*lane];
  hv.x += a0 * inv;
  hv.y += a1 * inv;
  *(float2*)&h2[(size_t)d*128 + 2*lane] = hv;
}

// ---------------- relu(layernorm) per row ----------------
__global__ __launch_bounds__(256) void k_lnrelu(
    const float* __restrict__ in, const float* __restrict__ g,
    const float* __restrict__ b, float* __restrict__ outp){
  int node = blockIdx.x * 4 + (threadIdx.x >> 6);
  int lane = threadIdx.x & 63;
  float x0 = in[(size_t)node*128 + 2*lane], x1 = in[(size_t)node*128 + 2*lane + 1];
  float s = wredf(x0 + x1);
  float qq = wredf(x0*x0 + x1*x1);
  float mu = s * 0.0078125f;
  float var = qq * 0.0078125f - mu*mu;
  float rstd = rsqrtf(var + 1e-5f);
  float y0 = (x0 - mu)*rstd*g[2*lane]   + b[2*lane];
  float y1 = (x1 - mu)*rstd*g[2*lane+1] + b[2*lane+1];
  outp[(size_t)node*128 + 2*lane]     = fmaxf(y0, 0.f);
  outp[(size_t)node*128 + 2*lane + 1] = fmaxf(y1, 0.f);
}

// ---------------- cluster assignment ----------------
__global__ __launch_bounds__(256) void k_classify(
    const float* __restrict__ h, const float* __restrict__ cn,
    const int* __restrict__ batch, const int* __restrict__ callsq,
    int* __restrict__ grp, int* __restrict__ inv){
  int node = blockIdx.x * 4 + (threadIdx.x >> 6);
  int lane = threadIdx.x & 63;
  float h0 = h[(size_t)node*128 + 2*lane], h1 = h[(size_t)node*128 + 2*lane + 1];
  float p0 = h0*cn[      2*lane] + h1*cn[      2*lane+1];
  float p1 = h0*cn[128 + 2*lane] + h1*cn[128 + 2*lane+1];
  float p2 = h0*cn[256 + 2*lane] + h1*cn[256 + 2*lane+1];
  float p3 = h0*cn[384 + 2*lane] + h1*cn[384 + 2*lane+1];
  p0 = wredf(p0); p1 = wredf(p1); p2 = wredf(p2); p3 = wredf(p3);
  if (lane == 0){
    float best = p0; int bi = 0;
    if (p1 > best){ best = p1; bi = 1; }
    if (p2 > best){ best = p2; bi = 2; }
    if (p3 > best){ best = p3; bi = 3; }
    grp[node] = batch[node]*4 + bi;
    inv[callsq[node]] = node;
  }
}

// ---------------- grouping: chunked multisplit ----------------
__global__ __launch_bounds__(256) void k_g1(const int* __restrict__ inv,
                                            const int* __restrict__ grp,
                                            int* __restrict__ ch){
  __shared__ int hist[GG];
  int c = blockIdx.x, t = threadIdx.x;
  hist[t] = 0; hist[t + 256] = 0;
  __syncthreads();
  int g = grp[inv[c*256 + t]];
  atomicAdd(&hist[g], 1);
  __syncthreads();
  ch[c*GG + t] = hist[t];
  ch[c*GG + 256 + t] = hist[256 + t];
}
__global__ void k_g2(int* __restrict__ ch, int* __restrict__ cnt){
  int g = threadIdx.x;   // 512
  int run = 0;
  for (int c = 0; c < NCHUNK; ++c){
    int idx = c*GG + g;
    int t = ch[idx];
    ch[idx] = run;
    run += t;
  }
  cnt[g] = run;
}
__global__ __launch_bounds__(256) void k_g3(
    const int* __restrict__ inv, const int* __restrict__ grp,
    const int* __restrict__ ch, int* __restrict__ pos, int* __restrict__ gn){
  __shared__ int hist[GG];
  int c = blockIdx.x, t = threadIdx.x;
  hist[t] = 0; hist[t + 256] = 0;
  __syncthreads();
  int node = inv[c*256 + t];
  int g = grp[node];
  int lane = t & 63, w = t >> 6;
  int before = 0, total = 0;
  for (int j = 0; j < 64; ++j){
    int gj = __shfl(g, j);
    if (gj == g){ total++; if (j < lane) before++; }
  }
  int base = 0;
  for (int wv = 0; wv < 4; ++wv){
    if (w == wv){
      base = hist[g];
      if (before == total - 1) hist[g] = base + total;  // last lane of its g
    }
    __syncthreads();
  }
  int p = ch[c*GG + g] + base + before;
  pos[node] = p;
  gn[(size_t)g*SMAX + p] = node;
}

// ---------------- GRU v2: f16 dot2, per-lane rows + XOR swizzle, b128 reads --------
// LDS: Wl16 3*128*64 u32 = 96KB (layout [gate][t][kp], row = 64 u32 = 16 uint4),
// hb16[2][128] f16, red[8]. h held in registers; f16 copy in LDS for dot2.
__global__ __launch_bounds__(256) void k_gru(
    const u16* __restrict__ gi, const u32* __restrict__ wt,
    const float* __restrict__ bhh, const float* __restrict__ sg,
    const float* __restrict__ sb, const int* __restrict__ gn,
    const int* __restrict__ cnt, u16* __restrict__ node_out){
  __shared__ __align__(16) u32 Wl[3*128*64];     // 96 KB, f16x2 packed along k
  __shared__ __align__(16) u16 hb16[2][128];     // h as f16
  __shared__ float redS[4], redQ[4];
  int tid = threadIdx.x;
  int sub = tid >> 7, t = tid & 127;
  int wv = t >> 6, lane = t & 63;
  int g = blockIdx.x * 2 + sub;
  int c0 = cnt[blockIdx.x*2], c1 = cnt[blockIdx.x*2 + 1];
  c0 = (c0 <= 1) ? 0 : c0;
  c1 = (c1 <= 1) ? 0 : c1;
  int nsteps = max(c0, c1);
  if (nsteps == 0) return;
  int my = sub ? c1 : c0;
  for (int idx = tid; idx < 6144; idx += 256)
    ((uint4*)Wl)[idx] = ((const uint4*)wt)[idx];
  hb16[sub][t] = 0;
  __syncthreads();
  float br = bhh[t], bz = bhh[128 + t], bn = bhh[256 + t];
  float gmul = sg[t], gadd = sb[t];
  const int* gnr = gn + (size_t)g*SMAX;
  const uint4* WR = (const uint4*)Wl + (size_t)t*16;           // gate r row
  const uint4* WZ = WR + 128*16;                                // gate z row
  const uint4* WN = WZ + 128*16;                                // gate n row
  const uint4* HB = (const uint4*)&hb16[sub][0];                // 16 uint4
  int swz = t & 15;
  float hprev = 0.f;
  for (int p = 0; p < nsteps; ++p){
    int node = (my > 0) ? gnr[min(p, my - 1)] : 0;
    const u16* gir = gi + (size_t)node*384;
    float xr = bf2f(gir[t]), xz = bf2f(gir[128 + t]), xn = bf2f(gir[256 + t]);
    float ar = br, az = bz, an = bn;
    #pragma unroll
    for (int s = 0; s < 16; ++s){
      int slot = s ^ swz;
      uint4 hh = HB[slot];
      uint4 wr = WR[slot];
      uint4 wz = WZ[slot];
      uint4 wn = WN[slot];
      ar = dot2f(wr.x, hh.x, ar); az = dot2f(wz.x, hh.x, az); an = dot2f(wn.x, hh.x, an);
      ar = dot2f(wr.y, hh.y, ar); az = dot2f(wz.y, hh.y, az); an = dot2f(wn.y, hh.y, an);
      ar = dot2f(wr.z, hh.z, ar); az = dot2f(wz.z, hh.z, az); an = dot2f(wn.z, hh.z, an);
      ar = dot2f(wr.w, hh.w, ar); az = dot2f(wz.w, hh.w, az); an = dot2f(wn.w, hh.w, an);
    }
    float r = 1.f / (1.f + expf(-(xr + ar)));
    float z = 1.f / (1.f + expf(-(xz + az)));
    float n = tanhf(xn + r * an);
    float hnew = (1.f - z) * n + z * hprev;
    hprev = hnew;
    __syncthreads();                        // B1: all h reads of this step done
    _Float16 hf = (_Float16)hnew;
    hb16[sub][t] = __builtin_bit_cast(u16, hf);
    float s = hnew, qq = hnew * hnew;
    #pragma unroll
    for (int o = 32; o; o >>= 1){ s += __shfl_xor(s, o); qq += __shfl_xor(qq, o); }
    if (lane == 0){ redS[sub*2 + wv] = s; redQ[sub*2 + wv] = qq; }
    __syncthreads();                        // B2: h16 + reductions visible
    if (p < my){
      float mu  = (redS[sub*2] + redS[sub*2 + 1]) * 0.0078125f;
      float var = (redQ[sub*2] + redQ[sub*2 + 1]) * 0.0078125f - mu*mu;
      float rstd = rsqrtf(var + 1e-5f);
      float o = (hnew - mu) * rstd * gmul + gadd;
      node_out[(size_t)node*128 + t] = (u16)bf16rne(fmaxf(o, 0.f));
    }
  }
}

// ---------------- head: gelu(lin1) -> sigmoid(lin2) ----------------
__global__ __launch_bounds__(256) void k_head(
    const float* __restrict__ h, const u16* __restrict__ node_out,
    const int* __restrict__ grp, const int* __restrict__ cnt,
    const float* __restrict__ l1W, const float* __restrict__ l1b,
    const float* __restrict__ l2W, const float* __restrict__ l2b,
    float* __restrict__ out){
  int node = blockIdx.x * 4 + (threadIdx.x >> 6);
  int lane = threadIdx.x & 63;
  bool single = (cnt[grp[node]] == 1);
  float x0, x1;
  if (single){
    x0 = h[(size_t)node*128 + 2*lane];
    x1 = h[(size_t)node*128 + 2*lane + 1];
  } else {
    x0 = bf2f(node_out[(size_t)node*128 + 2*lane]);
    x1 = bf2f(node_out[(size_t)node*128 + 2*lane + 1]);
  }
  float acc[8];
  #pragma unroll
  for (int j = 0; j < 8; ++j)
    acc[j] = x0 * l1W[(2*lane)*8 + j] + x1 * l1W[(2*lane + 1)*8 + j];
  #pragma unroll
  for (int o = 32; o; o >>= 1)
    #pragma unroll
    for (int j = 0; j < 8; ++j) acc[j] += __shfl_xor(acc[j], o);
  if (lane == 0){
    float zz = l2b[0];
    #pragma unroll
    for (int j = 0; j < 8; ++j){
      float xx = acc[j] + l1b[j];
      float ge = 0.5f * xx * (1.f + erff(xx * 0.7071067811865476f));
      zz += ge * l2W[j];
    }
    out[node] = 1.f / (1.f + expf(-zz));
  }
}

extern "C" void kernel_launch(void* const* d_in, const int* in_sizes, int n_in,
                              void* d_out, int out_size, void* d_ws, size_t ws_size,
                              hipStream_t stream){
  float* out = (float*)d_out;

  // ---- ws-size guard: encode ws MB into output instead of faulting ----
  if (ws_size < WS_NEEDED){
    float code = -(float)(ws_size >> 20);
    k_sentinel<<<(out_size + 255)/256, 256, 0, stream>>>(out, out_size, code);
    return;
  }

  const float* x       = (const float*)d_in[0];
  const int*   tei     = (const int*)d_in[1];
  const int*   callsq  = (const int*)d_in[2];
  const int*   batch   = (const int*)d_in[3];
  const float* Wq      = (const float*)d_in[4];
  const float* bq      = (const float*)d_in[5];
  const float* Wk      = (const float*)d_in[6];
  const float* bk      = (const float*)d_in[7];
  const float* Wv      = (const float*)d_in[8];
  const float* bv      = (const float*)d_in[9];
  const float* Wsk     = (const float*)d_in[10];
  const float* bsk     = (const float*)d_in[11];
  const float* lng     = (const float*)d_in[12];
  const float* lnb     = (const float*)d_in[13];
  const float* centers = (const float*)d_in[14];
  const float* projW   = (const float*)d_in[15];
  const float* projb   = (const float*)d_in[16];
  const float* Wih     = (const float*)d_in[17];
  const float* Whh     = (const float*)d_in[18];
  const float* bih     = (const float*)d_in[19];
  const float* bhh     = (const float*)d_in[20];
  const float* sqg     = (const float*)d_in[21];
  const float* sqb     = (const float*)d_in[22];
  const float* l1W     = (const float*)d_in[23];
  const float* l1b     = (const float*)d_in[24];
  const float* l2W     = (const float*)d_in[25];
  const float* l2b     = (const float*)d_in[26];

  float* wf = (float*)d_ws;
  float* f_h    = wf + F_H;
  float* f_a    = wf + F_A;
  float* f_b    = wf + F_B;
  float* f_elog = wf + F_ELOG;
  float* f_rmax = wf + F_RMAX;
  float* f_cn   = wf + F_CN;
  float* f_cw   = wf + F_CW;
  float* f_pew  = wf + F_PEW;
  float* f_peb  = wf + F_PEB;
  u16*   gi_bf  = (u16*)(wf + F_A);      // N x 384 bf16 (overlay, post-conv)
  u16*   no_bf  = (u16*)(wf + F_NODE);   // N x 128 bf16 node_out (overlay)
  int* wi = (int*)(wf + F_END);
  int* i_rowp = wi + I_ROWP;
  int* i_cur  = wi + I_CUR;
  int* i_col  = wi + I_COL;
  int* i_grp  = wi + I_GRP;
  int* i_inv  = wi + I_INV;
  int* i_pos  = wi + I_POS;
  int* i_gn   = wi + I_GN;
  int* i_cnt  = wi + I_CNT;
  int* i_ch   = wi + I_CH;
  int* i_bs   = wi + I_BS;
  u32* i_wt   = (u32*)(wi + I_WT);

  const int* esrc = tei;
  const int* edst = tei + EE;

  // CSR build
  k_zero<<<NN/256, 256, 0, stream>>>(i_cur);
  k_hist<<<EE/256, 256, 0, stream>>>(edst, i_cur);
  k_s1<<<NCHUNK, 256, 0, stream>>>(i_cur, i_bs);
  k_s2<<<1, 512, 0, stream>>>(i_bs);
  k_s3<<<NCHUNK, 256, 0, stream>>>(i_bs, i_rowp, i_cur);
  k_scatter<<<EE/256, 256, 0, stream>>>(esrc, edst, i_cur, i_col);

  // centers, PE tables, combined weights, packed f16 Whh rows
  k_setup<<<1, 128, 0, stream>>>(centers, f_cn, out + NN);
  k_pe<<<1000, 128, 0, stream>>>(projb, f_peb);
  k_pew<<<dim3(1000, 3), 128, 0, stream>>>(f_peb, Wih, bih, f_pew);
  k_combw<<<dim3(128, 3), 128, 0, stream>>>(projW, Wih, f_cw);
  k_packwhh16<<<dim3(64, 3), 128, 0, stream>>>(Whh, i_wt);

  // 3x TransformerConv + relu(LN); A/B ping-pong keeps peak mem at 2 buffers
  for (int i = 0; i < 3; ++i){
    const float* xin = i ? f_h : x;
    size_t wo = (size_t)i * 128 * 128, bo = (size_t)i * 128;
    k_gemm<<<dim3(NN/32, 1), 256, 0, stream>>>(xin, Wq + wo, 128, bq + bo, nullptr, nullptr, f_a, nullptr, 128);
    k_gemm<<<dim3(NN/32, 1), 256, 0, stream>>>(xin, Wk + wo, 128, bk + bo, nullptr, nullptr, f_b, nullptr, 128);
    k_logits<<<NN/4, 256, 0, stream>>>(f_a, f_b, i_rowp, i_col, f_elog, f_rmax);
    k_gemm<<<dim3(NN/32, 1), 256, 0, stream>>>(xin, Wv + wo, 128, bv + bo, nullptr, nullptr, f_a, nullptr, 128);
    k_gemm<<<dim3(NN/32, 1), 256, 0, stream>>>(xin, Wsk + wo, 128, bsk + bo, nullptr, nullptr, f_b, nullptr, 128);
    k_agg<<<NN/4, 256, 0, stream>>>(f_a, i_rowp, i_col, f_elog, f_rmax, f_b);
    k_lnrelu<<<NN/4, 256, 0, stream>>>(f_b, lng + bo, lnb + bo, f_h);
  }

  // cluster assignment + grouping
  k_classify<<<NN/4, 256, 0, stream>>>(f_h, f_cn, batch, callsq, i_grp, i_inv);
  k_g1<<<NCHUNK, 256, 0, stream>>>(i_inv, i_grp, i_ch);
  k_g2<<<1, 512, 0, stream>>>(i_ch, i_cnt);
  k_g3<<<NCHUNK, 256, 0, stream>>>(i_inv, i_grp, i_ch, i_pos, i_gn);

  // gi = h @ (projW@Wih^T) + PEW[pos]  -> bf16 overlay on A (+ part of B)
  k_gemm<<<dim3(NN/32, 3), 256, 0, stream>>>(f_h, f_cw, 384, nullptr, f_pew, i_pos, nullptr, gi_bf, 384);

  // GRU + LN + ReLU -> node_out (bf16, tail of B)
  k_gru<<<GG/2, 256, 0, stream>>>(gi_bf, i_wt, bhh, sqg, sqb, i_gn, i_cnt, no_bf);

  // head
  k_head<<<NN/4, 256, 0, stream>>>(f_h, no_bf, i_grp, i_cnt, l1W, l1b, l2W, l2b, out);
}

// Round 6
// 5558.703 us; speedup vs baseline: 1.2096x; 1.0332x over previous
//
#include <hip/hip_runtime.h>

#define NN 128000
#define EE 1024000
#define HH 128
#define GG 512
#define SMAX 1000
#define NCHUNK 500   // 500 * 256 = 128000

typedef unsigned int u32;
typedef unsigned short u16;

// ---------------- workspace layout (floats, then ints) ----------------
// ws budget measured round 3: 256 MiB. This layout: 213.3 MiB.
constexpr size_t NH     = (size_t)NN*HH;              // 16,384,000
constexpr size_t F_H    = 0;                          // h (persist, f32)
constexpr size_t F_A    = NH;                         // work A: q / v
constexpr size_t F_B    = 2*NH;                       // work B: k / skip+agg
constexpr size_t F_NODE = F_A + (size_t)NN*192;       // bf16 node_out overlay
constexpr size_t F_ELOG = 3*NH;                       // E edge logits
constexpr size_t F_RMAX = F_ELOG + EE;                // N per-dst max
constexpr size_t F_CN   = F_RMAX + NN;                // 4*128 normalized centers
constexpr size_t F_CW   = F_CN   + 512;               // 128*384 projW@Wih^T
constexpr size_t F_PEW  = F_CW   + 128*384;           // 1000*384 (pe+projb)@Wih^T + bih
constexpr size_t F_PEB  = F_PEW  + 1000*384;          // 1000*128 pe + projb
constexpr size_t F_END  = F_PEB  + 1000*128;

constexpr size_t I_ROWP = 0;                          // N+8 CSR row ptr
constexpr size_t I_CUR  = I_ROWP + NN + 8;
constexpr size_t I_COL  = I_CUR  + NN;                // E
constexpr size_t I_GRP  = I_COL  + EE;
constexpr size_t I_INV  = I_GRP  + NN;
constexpr size_t I_POS  = I_INV  + NN;
constexpr size_t I_GN   = I_POS  + NN;                // 512*1000
constexpr size_t I_CNT  = I_GN   + (size_t)GG*SMAX;
constexpr size_t I_CH   = I_CNT  + GG;                // 500*512
constexpr size_t I_BS   = I_CH   + (size_t)NCHUNK*GG;
constexpr size_t I_WT   = I_BS   + 512;               // 384*64 packed f16 Whh^T rows
constexpr size_t I_END  = I_WT   + 64*384;

constexpr size_t WS_NEEDED = F_END*4 + I_END*4;       // 213,293,088 B

__device__ inline float wredf(float v){
  #pragma unroll
  for (int o = 32; o; o >>= 1) v += __shfl_xor(v, o);
  return v;
}
__device__ inline u32 bf16rne(float f){
  u32 u = __float_as_uint(f);
  return (u + 0x7fffu + ((u >> 16) & 1u)) >> 16;
}
__device__ inline float bf2f(u16 u){
  return __uint_as_float(((u32)u) << 16);
}

typedef _Float16 h2_t __attribute__((ext_vector_type(2)));
__device__ inline float dot2f(u32 w, u32 h, float acc){
#if __has_builtin(__builtin_amdgcn_fdot2)
  return __builtin_amdgcn_fdot2(__builtin_bit_cast(h2_t, w),
                                __builtin_bit_cast(h2_t, h), acc, false);
#else
  float r;
  asm("v_dot2_f32_f16 %0, %1, %2, %3" : "=v"(r) : "v"(w), "v"(h), "v"(acc));
  return r;
#endif
}

// ---------------- ws-size diagnostic sentinel ----------------
__global__ void k_sentinel(float* __restrict__ out, int n, float val){
  int i = blockIdx.x * 256 + threadIdx.x;
  if (i < n) out[i] = val;
}

// ---------------- CSR build ----------------
__global__ void k_zero(int* __restrict__ p){
  p[blockIdx.x * 256 + threadIdx.x] = 0;
}
__global__ void k_hist(const int* __restrict__ dst, int* __restrict__ deg){
  int e = blockIdx.x * 256 + threadIdx.x;
  atomicAdd(&deg[dst[e]], 1);
}
__global__ void k_s1(const int* __restrict__ deg, int* __restrict__ bsum){
  __shared__ int red[256];
  int t = threadIdx.x;
  red[t] = deg[blockIdx.x * 256 + t];
  __syncthreads();
  for (int s = 128; s; s >>= 1){ if (t < s) red[t] += red[t + s]; __syncthreads(); }
  if (!t) bsum[blockIdx.x] = red[0];
}
__global__ void k_s2(int* __restrict__ bsum){
  __shared__ int arr[512];
  int t = threadIdx.x;
  int v0 = (t < NCHUNK) ? bsum[t] : 0;
  arr[t] = v0; __syncthreads();
  for (int off = 1; off < 512; off <<= 1){
    int v = (t >= off) ? arr[t - off] : 0;
    __syncthreads();
    arr[t] += v;
    __syncthreads();
  }
  if (t < NCHUNK) bsum[t] = arr[t] - v0;   // exclusive
}
__global__ void k_s3(const int* __restrict__ bsum, int* __restrict__ row_ptr,
                     int* __restrict__ cursor){
  __shared__ int arr[256];
  int t = threadIdx.x;
  int i = blockIdx.x * 256 + t;
  int v0 = cursor[i];                      // cursor currently holds deg
  arr[t] = v0; __syncthreads();
  for (int off = 1; off < 256; off <<= 1){
    int v = (t >= off) ? arr[t - off] : 0;
    __syncthreads();
    arr[t] += v;
    __syncthreads();
  }
  int exc = arr[t] - v0 + bsum[blockIdx.x];
  row_ptr[i] = exc;
  cursor[i]  = exc;
  if (i == 0) row_ptr[NN] = EE;
}
__global__ void k_scatter(const int* __restrict__ src, const int* __restrict__ dst,
                          int* __restrict__ cursor, int* __restrict__ col){
  int e = blockIdx.x * 256 + threadIdx.x;
  int idx = atomicAdd(&cursor[dst[e]], 1);
  col[idx] = src[e];
}

// ---------------- centers: normalize + distance ----------------
__global__ void k_setup(const float* __restrict__ centers, float* __restrict__ cn,
                        float* __restrict__ dist_out){
  __shared__ float red[128];
  int t = threadIdx.x;
  for (int l = 0; l < 4; ++l){
    float v = centers[l*128 + t];
    red[t] = v * v; __syncthreads();
    for (int s = 64; s; s >>= 1){ if (t < s) red[t] += red[t + s]; __syncthreads(); }
    float nrm = sqrtf(red[0]);
    __syncthreads();
    cn[l*128 + t] = v / fmaxf(nrm, 1e-8f);
  }
  const int iu0[6] = {0,0,0,1,1,2}, iu1[6] = {1,2,3,2,3,3};
  __shared__ float dv[6];
  for (int p = 0; p < 6; ++p){
    float d = centers[iu0[p]*128 + t] - centers[iu1[p]*128 + t];
    red[t] = d * d; __syncthreads();
    for (int s = 64; s; s >>= 1){ if (t < s) red[t] += red[t + s]; __syncthreads(); }
    if (!t) dv[p] = sqrtf(red[0]);
    __syncthreads();
  }
  if (!t){
    float mean = 0.f;
    for (int p = 0; p < 6; ++p) mean += dv[p];
    mean /= 6.f;
    float var = 0.f;
    for (int p = 0; p < 6; ++p){ float d = dv[p] - mean; var += d * d; }
    var /= 5.f;                              // ddof=1
    dist_out[0] = -var;
  }
}

// ---------------- pos-enc tables ----------------
__global__ void k_pe(const float* __restrict__ projb, float* __restrict__ peb){
  int p = blockIdx.x, t = threadIdx.x;     // 1000 x 128
  float ex  = (float)(t >> 1) * (-2.0f * 9.210340371976184f / 128.0f);
  float ang = (float)p * expf(ex);
  float v = (t & 1) ? cosf(ang) : sinf(ang);
  peb[p*128 + t] = v + projb[t];
}
__global__ void k_pew(const float* __restrict__ peb, const float* __restrict__ Wih,
                      const float* __restrict__ bih, float* __restrict__ pew){
  int p = blockIdx.x;                       // 1000
  int j = blockIdx.y * 128 + threadIdx.x;   // 384
  const float* pb = peb + p*128;
  const float* wr = Wih + (size_t)j*128;
  float acc = bih[j];
  #pragma unroll 4
  for (int m = 0; m < 128; ++m) acc += pb[m] * wr[m];
  pew[(size_t)p*384 + j] = acc;
}
__global__ void k_combw(const float* __restrict__ projW, const float* __restrict__ Wih,
                        float* __restrict__ cw){
  int kk = blockIdx.x;                      // 128
  int j  = blockIdx.y * 128 + threadIdx.x;  // 384
  const float* pr = projW + (size_t)kk*128;
  const float* wr = Wih + (size_t)j*128;
  float acc = 0.f;
  #pragma unroll 4
  for (int m = 0; m < 128; ++m) acc += pr[m] * wr[m];
  cw[(size_t)kk*384 + j] = acc;
}
// pack Whh rows as f16x2 along k: wt[j*64 + kp] = (f16(W[j][2kp+1])<<16)|f16(W[j][2kp])
__global__ void k_packwhh16(const float* __restrict__ Whh, u32* __restrict__ wt){
  int kp = blockIdx.x;                      // 64
  int j  = blockIdx.y * 128 + threadIdx.x;  // 384
  _Float16 a = (_Float16)Whh[(size_t)j*128 + 2*kp];
  _Float16 b = (_Float16)Whh[(size_t)j*128 + 2*kp + 1];
  u32 lo = (u32)__builtin_bit_cast(u16, a);
  u32 hi = (u32)__builtin_bit_cast(u16, b);
  wt[(size_t)j*64 + kp] = (hi << 16) | lo;
}

// ---------------- tiled f32 GEMM: 32-row tiles, K staged in 2 halves ----------------
__global__ __launch_bounds__(256) void k_gemm(
    const float* __restrict__ X, const float* __restrict__ W, int ldw,
    const float* __restrict__ bias, const float* __restrict__ pew,
    const int* __restrict__ pos, float* __restrict__ out,
    u16* __restrict__ outb, int ldo){
  __shared__ __align__(16) float Wl[64*128];
  __shared__ __align__(16) float Xl[32*132];
  int tid = threadIdx.x;
  int rb = blockIdx.x * 32;
  int cb = blockIdx.y * 128;
  for (int idx = tid; idx < 32*32; idx += 256){
    int r = idx >> 5, c4 = idx & 31;
    *(float4*)&Xl[r*132 + c4*4] = *(const float4*)&X[(size_t)(rb + r)*128 + c4*4];
  }
  int rg = tid >> 4, cg = tid & 15;
  float acc[2][8];
  #pragma unroll
  for (int a = 0; a < 2; ++a)
    #pragma unroll
    for (int b = 0; b < 8; ++b) acc[a][b] = 0.f;
  for (int half = 0; half < 2; ++half){
    __syncthreads();
    for (int idx = tid; idx < 64*32; idx += 256){
      int kk = idx >> 5, c4 = idx & 31;
      *(float4*)&Wl[kk*128 + c4*4] =
          *(const float4*)&W[(size_t)(half*64 + kk)*ldw + cb + c4*4];
    }
    __syncthreads();
    #pragma unroll 4
    for (int kk = 0; kk < 64; ++kk){
      float4 wa = *(const float4*)&Wl[kk*128 + cg*8];
      float4 wb = *(const float4*)&Wl[kk*128 + cg*8 + 4];
      #pragma unroll
      for (int rr = 0; rr < 2; ++rr){
        float xv = Xl[(rg*2 + rr)*132 + half*64 + kk];
        acc[rr][0] += xv * wa.x; acc[rr][1] += xv * wa.y;
        acc[rr][2] += xv * wa.z; acc[rr][3] += xv * wa.w;
        acc[rr][4] += xv * wb.x; acc[rr][5] += xv * wb.y;
        acc[rr][6] += xv * wb.z; acc[rr][7] += xv * wb.w;
      }
    }
  }
  #pragma unroll
  for (int rr = 0; rr < 2; ++rr){
    int r = rb + rg*2 + rr;
    float bv[8];
    if (pos){
      const float* pw = pew + (size_t)pos[r]*384 + cb + cg*8;
      #pragma unroll
      for (int j = 0; j < 8; ++j) bv[j] = pw[j];
    } else {
      #pragma unroll
      for (int j = 0; j < 8; ++j) bv[j] = bias[cb + cg*8 + j];
    }
    if (outb){
      u16* op = outb + (size_t)r*ldo + cb + cg*8;
      #pragma unroll
      for (int j = 0; j < 8; ++j) op[j] = (u16)bf16rne(acc[rr][j] + bv[j]);
    } else {
      float* op = out + (size_t)r*ldo + cb + cg*8;
      #pragma unroll
      for (int j = 0; j < 8; ++j) op[j] = acc[rr][j] + bv[j];
    }
  }
}

// ---------------- edge phase 1: logits + per-dst max (4 dst per block) ----------------
__global__ __launch_bounds__(256) void k_logits(
    const float* __restrict__ q, const float* __restrict__ k,
    const int* __restrict__ row_ptr, const int* __restrict__ col,
    float* __restrict__ elog, float* __restrict__ rmax){
  int d = blockIdx.x * 4 + (threadIdx.x >> 6);
  int lane = threadIdx.x & 63;
  int e0 = row_ptr[d], e1 = row_ptr[d+1];
  if (e0 == e1) return;
  float2 qv = *(const float2*)&q[(size_t)d*128 + 2*lane];
  float m = -INFINITY;
  for (int e = e0; e < e1; ++e){
    int s = col[e];
    float2 kv = *(const float2*)&k[(size_t)s*128 + 2*lane];
    float p = qv.x * kv.x + qv.y * kv.y;
    p = wredf(p) * 0.08838834764831845f;   // 1/sqrt(128)
    if (lane == 0) elog[e] = p;
    m = fmaxf(m, p);
  }
  if (lane == 0) rmax[d] = m;
}

// ---------------- edge phase 2: softmax-weighted aggregation ----------------
__global__ __launch_bounds__(256) void k_agg(
    const float* __restrict__ v, const int* __restrict__ row_ptr,
    const int* __restrict__ col, const float* __restrict__ elog,
    const float* __restrict__ rmax, float* __restrict__ h2){
  int d = blockIdx.x * 4 + (threadIdx.x >> 6);
  int lane = threadIdx.x & 63;
  int e0 = row_ptr[d], e1 = row_ptr[d+1];
  if (e0 == e1) return;                    // h2 keeps skip value
  float m = rmax[d];
  float ssum = 0.f, a0 = 0.f, a1 = 0.f;
  for (int e = e0; e < e1; ++e){
    int s = col[e];
    float el = expf(elog[e] - m);
    float2 vv = *(const float2*)&v[(size_t)s*128 + 2*lane];
    ssum += el;
    a0 += el * vv.x;
    a1 += el * vv.y;
  }
  float inv = 1.f / ssum;
  float2 hv = *(float2*)&h2[(size_t)d*128 + 2*lane];
  hv.x += a0 * inv;
  hv.y += a1 * inv;
  *(float2*)&h2[(size_t)d*128 + 2*lane] = hv;
}

// ---------------- relu(layernorm) per row ----------------
__global__ __launch_bounds__(256) void k_lnrelu(
    const float* __restrict__ in, const float* __restrict__ g,
    const float* __restrict__ b, float* __restrict__ outp){
  int node = blockIdx.x * 4 + (threadIdx.x >> 6);
  int lane = threadIdx.x & 63;
  float x0 = in[(size_t)node*128 + 2*lane], x1 = in[(size_t)node*128 + 2*lane + 1];
  float s = wredf(x0 + x1);
  float qq = wredf(x0*x0 + x1*x1);
  float mu = s * 0.0078125f;
  float var = qq * 0.0078125f - mu*mu;
  float rstd = rsqrtf(var + 1e-5f);
  float y0 = (x0 - mu)*rstd*g[2*lane]   + b[2*lane];
  float y1 = (x1 - mu)*rstd*g[2*lane+1] + b[2*lane+1];
  outp[(size_t)node*128 + 2*lane]     = fmaxf(y0, 0.f);
  outp[(size_t)node*128 + 2*lane + 1] = fmaxf(y1, 0.f);
}

// ---------------- cluster assignment ----------------
__global__ __launch_bounds__(256) void k_classify(
    const float* __restrict__ h, const float* __restrict__ cn,
    const int* __restrict__ batch, const int* __restrict__ callsq,
    int* __restrict__ grp, int* __restrict__ inv){
  int node = blockIdx.x * 4 + (threadIdx.x >> 6);
  int lane = threadIdx.x & 63;
  float h0 = h[(size_t)node*128 + 2*lane], h1 = h[(size_t)node*128 + 2*lane + 1];
  float p0 = h0*cn[      2*lane] + h1*cn[      2*lane+1];
  float p1 = h0*cn[128 + 2*lane] + h1*cn[128 + 2*lane+1];
  float p2 = h0*cn[256 + 2*lane] + h1*cn[256 + 2*lane+1];
  float p3 = h0*cn[384 + 2*lane] + h1*cn[384 + 2*lane+1];
  p0 = wredf(p0); p1 = wredf(p1); p2 = wredf(p2); p3 = wredf(p3);
  if (lane == 0){
    float best = p0; int bi = 0;
    if (p1 > best){ best = p1; bi = 1; }
    if (p2 > best){ best = p2; bi = 2; }
    if (p3 > best){ best = p3; bi = 3; }
    grp[node] = batch[node]*4 + bi;
    inv[callsq[node]] = node;
  }
}

// ---------------- grouping: chunked multisplit ----------------
__global__ __launch_bounds__(256) void k_g1(const int* __restrict__ inv,
                                            const int* __restrict__ grp,
                                            int* __restrict__ ch){
  __shared__ int hist[GG];
  int c = blockIdx.x, t = threadIdx.x;
  hist[t] = 0; hist[t + 256] = 0;
  __syncthreads();
  int g = grp[inv[c*256 + t]];
  atomicAdd(&hist[g], 1);
  __syncthreads();
  ch[c*GG + t] = hist[t];
  ch[c*GG + 256 + t] = hist[256 + t];
}
__global__ void k_g2(int* __restrict__ ch, int* __restrict__ cnt){
  int g = threadIdx.x;   // 512
  int run = 0;
  for (int c = 0; c < NCHUNK; ++c){
    int idx = c*GG + g;
    int t = ch[idx];
    ch[idx] = run;
    run += t;
  }
  cnt[g] = run;
}
__global__ __launch_bounds__(256) void k_g3(
    const int* __restrict__ inv, const int* __restrict__ grp,
    const int* __restrict__ ch, int* __restrict__ pos, int* __restrict__ gn){
  __shared__ int hist[GG];
  int c = blockIdx.x, t = threadIdx.x;
  hist[t] = 0; hist[t + 256] = 0;
  __syncthreads();
  int node = inv[c*256 + t];
  int g = grp[node];
  int lane = t & 63, w = t >> 6;
  int before = 0, total = 0;
  for (int j = 0; j < 64; ++j){
    int gj = __shfl(g, j);
    if (gj == g){ total++; if (j < lane) before++; }
  }
  int base = 0;
  for (int wv = 0; wv < 4; ++wv){
    if (w == wv){
      base = hist[g];
      if (before == total - 1) hist[g] = base + total;  // last lane of its g
    }
    __syncthreads();
  }
  int p = ch[c*GG + g] + base + before;
  pos[node] = p;
  gn[(size_t)g*SMAX + p] = node;
}

// ---------------- GRU v3: weights in VGPRs, 2 threads per output j ----------------
// Block = 256 threads = 1 group; j = t>>1, kh = t&1 owns k-half [kh*64, kh*64+64).
// Per-thread weights: 3 gates x 8 uint4 (f16x2 pairs) = 96 VGPRs, loaded once.
// Per step: 8 ds_read_b128 (h half, broadcast across 32 lanes), 96 v_dot2_f32_f16,
// shfl_xor(1) pair-reduce, gate math. gi prefetched one step ahead.
__global__ __launch_bounds__(256, 2) void k_gru(
    const u16* __restrict__ gi, const u32* __restrict__ wt,
    const float* __restrict__ bhh, const float* __restrict__ sg,
    const float* __restrict__ sb, const int* __restrict__ gn,
    const int* __restrict__ cnt, u16* __restrict__ node_out){
  __shared__ __align__(16) u16 hb16[128];      // h as f16
  __shared__ float redS[4], redQ[4];
  int t = threadIdx.x;
  int j = t >> 1;              // output index 0..127
  int kh = t & 1;              // k-half 0/1
  int wv = t >> 6, lane = t & 63;
  int g = blockIdx.x;
  int my = cnt[g];
  if (my <= 1) return;
  // ---- load per-thread weight rows into registers (once) ----
  uint4 wr_[8], wz_[8], wn_[8];
  {
    const uint4* wt4 = (const uint4*)wt;
    size_t b0 = (size_t)(0*128 + j)*16 + kh*8;
    size_t b1 = (size_t)(1*128 + j)*16 + kh*8;
    size_t b2 = (size_t)(2*128 + j)*16 + kh*8;
    #pragma unroll
    for (int s = 0; s < 8; ++s){
      wr_[s] = wt4[b0 + s];
      wz_[s] = wt4[b1 + s];
      wn_[s] = wt4[b2 + s];
    }
  }
  if (t < 128) hb16[t] = 0;
  __syncthreads();
  float br = bhh[j], bz = bhh[128 + j], bn = bhh[256 + j];
  float gmul = sg[j], gadd = sb[j];
  const int* gnr = gn + (size_t)g*SMAX;
  const uint4* HB = (const uint4*)&hb16[0];    // 16 uint4; our half: [kh*8, kh*8+8)
  float hprev = 0.f;
  int node = gnr[0];
  {
    const u16* gir = gi + (size_t)node*384;
    // prefetch roll-in handled by first loop iteration reading these:
  }
  const u16* gir0 = gi + (size_t)node*384;
  float pxr = bf2f(gir0[j]), pxz = bf2f(gir0[128 + j]), pxn = bf2f(gir0[256 + j]);
  for (int p = 0; p < my; ++p){
    float xr = pxr, xz = pxz, xn = pxn;
    int nodeN = gnr[min(p + 1, my - 1)];
    const u16* girN = gi + (size_t)nodeN*384;
    pxr = bf2f(girN[j]); pxz = bf2f(girN[128 + j]); pxn = bf2f(girN[256 + j]);
    uint4 hh[8];
    #pragma unroll
    for (int s = 0; s < 8; ++s) hh[s] = HB[kh*8 + s];
    float ar = 0.f, az = 0.f, an = 0.f;
    #pragma unroll
    for (int s = 0; s < 8; ++s){
      ar = dot2f(wr_[s].x, hh[s].x, ar); az = dot2f(wz_[s].x, hh[s].x, az); an = dot2f(wn_[s].x, hh[s].x, an);
      ar = dot2f(wr_[s].y, hh[s].y, ar); az = dot2f(wz_[s].y, hh[s].y, az); an = dot2f(wn_[s].y, hh[s].y, an);
      ar = dot2f(wr_[s].z, hh[s].z, ar); az = dot2f(wz_[s].z, hh[s].z, az); an = dot2f(wn_[s].z, hh[s].z, an);
      ar = dot2f(wr_[s].w, hh[s].w, ar); az = dot2f(wz_[s].w, hh[s].w, az); an = dot2f(wn_[s].w, hh[s].w, an);
    }
    // pair-reduce k-halves (partner = lane^1), then add bias
    ar += __shfl_xor(ar, 1); az += __shfl_xor(az, 1); an += __shfl_xor(an, 1);
    ar += br; az += bz; an += bn;
    float r = 1.f / (1.f + expf(-(xr + ar)));
    float z = 1.f / (1.f + expf(-(xz + az)));
    float n = tanhf(xn + r * an);
    float hnew = (1.f - z) * n + z * hprev;
    hprev = hnew;
    __syncthreads();                        // B1: all h reads of this step done
    if (!kh){
      _Float16 hf = (_Float16)hnew;
      hb16[j] = __builtin_bit_cast(u16, hf);
    }
    float s_ = kh ? 0.f : hnew;
    float q_ = kh ? 0.f : hnew * hnew;
    #pragma unroll
    for (int o = 32; o; o >>= 1){ s_ += __shfl_xor(s_, o); q_ += __shfl_xor(q_, o); }
    if (lane == 0){ redS[wv] = s_; redQ[wv] = q_; }
    __syncthreads();                        // B2: h16 + reductions visible
    if (!kh){
      float S = redS[0] + redS[1] + redS[2] + redS[3];
      float Q = redQ[0] + redQ[1] + redQ[2] + redQ[3];
      float mu  = S * 0.0078125f;
      float var = Q * 0.0078125f - mu*mu;
      float rstd = rsqrtf(var + 1e-5f);
      float o = (hnew - mu) * rstd * gmul + gadd;
      node_out[(size_t)node*128 + j] = (u16)bf16rne(fmaxf(o, 0.f));
    }
    node = nodeN;
  }
}

// ---------------- head: gelu(lin1) -> sigmoid(lin2) ----------------
__global__ __launch_bounds__(256) void k_head(
    const float* __restrict__ h, const u16* __restrict__ node_out,
    const int* __restrict__ grp, const int* __restrict__ cnt,
    const float* __restrict__ l1W, const float* __restrict__ l1b,
    const float* __restrict__ l2W, const float* __restrict__ l2b,
    float* __restrict__ out){
  int node = blockIdx.x * 4 + (threadIdx.x >> 6);
  int lane = threadIdx.x & 63;
  bool single = (cnt[grp[node]] == 1);
  float x0, x1;
  if (single){
    x0 = h[(size_t)node*128 + 2*lane];
    x1 = h[(size_t)node*128 + 2*lane + 1];
  } else {
    x0 = bf2f(node_out[(size_t)node*128 + 2*lane]);
    x1 = bf2f(node_out[(size_t)node*128 + 2*lane + 1]);
  }
  float acc[8];
  #pragma unroll
  for (int j = 0; j < 8; ++j)
    acc[j] = x0 * l1W[(2*lane)*8 + j] + x1 * l1W[(2*lane + 1)*8 + j];
  #pragma unroll
  for (int o = 32; o; o >>= 1)
    #pragma unroll
    for (int j = 0; j < 8; ++j) acc[j] += __shfl_xor(acc[j], o);
  if (lane == 0){
    float zz = l2b[0];
    #pragma unroll
    for (int j = 0; j < 8; ++j){
      float xx = acc[j] + l1b[j];
      float ge = 0.5f * xx * (1.f + erff(xx * 0.7071067811865476f));
      zz += ge * l2W[j];
    }
    out[node] = 1.f / (1.f + expf(-zz));
  }
}

extern "C" void kernel_launch(void* const* d_in, const int* in_sizes, int n_in,
                              void* d_out, int out_size, void* d_ws, size_t ws_size,
                              hipStream_t stream){
  float* out = (float*)d_out;

  // ---- ws-size guard: encode ws MB into output instead of faulting ----
  if (ws_size < WS_NEEDED){
    float code = -(float)(ws_size >> 20);
    k_sentinel<<<(out_size + 255)/256, 256, 0, stream>>>(out, out_size, code);
    return;
  }

  const float* x       = (const float*)d_in[0];
  const int*   tei     = (const int*)d_in[1];
  const int*   callsq  = (const int*)d_in[2];
  const int*   batch   = (const int*)d_in[3];
  const float* Wq      = (const float*)d_in[4];
  const float* bq      = (const float*)d_in[5];
  const float* Wk      = (const float*)d_in[6];
  const float* bk      = (const float*)d_in[7];
  const float* Wv      = (const float*)d_in[8];
  const float* bv      = (const float*)d_in[9];
  const float* Wsk     = (const float*)d_in[10];
  const float* bsk     = (const float*)d_in[11];
  const float* lng     = (const float*)d_in[12];
  const float* lnb     = (const float*)d_in[13];
  const float* centers = (const float*)d_in[14];
  const float* projW   = (const float*)d_in[15];
  const float* projb   = (const float*)d_in[16];
  const float* Wih     = (const float*)d_in[17];
  const float* Whh     = (const float*)d_in[18];
  const float* bih     = (const float*)d_in[19];
  const float* bhh     = (const float*)d_in[20];
  const float* sqg     = (const float*)d_in[21];
  const float* sqb     = (const float*)d_in[22];
  const float* l1W     = (const float*)d_in[23];
  const float* l1b     = (const float*)d_in[24];
  const float* l2W     = (const float*)d_in[25];
  const float* l2b     = (const float*)d_in[26];

  float* wf = (float*)d_ws;
  float* f_h    = wf + F_H;
  float* f_a    = wf + F_A;
  float* f_b    = wf + F_B;
  float* f_elog = wf + F_ELOG;
  float* f_rmax = wf + F_RMAX;
  float* f_cn   = wf + F_CN;
  float* f_cw   = wf + F_CW;
  float* f_pew  = wf + F_PEW;
  float* f_peb  = wf + F_PEB;
  u16*   gi_bf  = (u16*)(wf + F_A);      // N x 384 bf16 (overlay, post-conv)
  u16*   no_bf  = (u16*)(wf + F_NODE);   // N x 128 bf16 node_out (overlay)
  int* wi = (int*)(wf + F_END);
  int* i_rowp = wi + I_ROWP;
  int* i_cur  = wi + I_CUR;
  int* i_col  = wi + I_COL;
  int* i_grp  = wi + I_GRP;
  int* i_inv  = wi + I_INV;
  int* i_pos  = wi + I_POS;
  int* i_gn   = wi + I_GN;
  int* i_cnt  = wi + I_CNT;
  int* i_ch   = wi + I_CH;
  int* i_bs   = wi + I_BS;
  u32* i_wt   = (u32*)(wi + I_WT);

  const int* esrc = tei;
  const int* edst = tei + EE;

  // CSR build
  k_zero<<<NN/256, 256, 0, stream>>>(i_cur);
  k_hist<<<EE/256, 256, 0, stream>>>(edst, i_cur);
  k_s1<<<NCHUNK, 256, 0, stream>>>(i_cur, i_bs);
  k_s2<<<1, 512, 0, stream>>>(i_bs);
  k_s3<<<NCHUNK, 256, 0, stream>>>(i_bs, i_rowp, i_cur);
  k_scatter<<<EE/256, 256, 0, stream>>>(esrc, edst, i_cur, i_col);

  // centers, PE tables, combined weights, packed f16 Whh rows
  k_setup<<<1, 128, 0, stream>>>(centers, f_cn, out + NN);
  k_pe<<<1000, 128, 0, stream>>>(projb, f_peb);
  k_pew<<<dim3(1000, 3), 128, 0, stream>>>(f_peb, Wih, bih, f_pew);
  k_combw<<<dim3(128, 3), 128, 0, stream>>>(projW, Wih, f_cw);
  k_packwhh16<<<dim3(64, 3), 128, 0, stream>>>(Whh, i_wt);

  // 3x TransformerConv + relu(LN); A/B ping-pong keeps peak mem at 2 buffers
  for (int i = 0; i < 3; ++i){
    const float* xin = i ? f_h : x;
    size_t wo = (size_t)i * 128 * 128, bo = (size_t)i * 128;
    k_gemm<<<dim3(NN/32, 1), 256, 0, stream>>>(xin, Wq + wo, 128, bq + bo, nullptr, nullptr, f_a, nullptr, 128);
    k_gemm<<<dim3(NN/32, 1), 256, 0, stream>>>(xin, Wk + wo, 128, bk + bo, nullptr, nullptr, f_b, nullptr, 128);
    k_logits<<<NN/4, 256, 0, stream>>>(f_a, f_b, i_rowp, i_col, f_elog, f_rmax);
    k_gemm<<<dim3(NN/32, 1), 256, 0, stream>>>(xin, Wv + wo, 128, bv + bo, nullptr, nullptr, f_a, nullptr, 128);
    k_gemm<<<dim3(NN/32, 1), 256, 0, stream>>>(xin, Wsk + wo, 128, bsk + bo, nullptr, nullptr, f_b, nullptr, 128);
    k_agg<<<NN/4, 256, 0, stream>>>(f_a, i_rowp, i_col, f_elog, f_rmax, f_b);
    k_lnrelu<<<NN/4, 256, 0, stream>>>(f_b, lng + bo, lnb + bo, f_h);
  }

  // cluster assignment + grouping
  k_classify<<<NN/4, 256, 0, stream>>>(f_h, f_cn, batch, callsq, i_grp, i_inv);
  k_g1<<<NCHUNK, 256, 0, stream>>>(i_inv, i_grp, i_ch);
  k_g2<<<1, 512, 0, stream>>>(i_ch, i_cnt);
  k_g3<<<NCHUNK, 256, 0, stream>>>(i_inv, i_grp, i_ch, i_pos, i_gn);

  // gi = h @ (projW@Wih^T) + PEW[pos]  -> bf16 overlay on A (+ part of B)
  k_gemm<<<dim3(NN/32, 3), 256, 0, stream>>>(f_h, f_cw, 384, nullptr, f_pew, i_pos, nullptr, gi_bf, 384);

  // GRU + LN + ReLU -> node_out (bf16, tail of B); 1 group per block
  k_gru<<<GG, 256, 0, stream>>>(gi_bf, i_wt, bhh, sqg, sqb, i_gn, i_cnt, no_bf);

  // head
  k_head<<<NN/4, 256, 0, stream>>>(f_h, no_bf, i_grp, i_cnt, l1W, l1b, l2W, l2b, out);
}

// Round 7
// 4267.942 us; speedup vs baseline: 1.5754x; 1.3024x over previous
//
#include <hip/hip_runtime.h>

#define NN 128000
#define EE 1024000
#define HH 128
#define GG 512
#define SMAX 1000
#define NCHUNK 500   // 500 * 256 = 128000

typedef unsigned int u32;
typedef unsigned short u16;

// ---------------- workspace layout (floats, then ints) ----------------
// ws budget measured round 3: 256 MiB. This layout: 213.3 MiB.
constexpr size_t NH     = (size_t)NN*HH;              // 16,384,000
constexpr size_t F_H    = 0;                          // h (persist, f32)
constexpr size_t F_A    = NH;                         // work A: q / v
constexpr size_t F_B    = 2*NH;                       // work B: k / skip+agg
constexpr size_t F_NODE = F_A + (size_t)NN*192;       // bf16 node_out overlay
constexpr size_t F_ELOG = 3*NH;                       // E edge logits
constexpr size_t F_RMAX = F_ELOG + EE;                // N per-dst max
constexpr size_t F_CN   = F_RMAX + NN;                // 4*128 normalized centers
constexpr size_t F_CW   = F_CN   + 512;               // 128*384 projW@Wih^T
constexpr size_t F_PEW  = F_CW   + 128*384;           // 1000*384 (pe+projb)@Wih^T + bih
constexpr size_t F_PEB  = F_PEW  + 1000*384;          // 1000*128 pe + projb
constexpr size_t F_END  = F_PEB  + 1000*128;

constexpr size_t I_ROWP = 0;                          // N+8 CSR row ptr
constexpr size_t I_CUR  = I_ROWP + NN + 8;
constexpr size_t I_COL  = I_CUR  + NN;                // E
constexpr size_t I_GRP  = I_COL  + EE;
constexpr size_t I_INV  = I_GRP  + NN;
constexpr size_t I_POS  = I_INV  + NN;
constexpr size_t I_GN   = I_POS  + NN;                // 512*1000
constexpr size_t I_CNT  = I_GN   + (size_t)GG*SMAX;
constexpr size_t I_CH   = I_CNT  + GG;                // 500*512
constexpr size_t I_BS   = I_CH   + (size_t)NCHUNK*GG;
constexpr size_t I_WT   = I_BS   + 512;               // 384*64 packed f16 Whh^T rows
constexpr size_t I_END  = I_WT   + 64*384;

constexpr size_t WS_NEEDED = F_END*4 + I_END*4;       // 213,293,088 B

__device__ inline float wredf(float v){
  #pragma unroll
  for (int o = 32; o; o >>= 1) v += __shfl_xor(v, o);
  return v;
}
__device__ inline u32 bf16rne(float f){
  u32 u = __float_as_uint(f);
  return (u + 0x7fffu + ((u >> 16) & 1u)) >> 16;
}
__device__ inline float bf2f(u16 u){
  return __uint_as_float(((u32)u) << 16);
}

typedef _Float16 h2_t __attribute__((ext_vector_type(2)));
__device__ inline float dot2f(u32 w, u32 h, float acc){
#if __has_builtin(__builtin_amdgcn_fdot2)
  return __builtin_amdgcn_fdot2(__builtin_bit_cast(h2_t, w),
                                __builtin_bit_cast(h2_t, h), acc, false);
#else
  float r;
  asm("v_dot2_f32_f16 %0, %1, %2, %3" : "=v"(r) : "v"(w), "v"(h), "v"(acc));
  return r;
#endif
}
// pin a uint4 into VGPRs: compiler can no longer rematerialize the load
#define PIN4(v) asm volatile("" : "+v"((v).x), "+v"((v).y), "+v"((v).z), "+v"((v).w))

// ---------------- ws-size diagnostic sentinel ----------------
__global__ void k_sentinel(float* __restrict__ out, int n, float val){
  int i = blockIdx.x * 256 + threadIdx.x;
  if (i < n) out[i] = val;
}

// ---------------- CSR build ----------------
__global__ void k_zero(int* __restrict__ p){
  p[blockIdx.x * 256 + threadIdx.x] = 0;
}
__global__ void k_hist(const int* __restrict__ dst, int* __restrict__ deg){
  int e = blockIdx.x * 256 + threadIdx.x;
  atomicAdd(&deg[dst[e]], 1);
}
__global__ void k_s1(const int* __restrict__ deg, int* __restrict__ bsum){
  __shared__ int red[256];
  int t = threadIdx.x;
  red[t] = deg[blockIdx.x * 256 + t];
  __syncthreads();
  for (int s = 128; s; s >>= 1){ if (t < s) red[t] += red[t + s]; __syncthreads(); }
  if (!t) bsum[blockIdx.x] = red[0];
}
__global__ void k_s2(int* __restrict__ bsum){
  __shared__ int arr[512];
  int t = threadIdx.x;
  int v0 = (t < NCHUNK) ? bsum[t] : 0;
  arr[t] = v0; __syncthreads();
  for (int off = 1; off < 512; off <<= 1){
    int v = (t >= off) ? arr[t - off] : 0;
    __syncthreads();
    arr[t] += v;
    __syncthreads();
  }
  if (t < NCHUNK) bsum[t] = arr[t] - v0;   // exclusive
}
__global__ void k_s3(const int* __restrict__ bsum, int* __restrict__ row_ptr,
                     int* __restrict__ cursor){
  __shared__ int arr[256];
  int t = threadIdx.x;
  int i = blockIdx.x * 256 + t;
  int v0 = cursor[i];                      // cursor currently holds deg
  arr[t] = v0; __syncthreads();
  for (int off = 1; off < 256; off <<= 1){
    int v = (t >= off) ? arr[t - off] : 0;
    __syncthreads();
    arr[t] += v;
    __syncthreads();
  }
  int exc = arr[t] - v0 + bsum[blockIdx.x];
  row_ptr[i] = exc;
  cursor[i]  = exc;
  if (i == 0) row_ptr[NN] = EE;
}
__global__ void k_scatter(const int* __restrict__ src, const int* __restrict__ dst,
                          int* __restrict__ cursor, int* __restrict__ col){
  int e = blockIdx.x * 256 + threadIdx.x;
  int idx = atomicAdd(&cursor[dst[e]], 1);
  col[idx] = src[e];
}

// ---------------- centers: normalize + distance ----------------
__global__ void k_setup(const float* __restrict__ centers, float* __restrict__ cn,
                        float* __restrict__ dist_out){
  __shared__ float red[128];
  int t = threadIdx.x;
  for (int l = 0; l < 4; ++l){
    float v = centers[l*128 + t];
    red[t] = v * v; __syncthreads();
    for (int s = 64; s; s >>= 1){ if (t < s) red[t] += red[t + s]; __syncthreads(); }
    float nrm = sqrtf(red[0]);
    __syncthreads();
    cn[l*128 + t] = v / fmaxf(nrm, 1e-8f);
  }
  const int iu0[6] = {0,0,0,1,1,2}, iu1[6] = {1,2,3,2,3,3};
  __shared__ float dv[6];
  for (int p = 0; p < 6; ++p){
    float d = centers[iu0[p]*128 + t] - centers[iu1[p]*128 + t];
    red[t] = d * d; __syncthreads();
    for (int s = 64; s; s >>= 1){ if (t < s) red[t] += red[t + s]; __syncthreads(); }
    if (!t) dv[p] = sqrtf(red[0]);
    __syncthreads();
  }
  if (!t){
    float mean = 0.f;
    for (int p = 0; p < 6; ++p) mean += dv[p];
    mean /= 6.f;
    float var = 0.f;
    for (int p = 0; p < 6; ++p){ float d = dv[p] - mean; var += d * d; }
    var /= 5.f;                              // ddof=1
    dist_out[0] = -var;
  }
}

// ---------------- pos-enc tables ----------------
__global__ void k_pe(const float* __restrict__ projb, float* __restrict__ peb){
  int p = blockIdx.x, t = threadIdx.x;     // 1000 x 128
  float ex  = (float)(t >> 1) * (-2.0f * 9.210340371976184f / 128.0f);
  float ang = (float)p * expf(ex);
  float v = (t & 1) ? cosf(ang) : sinf(ang);
  peb[p*128 + t] = v + projb[t];
}
__global__ void k_pew(const float* __restrict__ peb, const float* __restrict__ Wih,
                      const float* __restrict__ bih, float* __restrict__ pew){
  int p = blockIdx.x;                       // 1000
  int j = blockIdx.y * 128 + threadIdx.x;   // 384
  const float* pb = peb + p*128;
  const float* wr = Wih + (size_t)j*128;
  float acc = bih[j];
  #pragma unroll 4
  for (int m = 0; m < 128; ++m) acc += pb[m] * wr[m];
  pew[(size_t)p*384 + j] = acc;
}
__global__ void k_combw(const float* __restrict__ projW, const float* __restrict__ Wih,
                        float* __restrict__ cw){
  int kk = blockIdx.x;                      // 128
  int j  = blockIdx.y * 128 + threadIdx.x;  // 384
  const float* pr = projW + (size_t)kk*128;
  const float* wr = Wih + (size_t)j*128;
  float acc = 0.f;
  #pragma unroll 4
  for (int m = 0; m < 128; ++m) acc += pr[m] * wr[m];
  cw[(size_t)kk*384 + j] = acc;
}
// pack Whh rows as f16x2 along k: wt[j*64 + kp] = (f16(W[j][2kp+1])<<16)|f16(W[j][2kp])
__global__ void k_packwhh16(const float* __restrict__ Whh, u32* __restrict__ wt){
  int kp = blockIdx.x;                      // 64
  int j  = blockIdx.y * 128 + threadIdx.x;  // 384
  _Float16 a = (_Float16)Whh[(size_t)j*128 + 2*kp];
  _Float16 b = (_Float16)Whh[(size_t)j*128 + 2*kp + 1];
  u32 lo = (u32)__builtin_bit_cast(u16, a);
  u32 hi = (u32)__builtin_bit_cast(u16, b);
  wt[(size_t)j*64 + kp] = (hi << 16) | lo;
}

// ---------------- tiled f32 GEMM: 64-row tiles, 4x8 acc, K staged in 2 halves ------
// LDS = 32KB (Wl) + 33.8KB (Xl) = 65.8KB -> 2 blocks/CU.
__global__ __launch_bounds__(256) void k_gemm(
    const float* __restrict__ X, const float* __restrict__ W, int ldw,
    const float* __restrict__ bias, const float* __restrict__ pew,
    const int* __restrict__ pos, float* __restrict__ out,
    u16* __restrict__ outb, int ldo){
  __shared__ __align__(16) float Wl[64*128];
  __shared__ __align__(16) float Xl[64*132];
  int tid = threadIdx.x;
  int rb = blockIdx.x * 64;
  int cb = blockIdx.y * 128;
  for (int idx = tid; idx < 64*32; idx += 256){
    int r = idx >> 5, c4 = idx & 31;
    *(float4*)&Xl[r*132 + c4*4] = *(const float4*)&X[(size_t)(rb + r)*128 + c4*4];
  }
  int rg = tid >> 4, cg = tid & 15;
  float acc[4][8];
  #pragma unroll
  for (int a = 0; a < 4; ++a)
    #pragma unroll
    for (int b = 0; b < 8; ++b) acc[a][b] = 0.f;
  for (int half = 0; half < 2; ++half){
    __syncthreads();
    for (int idx = tid; idx < 64*32; idx += 256){
      int kk = idx >> 5, c4 = idx & 31;
      *(float4*)&Wl[kk*128 + c4*4] =
          *(const float4*)&W[(size_t)(half*64 + kk)*ldw + cb + c4*4];
    }
    __syncthreads();
    #pragma unroll 4
    for (int kk = 0; kk < 64; ++kk){
      float4 wa = *(const float4*)&Wl[kk*128 + cg*8];
      float4 wb = *(const float4*)&Wl[kk*128 + cg*8 + 4];
      #pragma unroll
      for (int rr = 0; rr < 4; ++rr){
        float xv = Xl[(rg*4 + rr)*132 + half*64 + kk];
        acc[rr][0] += xv * wa.x; acc[rr][1] += xv * wa.y;
        acc[rr][2] += xv * wa.z; acc[rr][3] += xv * wa.w;
        acc[rr][4] += xv * wb.x; acc[rr][5] += xv * wb.y;
        acc[rr][6] += xv * wb.z; acc[rr][7] += xv * wb.w;
      }
    }
  }
  #pragma unroll
  for (int rr = 0; rr < 4; ++rr){
    int r = rb + rg*4 + rr;
    float bv[8];
    if (pos){
      const float* pw = pew + (size_t)pos[r]*384 + cb + cg*8;
      #pragma unroll
      for (int j = 0; j < 8; ++j) bv[j] = pw[j];
    } else {
      #pragma unroll
      for (int j = 0; j < 8; ++j) bv[j] = bias[cb + cg*8 + j];
    }
    if (outb){
      u16* op = outb + (size_t)r*ldo + cb + cg*8;
      #pragma unroll
      for (int j = 0; j < 8; ++j) op[j] = (u16)bf16rne(acc[rr][j] + bv[j]);
    } else {
      float* op = out + (size_t)r*ldo + cb + cg*8;
      #pragma unroll
      for (int j = 0; j < 8; ++j) op[j] = acc[rr][j] + bv[j];
    }
  }
}

// ---------------- edge phase 1: logits + per-dst max (4 dst per block) ----------------
__global__ __launch_bounds__(256) void k_logits(
    const float* __restrict__ q, const float* __restrict__ k,
    const int* __restrict__ row_ptr, const int* __restrict__ col,
    float* __restrict__ elog, float* __restrict__ rmax){
  int d = blockIdx.x * 4 + (threadIdx.x >> 6);
  int lane = threadIdx.x & 63;
  int e0 = row_ptr[d], e1 = row_ptr[d+1];
  if (e0 == e1) return;
  float2 qv = *(const float2*)&q[(size_t)d*128 + 2*lane];
  float m = -INFINITY;
  for (int e = e0; e < e1; ++e){
    int s = col[e];
    float2 kv = *(const float2*)&k[(size_t)s*128 + 2*lane];
    float p = qv.x * kv.x + qv.y * kv.y;
    p = wredf(p) * 0.08838834764831845f;   // 1/sqrt(128)
    if (lane == 0) elog[e] = p;
    m = fmaxf(m, p);
  }
  if (lane == 0) rmax[d] = m;
}

// ---------------- edge phase 2: softmax-weighted aggregation ----------------
__global__ __launch_bounds__(256) void k_agg(
    const float* __restrict__ v, const int* __restrict__ row_ptr,
    const int* __restrict__ col, const float* __restrict__ elog,
    const float* __restrict__ rmax, float* __restrict__ h2){
  int d = blockIdx.x * 4 + (threadIdx.x >> 6);
  int lane = threadIdx.x & 63;
  int e0 = row_ptr[d], e1 = row_ptr[d+1];
  if (e0 == e1) return;                    // h2 keeps skip value
  float m = rmax[d];
  float ssum = 0.f, a0 = 0.f, a1 = 0.f;
  for (int e = e0; e < e1; ++e){
    int s = col[e];
    float el = expf(elog[e] - m);
    float2 vv = *(const float2*)&v[(size_t)s*128 + 2*lane];
    ssum += el;
    a0 += el * vv.x;
    a1 += el * vv.y;
  }
  float inv = 1.f / ssum;
  float2 hv = *(float2*)&h2[(size_t)d*128 + 2*lane];
  hv.x += a0 * inv;
  hv.y += a1 * inv;
  *(float2*)&h2[(size_t)d*128 + 2*lane] = hv;
}

// ---------------- relu(layernorm) per row ----------------
__global__ __launch_bounds__(256) void k_lnrelu(
    const float* __restrict__ in, const float* __restrict__ g,
    const float* __restrict__ b, float* __restrict__ outp){
  int node = blockIdx.x * 4 + (threadIdx.x >> 6);
  int lane = threadIdx.x & 63;
  float x0 = in[(size_t)node*128 + 2*lane], x1 = in[(size_t)node*128 + 2*lane + 1];
  float s = wredf(x0 + x1);
  float qq = wredf(x0*x0 + x1*x1);
  float mu = s * 0.0078125f;
  float var = qq * 0.0078125f - mu*mu;
  float rstd = rsqrtf(var + 1e-5f);
  float y0 = (x0 - mu)*rstd*g[2*lane]   + b[2*lane];
  float y1 = (x1 - mu)*rstd*g[2*lane+1] + b[2*lane+1];
  outp[(size_t)node*128 + 2*lane]     = fmaxf(y0, 0.f);
  outp[(size_t)node*128 + 2*lane + 1] = fmaxf(y1, 0.f);
}

// ---------------- cluster assignment ----------------
__global__ __launch_bounds__(256) void k_classify(
    const float* __restrict__ h, const float* __restrict__ cn,
    const int* __restrict__ batch, const int* __restrict__ callsq,
    int* __restrict__ grp, int* __restrict__ inv){
  int node = blockIdx.x * 4 + (threadIdx.x >> 6);
  int lane = threadIdx.x & 63;
  float h0 = h[(size_t)node*128 + 2*lane], h1 = h[(size_t)node*128 + 2*lane + 1];
  float p0 = h0*cn[      2*lane] + h1*cn[      2*lane+1];
  float p1 = h0*cn[128 + 2*lane] + h1*cn[128 + 2*lane+1];
  float p2 = h0*cn[256 + 2*lane] + h1*cn[256 + 2*lane+1];
  float p3 = h0*cn[384 + 2*lane] + h1*cn[384 + 2*lane+1];
  p0 = wredf(p0); p1 = wredf(p1); p2 = wredf(p2); p3 = wredf(p3);
  if (lane == 0){
    float best = p0; int bi = 0;
    if (p1 > best){ best = p1; bi = 1; }
    if (p2 > best){ best = p2; bi = 2; }
    if (p3 > best){ best = p3; bi = 3; }
    grp[node] = batch[node]*4 + bi;
    inv[callsq[node]] = node;
  }
}

// ---------------- grouping: chunked multisplit ----------------
__global__ __launch_bounds__(256) void k_g1(const int* __restrict__ inv,
                                            const int* __restrict__ grp,
                                            int* __restrict__ ch){
  __shared__ int hist[GG];
  int c = blockIdx.x, t = threadIdx.x;
  hist[t] = 0; hist[t + 256] = 0;
  __syncthreads();
  int g = grp[inv[c*256 + t]];
  atomicAdd(&hist[g], 1);
  __syncthreads();
  ch[c*GG + t] = hist[t];
  ch[c*GG + 256 + t] = hist[256 + t];
}
__global__ void k_g2(int* __restrict__ ch, int* __restrict__ cnt){
  int g = threadIdx.x;   // 512
  int run = 0;
  for (int c = 0; c < NCHUNK; ++c){
    int idx = c*GG + g;
    int t = ch[idx];
    ch[idx] = run;
    run += t;
  }
  cnt[g] = run;
}
__global__ __launch_bounds__(256) void k_g3(
    const int* __restrict__ inv, const int* __restrict__ grp,
    const int* __restrict__ ch, int* __restrict__ pos, int* __restrict__ gn){
  __shared__ int hist[GG];
  int c = blockIdx.x, t = threadIdx.x;
  hist[t] = 0; hist[t + 256] = 0;
  __syncthreads();
  int node = inv[c*256 + t];
  int g = grp[node];
  int lane = t & 63, w = t >> 6;
  int before = 0, total = 0;
  for (int j = 0; j < 64; ++j){
    int gj = __shfl(g, j);
    if (gj == g){ total++; if (j < lane) before++; }
  }
  int base = 0;
  for (int wv = 0; wv < 4; ++wv){
    if (w == wv){
      base = hist[g];
      if (before == total - 1) hist[g] = base + total;  // last lane of its g
    }
    __syncthreads();
  }
  int p = ch[c*GG + g] + base + before;
  pos[node] = p;
  gn[(size_t)g*SMAX + p] = node;
}

// ---------------- GRU v4: pinned VGPR weights, double-buffered h, 1 barrier/step ---
// Block = 256 threads = 1 group; j = t>>1, kh = t&1 owns k-half.
// Weights: 3 gates x 8 uint4 = 96 VGPRs, loaded once and PINNED via asm.
__global__ __launch_bounds__(256, 2) void k_gru(
    const u16* __restrict__ gi, const u32* __restrict__ wt,
    const float* __restrict__ bhh, const float* __restrict__ sg,
    const float* __restrict__ sb, const int* __restrict__ gn,
    const int* __restrict__ cnt, u16* __restrict__ node_out){
  __shared__ __align__(16) u16 hb16[2][128];   // double-buffered h (f16)
  __shared__ float redS[2][4], redQ[2][4];
  int t = threadIdx.x;
  int j = t >> 1;              // output index 0..127
  int kh = t & 1;              // k-half 0/1
  int wv = t >> 6, lane = t & 63;
  int g = blockIdx.x;
  int my = cnt[g];
  if (my <= 1) return;
  // ---- load per-thread weight rows into registers (once), then pin ----
  uint4 wr_[8], wz_[8], wn_[8];
  {
    const uint4* wt4 = (const uint4*)wt;
    size_t b0 = (size_t)(0*128 + j)*16 + kh*8;
    size_t b1 = (size_t)(1*128 + j)*16 + kh*8;
    size_t b2 = (size_t)(2*128 + j)*16 + kh*8;
    #pragma unroll
    for (int s = 0; s < 8; ++s){
      wr_[s] = wt4[b0 + s];
      wz_[s] = wt4[b1 + s];
      wn_[s] = wt4[b2 + s];
    }
    #pragma unroll
    for (int s = 0; s < 8; ++s){
      PIN4(wr_[s]); PIN4(wz_[s]); PIN4(wn_[s]);
    }
  }
  if (t < 128) hb16[0][t] = 0;
  __syncthreads();
  float br = bhh[j], bz = bhh[128 + j], bn = bhh[256 + j];
  float gmul = sg[j], gadd = sb[j];
  const int* gnr = gn + (size_t)g*SMAX;
  float hprev = 0.f;
  int node = gnr[0];
  const u16* gir0 = gi + (size_t)node*384;
  float pxr = bf2f(gir0[j]), pxz = bf2f(gir0[128 + j]), pxn = bf2f(gir0[256 + j]);
  for (int p = 0; p < my; ++p){
    int cur = p & 1, nxt = cur ^ 1;
    float xr = pxr, xz = pxz, xn = pxn;
    int nodeN = gnr[min(p + 1, my - 1)];
    const u16* girN = gi + (size_t)nodeN*384;
    pxr = bf2f(girN[j]); pxz = bf2f(girN[128 + j]); pxn = bf2f(girN[256 + j]);
    const uint4* HB = (const uint4*)&hb16[cur][0];
    uint4 hh[8];
    #pragma unroll
    for (int s = 0; s < 8; ++s) hh[s] = HB[kh*8 + s];
    float ar = 0.f, az = 0.f, an = 0.f;
    #pragma unroll
    for (int s = 0; s < 8; ++s){
      ar = dot2f(wr_[s].x, hh[s].x, ar); az = dot2f(wz_[s].x, hh[s].x, az); an = dot2f(wn_[s].x, hh[s].x, an);
      ar = dot2f(wr_[s].y, hh[s].y, ar); az = dot2f(wz_[s].y, hh[s].y, az); an = dot2f(wn_[s].y, hh[s].y, an);
      ar = dot2f(wr_[s].z, hh[s].z, ar); az = dot2f(wz_[s].z, hh[s].z, az); an = dot2f(wn_[s].z, hh[s].z, an);
      ar = dot2f(wr_[s].w, hh[s].w, ar); az = dot2f(wz_[s].w, hh[s].w, az); an = dot2f(wn_[s].w, hh[s].w, an);
    }
    // pair-reduce k-halves (partner = lane^1), then add bias
    ar += __shfl_xor(ar, 1); az += __shfl_xor(az, 1); an += __shfl_xor(an, 1);
    ar += br; az += bz; an += bn;
    float r = 1.f / (1.f + expf(-(xr + ar)));
    float z = 1.f / (1.f + expf(-(xz + az)));
    float n = tanhf(xn + r * an);
    float hnew = (1.f - z) * n + z * hprev;
    hprev = hnew;
    if (!kh){
      _Float16 hf = (_Float16)hnew;
      hb16[nxt][j] = __builtin_bit_cast(u16, hf);   // write NEXT buffer
    }
    float s_ = kh ? 0.f : hnew;
    float q_ = kh ? 0.f : hnew * hnew;
    #pragma unroll
    for (int o = 32; o; o >>= 1){ s_ += __shfl_xor(s_, o); q_ += __shfl_xor(q_, o); }
    if (lane == 0){ redS[cur][wv] = s_; redQ[cur][wv] = q_; }
    __syncthreads();            // single barrier: h[nxt] + red[cur] now visible
    if (!kh){
      float S = redS[cur][0] + redS[cur][1] + redS[cur][2] + redS[cur][3];
      float Q = redQ[cur][0] + redQ[cur][1] + redQ[cur][2] + redQ[cur][3];
      float mu  = S * 0.0078125f;
      float var = Q * 0.0078125f - mu*mu;
      float rstd = rsqrtf(var + 1e-5f);
      float o = (hnew - mu) * rstd * gmul + gadd;
      node_out[(size_t)node*128 + j] = (u16)bf16rne(fmaxf(o, 0.f));
    }
    node = nodeN;
  }
}

// ---------------- head: gelu(lin1) -> sigmoid(lin2) ----------------
__global__ __launch_bounds__(256) void k_head(
    const float* __restrict__ h, const u16* __restrict__ node_out,
    const int* __restrict__ grp, const int* __restrict__ cnt,
    const float* __restrict__ l1W, const float* __restrict__ l1b,
    const float* __restrict__ l2W, const float* __restrict__ l2b,
    float* __restrict__ out){
  int node = blockIdx.x * 4 + (threadIdx.x >> 6);
  int lane = threadIdx.x & 63;
  bool single = (cnt[grp[node]] == 1);
  float x0, x1;
  if (single){
    x0 = h[(size_t)node*128 + 2*lane];
    x1 = h[(size_t)node*128 + 2*lane + 1];
  } else {
    x0 = bf2f(node_out[(size_t)node*128 + 2*lane]);
    x1 = bf2f(node_out[(size_t)node*128 + 2*lane + 1]);
  }
  float acc[8];
  #pragma unroll
  for (int j = 0; j < 8; ++j)
    acc[j] = x0 * l1W[(2*lane)*8 + j] + x1 * l1W[(2*lane + 1)*8 + j];
  #pragma unroll
  for (int o = 32; o; o >>= 1)
    #pragma unroll
    for (int j = 0; j < 8; ++j) acc[j] += __shfl_xor(acc[j], o);
  if (lane == 0){
    float zz = l2b[0];
    #pragma unroll
    for (int j = 0; j < 8; ++j){
      float xx = acc[j] + l1b[j];
      float ge = 0.5f * xx * (1.f + erff(xx * 0.7071067811865476f));
      zz += ge * l2W[j];
    }
    out[node] = 1.f / (1.f + expf(-zz));
  }
}

extern "C" void kernel_launch(void* const* d_in, const int* in_sizes, int n_in,
                              void* d_out, int out_size, void* d_ws, size_t ws_size,
                              hipStream_t stream){
  float* out = (float*)d_out;

  // ---- ws-size guard: encode ws MB into output instead of faulting ----
  if (ws_size < WS_NEEDED){
    float code = -(float)(ws_size >> 20);
    k_sentinel<<<(out_size + 255)/256, 256, 0, stream>>>(out, out_size, code);
    return;
  }

  const float* x       = (const float*)d_in[0];
  const int*   tei     = (const int*)d_in[1];
  const int*   callsq  = (const int*)d_in[2];
  const int*   batch   = (const int*)d_in[3];
  const float* Wq      = (const float*)d_in[4];
  const float* bq      = (const float*)d_in[5];
  const float* Wk      = (const float*)d_in[6];
  const float* bk      = (const float*)d_in[7];
  const float* Wv      = (const float*)d_in[8];
  const float* bv      = (const float*)d_in[9];
  const float* Wsk     = (const float*)d_in[10];
  const float* bsk     = (const float*)d_in[11];
  const float* lng     = (const float*)d_in[12];
  const float* lnb     = (const float*)d_in[13];
  const float* centers = (const float*)d_in[14];
  const float* projW   = (const float*)d_in[15];
  const float* projb   = (const float*)d_in[16];
  const float* Wih     = (const float*)d_in[17];
  const float* Whh     = (const float*)d_in[18];
  const float* bih     = (const float*)d_in[19];
  const float* bhh     = (const float*)d_in[20];
  const float* sqg     = (const float*)d_in[21];
  const float* sqb     = (const float*)d_in[22];
  const float* l1W     = (const float*)d_in[23];
  const float* l1b     = (const float*)d_in[24];
  const float* l2W     = (const float*)d_in[25];
  const float* l2b     = (const float*)d_in[26];

  float* wf = (float*)d_ws;
  float* f_h    = wf + F_H;
  float* f_a    = wf + F_A;
  float* f_b    = wf + F_B;
  float* f_elog = wf + F_ELOG;
  float* f_rmax = wf + F_RMAX;
  float* f_cn   = wf + F_CN;
  float* f_cw   = wf + F_CW;
  float* f_pew  = wf + F_PEW;
  float* f_peb  = wf + F_PEB;
  u16*   gi_bf  = (u16*)(wf + F_A);      // N x 384 bf16 (overlay, post-conv)
  u16*   no_bf  = (u16*)(wf + F_NODE);   // N x 128 bf16 node_out (overlay)
  int* wi = (int*)(wf + F_END);
  int* i_rowp = wi + I_ROWP;
  int* i_cur  = wi + I_CUR;
  int* i_col  = wi + I_COL;
  int* i_grp  = wi + I_GRP;
  int* i_inv  = wi + I_INV;
  int* i_pos  = wi + I_POS;
  int* i_gn   = wi + I_GN;
  int* i_cnt  = wi + I_CNT;
  int* i_ch   = wi + I_CH;
  int* i_bs   = wi + I_BS;
  u32* i_wt   = (u32*)(wi + I_WT);

  const int* esrc = tei;
  const int* edst = tei + EE;

  // CSR build
  k_zero<<<NN/256, 256, 0, stream>>>(i_cur);
  k_hist<<<EE/256, 256, 0, stream>>>(edst, i_cur);
  k_s1<<<NCHUNK, 256, 0, stream>>>(i_cur, i_bs);
  k_s2<<<1, 512, 0, stream>>>(i_bs);
  k_s3<<<NCHUNK, 256, 0, stream>>>(i_bs, i_rowp, i_cur);
  k_scatter<<<EE/256, 256, 0, stream>>>(esrc, edst, i_cur, i_col);

  // centers, PE tables, combined weights, packed f16 Whh rows
  k_setup<<<1, 128, 0, stream>>>(centers, f_cn, out + NN);
  k_pe<<<1000, 128, 0, stream>>>(projb, f_peb);
  k_pew<<<dim3(1000, 3), 128, 0, stream>>>(f_peb, Wih, bih, f_pew);
  k_combw<<<dim3(128, 3), 128, 0, stream>>>(projW, Wih, f_cw);
  k_packwhh16<<<dim3(64, 3), 128, 0, stream>>>(Whh, i_wt);

  // 3x TransformerConv + relu(LN); A/B ping-pong keeps peak mem at 2 buffers
  for (int i = 0; i < 3; ++i){
    const float* xin = i ? f_h : x;
    size_t wo = (size_t)i * 128 * 128, bo = (size_t)i * 128;
    k_gemm<<<dim3(NN/64, 1), 256, 0, stream>>>(xin, Wq + wo, 128, bq + bo, nullptr, nullptr, f_a, nullptr, 128);
    k_gemm<<<dim3(NN/64, 1), 256, 0, stream>>>(xin, Wk + wo, 128, bk + bo, nullptr, nullptr, f_b, nullptr, 128);
    k_logits<<<NN/4, 256, 0, stream>>>(f_a, f_b, i_rowp, i_col, f_elog, f_rmax);
    k_gemm<<<dim3(NN/64, 1), 256, 0, stream>>>(xin, Wv + wo, 128, bv + bo, nullptr, nullptr, f_a, nullptr, 128);
    k_gemm<<<dim3(NN/64, 1), 256, 0, stream>>>(xin, Wsk + wo, 128, bsk + bo, nullptr, nullptr, f_b, nullptr, 128);
    k_agg<<<NN/4, 256, 0, stream>>>(f_a, i_rowp, i_col, f_elog, f_rmax, f_b);
    k_lnrelu<<<NN/4, 256, 0, stream>>>(f_b, lng + bo, lnb + bo, f_h);
  }

  // cluster assignment + grouping
  k_classify<<<NN/4, 256, 0, stream>>>(f_h, f_cn, batch, callsq, i_grp, i_inv);
  k_g1<<<NCHUNK, 256, 0, stream>>>(i_inv, i_grp, i_ch);
  k_g2<<<1, 512, 0, stream>>>(i_ch, i_cnt);
  k_g3<<<NCHUNK, 256, 0, stream>>>(i_inv, i_grp, i_ch, i_pos, i_gn);

  // gi = h @ (projW@Wih^T) + PEW[pos]  -> bf16 overlay on A (+ part of B)
  k_gemm<<<dim3(NN/64, 3), 256, 0, stream>>>(f_h, f_cw, 384, nullptr, f_pew, i_pos, nullptr, gi_bf, 384);

  // GRU + LN + ReLU -> node_out (bf16, tail of B); 1 group per block
  k_gru<<<GG, 256, 0, stream>>>(gi_bf, i_wt, bhh, sqg, sqb, i_gn, i_cnt, no_bf);

  // head
  k_head<<<NN/4, 256, 0, stream>>>(f_h, no_bf, i_grp, i_cnt, l1W, l1b, l2W, l2b, out);
}

// Round 8
// 4203.307 us; speedup vs baseline: 1.5996x; 1.0154x over previous
//
#include <hip/hip_runtime.h>

#define NN 128000
#define EE 1024000
#define HH 128
#define GG 512
#define SMAX 1000
#define NCHUNK 500   // 500 * 256 = 128000

typedef unsigned int u32;
typedef unsigned short u16;

// ---------------- workspace layout (floats, then ints) ----------------
// ws budget measured round 3: 256 MiB. This layout: 213.3 MiB.
constexpr size_t NH     = (size_t)NN*HH;              // 16,384,000
constexpr size_t F_H    = 0;                          // h (persist, f32)
constexpr size_t F_A    = NH;                         // work A: q / v
constexpr size_t F_B    = 2*NH;                       // work B: k / skip+agg
constexpr size_t F_NODE = F_A + (size_t)NN*192;       // bf16 node_out overlay
constexpr size_t F_ELOG = 3*NH;                       // E edge logits
constexpr size_t F_RMAX = F_ELOG + EE;                // N per-dst max
constexpr size_t F_CN   = F_RMAX + NN;                // 4*128 normalized centers
constexpr size_t F_CW   = F_CN   + 512;               // 128*384 projW@Wih^T
constexpr size_t F_PEW  = F_CW   + 128*384;           // 1000*384 (pe+projb)@Wih^T + bih
constexpr size_t F_PEB  = F_PEW  + 1000*384;          // 1000*128 pe + projb
constexpr size_t F_END  = F_PEB  + 1000*128;

constexpr size_t I_ROWP = 0;                          // N+8 CSR row ptr
constexpr size_t I_CUR  = I_ROWP + NN + 8;
constexpr size_t I_COL  = I_CUR  + NN;                // E
constexpr size_t I_GRP  = I_COL  + EE;
constexpr size_t I_INV  = I_GRP  + NN;
constexpr size_t I_POS  = I_INV  + NN;
constexpr size_t I_GN   = I_POS  + NN;                // 512*1000
constexpr size_t I_CNT  = I_GN   + (size_t)GG*SMAX;
constexpr size_t I_CH   = I_CNT  + GG;                // 500*512
constexpr size_t I_BS   = I_CH   + (size_t)NCHUNK*GG;
constexpr size_t I_WT   = I_BS   + 512;               // 384*64 packed f16 Whh^T rows
constexpr size_t I_END  = I_WT   + 64*384;

constexpr size_t WS_NEEDED = F_END*4 + I_END*4;       // 213,293,088 B

__device__ inline float wredf(float v){
  #pragma unroll
  for (int o = 32; o; o >>= 1) v += __shfl_xor(v, o);
  return v;
}
__device__ inline u32 bf16rne(float f){
  u32 u = __float_as_uint(f);
  return (u + 0x7fffu + ((u >> 16) & 1u)) >> 16;
}
__device__ inline float bf2f(u16 u){
  return __uint_as_float(((u32)u) << 16);
}

typedef _Float16 h2_t __attribute__((ext_vector_type(2)));
__device__ inline float dot2f(u32 w, u32 h, float acc){
#if __has_builtin(__builtin_amdgcn_fdot2)
  return __builtin_amdgcn_fdot2(__builtin_bit_cast(h2_t, w),
                                __builtin_bit_cast(h2_t, h), acc, false);
#else
  float r;
  asm("v_dot2_f32_f16 %0, %1, %2, %3" : "=v"(r) : "v"(w), "v"(h), "v"(acc));
  return r;
#endif
}
// pin a uint4 into VGPRs: compiler can no longer rematerialize the load
#define PIN4(v) asm volatile("" : "+v"((v).x), "+v"((v).y), "+v"((v).z), "+v"((v).w))

// ---------------- ws-size diagnostic sentinel ----------------
__global__ void k_sentinel(float* __restrict__ out, int n, float val){
  int i = blockIdx.x * 256 + threadIdx.x;
  if (i < n) out[i] = val;
}

// ---------------- CSR build ----------------
__global__ void k_zero(int* __restrict__ p){
  p[blockIdx.x * 256 + threadIdx.x] = 0;
}
__global__ void k_hist(const int* __restrict__ dst, int* __restrict__ deg){
  int e = blockIdx.x * 256 + threadIdx.x;
  atomicAdd(&deg[dst[e]], 1);
}
__global__ void k_s1(const int* __restrict__ deg, int* __restrict__ bsum){
  __shared__ int red[256];
  int t = threadIdx.x;
  red[t] = deg[blockIdx.x * 256 + t];
  __syncthreads();
  for (int s = 128; s; s >>= 1){ if (t < s) red[t] += red[t + s]; __syncthreads(); }
  if (!t) bsum[blockIdx.x] = red[0];
}
__global__ void k_s2(int* __restrict__ bsum){
  __shared__ int arr[512];
  int t = threadIdx.x;
  int v0 = (t < NCHUNK) ? bsum[t] : 0;
  arr[t] = v0; __syncthreads();
  for (int off = 1; off < 512; off <<= 1){
    int v = (t >= off) ? arr[t - off] : 0;
    __syncthreads();
    arr[t] += v;
    __syncthreads();
  }
  if (t < NCHUNK) bsum[t] = arr[t] - v0;   // exclusive
}
__global__ void k_s3(const int* __restrict__ bsum, int* __restrict__ row_ptr,
                     int* __restrict__ cursor){
  __shared__ int arr[256];
  int t = threadIdx.x;
  int i = blockIdx.x * 256 + t;
  int v0 = cursor[i];                      // cursor currently holds deg
  arr[t] = v0; __syncthreads();
  for (int off = 1; off < 256; off <<= 1){
    int v = (t >= off) ? arr[t - off] : 0;
    __syncthreads();
    arr[t] += v;
    __syncthreads();
  }
  int exc = arr[t] - v0 + bsum[blockIdx.x];
  row_ptr[i] = exc;
  cursor[i]  = exc;
  if (i == 0) row_ptr[NN] = EE;
}
__global__ void k_scatter(const int* __restrict__ src, const int* __restrict__ dst,
                          int* __restrict__ cursor, int* __restrict__ col){
  int e = blockIdx.x * 256 + threadIdx.x;
  int idx = atomicAdd(&cursor[dst[e]], 1);
  col[idx] = src[e];
}

// ---------------- centers: normalize + distance ----------------
__global__ void k_setup(const float* __restrict__ centers, float* __restrict__ cn,
                        float* __restrict__ dist_out){
  __shared__ float red[128];
  int t = threadIdx.x;
  for (int l = 0; l < 4; ++l){
    float v = centers[l*128 + t];
    red[t] = v * v; __syncthreads();
    for (int s = 64; s; s >>= 1){ if (t < s) red[t] += red[t + s]; __syncthreads(); }
    float nrm = sqrtf(red[0]);
    __syncthreads();
    cn[l*128 + t] = v / fmaxf(nrm, 1e-8f);
  }
  const int iu0[6] = {0,0,0,1,1,2}, iu1[6] = {1,2,3,2,3,3};
  __shared__ float dv[6];
  for (int p = 0; p < 6; ++p){
    float d = centers[iu0[p]*128 + t] - centers[iu1[p]*128 + t];
    red[t] = d * d; __syncthreads();
    for (int s = 64; s; s >>= 1){ if (t < s) red[t] += red[t + s]; __syncthreads(); }
    if (!t) dv[p] = sqrtf(red[0]);
    __syncthreads();
  }
  if (!t){
    float mean = 0.f;
    for (int p = 0; p < 6; ++p) mean += dv[p];
    mean /= 6.f;
    float var = 0.f;
    for (int p = 0; p < 6; ++p){ float d = dv[p] - mean; var += d * d; }
    var /= 5.f;                              // ddof=1
    dist_out[0] = -var;
  }
}

// ---------------- pos-enc tables ----------------
__global__ void k_pe(const float* __restrict__ projb, float* __restrict__ peb){
  int p = blockIdx.x, t = threadIdx.x;     // 1000 x 128
  float ex  = (float)(t >> 1) * (-2.0f * 9.210340371976184f / 128.0f);
  float ang = (float)p * expf(ex);
  float v = (t & 1) ? cosf(ang) : sinf(ang);
  peb[p*128 + t] = v + projb[t];
}
__global__ void k_pew(const float* __restrict__ peb, const float* __restrict__ Wih,
                      const float* __restrict__ bih, float* __restrict__ pew){
  int p = blockIdx.x;                       // 1000
  int j = blockIdx.y * 128 + threadIdx.x;   // 384
  const float* pb = peb + p*128;
  const float* wr = Wih + (size_t)j*128;
  float acc = bih[j];
  #pragma unroll 4
  for (int m = 0; m < 128; ++m) acc += pb[m] * wr[m];
  pew[(size_t)p*384 + j] = acc;
}
__global__ void k_combw(const float* __restrict__ projW, const float* __restrict__ Wih,
                        float* __restrict__ cw){
  int kk = blockIdx.x;                      // 128
  int j  = blockIdx.y * 128 + threadIdx.x;  // 384
  const float* pr = projW + (size_t)kk*128;
  const float* wr = Wih + (size_t)j*128;
  float acc = 0.f;
  #pragma unroll 4
  for (int m = 0; m < 128; ++m) acc += pr[m] * wr[m];
  cw[(size_t)kk*384 + j] = acc;
}
// pack Whh rows as f16x2 along k: wt[j*64 + kp] = (f16(W[j][2kp+1])<<16)|f16(W[j][2kp])
__global__ void k_packwhh16(const float* __restrict__ Whh, u32* __restrict__ wt){
  int kp = blockIdx.x;                      // 64
  int j  = blockIdx.y * 128 + threadIdx.x;  // 384
  _Float16 a = (_Float16)Whh[(size_t)j*128 + 2*kp];
  _Float16 b = (_Float16)Whh[(size_t)j*128 + 2*kp + 1];
  u32 lo = (u32)__builtin_bit_cast(u16, a);
  u32 hi = (u32)__builtin_bit_cast(u16, b);
  wt[(size_t)j*64 + kp] = (hi << 16) | lo;
}

// ---------------- tiled f32 GEMM: 64-row tiles, 4x8 acc, K staged in 2 halves ------
// LDS = 32KB (Wl) + 33.8KB (Xl) = 65.8KB -> 2 blocks/CU.
__global__ __launch_bounds__(256) void k_gemm(
    const float* __restrict__ X, const float* __restrict__ W, int ldw,
    const float* __restrict__ bias, const float* __restrict__ pew,
    const int* __restrict__ pos, float* __restrict__ out,
    u16* __restrict__ outb, int ldo){
  __shared__ __align__(16) float Wl[64*128];
  __shared__ __align__(16) float Xl[64*132];
  int tid = threadIdx.x;
  int rb = blockIdx.x * 64;
  int cb = blockIdx.y * 128;
  for (int idx = tid; idx < 64*32; idx += 256){
    int r = idx >> 5, c4 = idx & 31;
    *(float4*)&Xl[r*132 + c4*4] = *(const float4*)&X[(size_t)(rb + r)*128 + c4*4];
  }
  int rg = tid >> 4, cg = tid & 15;
  float acc[4][8];
  #pragma unroll
  for (int a = 0; a < 4; ++a)
    #pragma unroll
    for (int b = 0; b < 8; ++b) acc[a][b] = 0.f;
  for (int half = 0; half < 2; ++half){
    __syncthreads();
    for (int idx = tid; idx < 64*32; idx += 256){
      int kk = idx >> 5, c4 = idx & 31;
      *(float4*)&Wl[kk*128 + c4*4] =
          *(const float4*)&W[(size_t)(half*64 + kk)*ldw + cb + c4*4];
    }
    __syncthreads();
    #pragma unroll 4
    for (int kk = 0; kk < 64; ++kk){
      float4 wa = *(const float4*)&Wl[kk*128 + cg*8];
      float4 wb = *(const float4*)&Wl[kk*128 + cg*8 + 4];
      #pragma unroll
      for (int rr = 0; rr < 4; ++rr){
        float xv = Xl[(rg*4 + rr)*132 + half*64 + kk];
        acc[rr][0] += xv * wa.x; acc[rr][1] += xv * wa.y;
        acc[rr][2] += xv * wa.z; acc[rr][3] += xv * wa.w;
        acc[rr][4] += xv * wb.x; acc[rr][5] += xv * wb.y;
        acc[rr][6] += xv * wb.z; acc[rr][7] += xv * wb.w;
      }
    }
  }
  #pragma unroll
  for (int rr = 0; rr < 4; ++rr){
    int r = rb + rg*4 + rr;
    float bv[8];
    if (pos){
      const float* pw = pew + (size_t)pos[r]*384 + cb + cg*8;
      #pragma unroll
      for (int j = 0; j < 8; ++j) bv[j] = pw[j];
    } else {
      #pragma unroll
      for (int j = 0; j < 8; ++j) bv[j] = bias[cb + cg*8 + j];
    }
    if (outb){
      u16* op = outb + (size_t)r*ldo + cb + cg*8;
      #pragma unroll
      for (int j = 0; j < 8; ++j) op[j] = (u16)bf16rne(acc[rr][j] + bv[j]);
    } else {
      float* op = out + (size_t)r*ldo + cb + cg*8;
      #pragma unroll
      for (int j = 0; j < 8; ++j) op[j] = acc[rr][j] + bv[j];
    }
  }
}

// ---------------- edge phase 1: logits + per-dst max (4 dst per block) ----------------
__global__ __launch_bounds__(256) void k_logits(
    const float* __restrict__ q, const float* __restrict__ k,
    const int* __restrict__ row_ptr, const int* __restrict__ col,
    float* __restrict__ elog, float* __restrict__ rmax){
  int d = blockIdx.x * 4 + (threadIdx.x >> 6);
  int lane = threadIdx.x & 63;
  int e0 = row_ptr[d], e1 = row_ptr[d+1];
  if (e0 == e1) return;
  float2 qv = *(const float2*)&q[(size_t)d*128 + 2*lane];
  float m = -INFINITY;
  for (int e = e0; e < e1; ++e){
    int s = col[e];
    float2 kv = *(const float2*)&k[(size_t)s*128 + 2*lane];
    float p = qv.x * kv.x + qv.y * kv.y;
    p = wredf(p) * 0.08838834764831845f;   // 1/sqrt(128)
    if (lane == 0) elog[e] = p;
    m = fmaxf(m, p);
  }
  if (lane == 0) rmax[d] = m;
}

// ---------------- edge phase 2: softmax-weighted aggregation ----------------
__global__ __launch_bounds__(256) void k_agg(
    const float* __restrict__ v, const int* __restrict__ row_ptr,
    const int* __restrict__ col, const float* __restrict__ elog,
    const float* __restrict__ rmax, float* __restrict__ h2){
  int d = blockIdx.x * 4 + (threadIdx.x >> 6);
  int lane = threadIdx.x & 63;
  int e0 = row_ptr[d], e1 = row_ptr[d+1];
  if (e0 == e1) return;                    // h2 keeps skip value
  float m = rmax[d];
  float ssum = 0.f, a0 = 0.f, a1 = 0.f;
  for (int e = e0; e < e1; ++e){
    int s = col[e];
    float el = expf(elog[e] - m);
    float2 vv = *(const float2*)&v[(size_t)s*128 + 2*lane];
    ssum += el;
    a0 += el * vv.x;
    a1 += el * vv.y;
  }
  float inv = 1.f / ssum;
  float2 hv = *(float2*)&h2[(size_t)d*128 + 2*lane];
  hv.x += a0 * inv;
  hv.y += a1 * inv;
  *(float2*)&h2[(size_t)d*128 + 2*lane] = hv;
}

// ---------------- relu(layernorm) per row ----------------
__global__ __launch_bounds__(256) void k_lnrelu(
    const float* __restrict__ in, const float* __restrict__ g,
    const float* __restrict__ b, float* __restrict__ outp){
  int node = blockIdx.x * 4 + (threadIdx.x >> 6);
  int lane = threadIdx.x & 63;
  float x0 = in[(size_t)node*128 + 2*lane], x1 = in[(size_t)node*128 + 2*lane + 1];
  float s = wredf(x0 + x1);
  float qq = wredf(x0*x0 + x1*x1);
  float mu = s * 0.0078125f;
  float var = qq * 0.0078125f - mu*mu;
  float rstd = rsqrtf(var + 1e-5f);
  float y0 = (x0 - mu)*rstd*g[2*lane]   + b[2*lane];
  float y1 = (x1 - mu)*rstd*g[2*lane+1] + b[2*lane+1];
  outp[(size_t)node*128 + 2*lane]     = fmaxf(y0, 0.f);
  outp[(size_t)node*128 + 2*lane + 1] = fmaxf(y1, 0.f);
}

// ---------------- cluster assignment ----------------
__global__ __launch_bounds__(256) void k_classify(
    const float* __restrict__ h, const float* __restrict__ cn,
    const int* __restrict__ batch, const int* __restrict__ callsq,
    int* __restrict__ grp, int* __restrict__ inv){
  int node = blockIdx.x * 4 + (threadIdx.x >> 6);
  int lane = threadIdx.x & 63;
  float h0 = h[(size_t)node*128 + 2*lane], h1 = h[(size_t)node*128 + 2*lane + 1];
  float p0 = h0*cn[      2*lane] + h1*cn[      2*lane+1];
  float p1 = h0*cn[128 + 2*lane] + h1*cn[128 + 2*lane+1];
  float p2 = h0*cn[256 + 2*lane] + h1*cn[256 + 2*lane+1];
  float p3 = h0*cn[384 + 2*lane] + h1*cn[384 + 2*lane+1];
  p0 = wredf(p0); p1 = wredf(p1); p2 = wredf(p2); p3 = wredf(p3);
  if (lane == 0){
    float best = p0; int bi = 0;
    if (p1 > best){ best = p1; bi = 1; }
    if (p2 > best){ best = p2; bi = 2; }
    if (p3 > best){ best = p3; bi = 3; }
    grp[node] = batch[node]*4 + bi;
    inv[callsq[node]] = node;
  }
}

// ---------------- grouping: chunked multisplit ----------------
__global__ __launch_bounds__(256) void k_g1(const int* __restrict__ inv,
                                            const int* __restrict__ grp,
                                            int* __restrict__ ch){
  __shared__ int hist[GG];
  int c = blockIdx.x, t = threadIdx.x;
  hist[t] = 0; hist[t + 256] = 0;
  __syncthreads();
  int g = grp[inv[c*256 + t]];
  atomicAdd(&hist[g], 1);
  __syncthreads();
  ch[c*GG + t] = hist[t];
  ch[c*GG + 256 + t] = hist[256 + t];
}
__global__ void k_g2(int* __restrict__ ch, int* __restrict__ cnt){
  int g = threadIdx.x;   // 512
  int run = 0;
  for (int c = 0; c < NCHUNK; ++c){
    int idx = c*GG + g;
    int t = ch[idx];
    ch[idx] = run;
    run += t;
  }
  cnt[g] = run;
}
__global__ __launch_bounds__(256) void k_g3(
    const int* __restrict__ inv, const int* __restrict__ grp,
    const int* __restrict__ ch, int* __restrict__ pos, int* __restrict__ gn){
  __shared__ int hist[GG];
  int c = blockIdx.x, t = threadIdx.x;
  hist[t] = 0; hist[t + 256] = 0;
  __syncthreads();
  int node = inv[c*256 + t];
  int g = grp[node];
  int lane = t & 63, w = t >> 6;
  int before = 0, total = 0;
  for (int j = 0; j < 64; ++j){
    int gj = __shfl(g, j);
    if (gj == g){ total++; if (j < lane) before++; }
  }
  int base = 0;
  for (int wv = 0; wv < 4; ++wv){
    if (w == wv){
      base = hist[g];
      if (before == total - 1) hist[g] = base + total;  // last lane of its g
    }
    __syncthreads();
  }
  int p = ch[c*GG + g] + base + before;
  pos[node] = p;
  gn[(size_t)g*SMAX + p] = node;
}

// ---------------- GRU v5: amdgpu_waves_per_eu(2,2) so weights stay in VGPRs -------
// Grid is 512 blocks = 2 blocks/CU = 2 waves/SIMD: occupancy beyond 2 waves/EU is
// unreachable, so force the allocator to budget 256 VGPRs (min=max=2 waves/EU).
// Block = 256 threads = 1 group; j = t>>1, kh = t&1 owns k-half.
// Weights: 3 gates x 8 uint4 = 96 VGPRs, loaded once and PINNED via asm.
__global__ __launch_bounds__(256)
__attribute__((amdgpu_waves_per_eu(2, 2)))
void k_gru(
    const u16* __restrict__ gi, const u32* __restrict__ wt,
    const float* __restrict__ bhh, const float* __restrict__ sg,
    const float* __restrict__ sb, const int* __restrict__ gn,
    const int* __restrict__ cnt, u16* __restrict__ node_out){
  __shared__ __align__(16) u16 hb16[2][128];   // double-buffered h (f16)
  __shared__ float redS[2][4], redQ[2][4];
  int t = threadIdx.x;
  int j = t >> 1;              // output index 0..127
  int kh = t & 1;              // k-half 0/1
  int wv = t >> 6, lane = t & 63;
  int g = blockIdx.x;
  int my = cnt[g];
  if (my <= 1) return;
  // ---- load per-thread weight rows into registers (once), then pin ----
  uint4 wr_[8], wz_[8], wn_[8];
  {
    const uint4* wt4 = (const uint4*)wt;
    size_t b0 = (size_t)(0*128 + j)*16 + kh*8;
    size_t b1 = (size_t)(1*128 + j)*16 + kh*8;
    size_t b2 = (size_t)(2*128 + j)*16 + kh*8;
    #pragma unroll
    for (int s = 0; s < 8; ++s){
      wr_[s] = wt4[b0 + s];
      wz_[s] = wt4[b1 + s];
      wn_[s] = wt4[b2 + s];
    }
    #pragma unroll
    for (int s = 0; s < 8; ++s){
      PIN4(wr_[s]); PIN4(wz_[s]); PIN4(wn_[s]);
    }
  }
  if (t < 128) hb16[0][t] = 0;
  __syncthreads();
  float br = bhh[j], bz = bhh[128 + j], bn = bhh[256 + j];
  float gmul = sg[j], gadd = sb[j];
  const int* gnr = gn + (size_t)g*SMAX;
  float hprev = 0.f;
  int node = gnr[0];
  const u16* gir0 = gi + (size_t)node*384;
  float pxr = bf2f(gir0[j]), pxz = bf2f(gir0[128 + j]), pxn = bf2f(gir0[256 + j]);
  for (int p = 0; p < my; ++p){
    int cur = p & 1, nxt = cur ^ 1;
    float xr = pxr, xz = pxz, xn = pxn;
    int nodeN = gnr[min(p + 1, my - 1)];
    const u16* girN = gi + (size_t)nodeN*384;
    pxr = bf2f(girN[j]); pxz = bf2f(girN[128 + j]); pxn = bf2f(girN[256 + j]);
    const uint4* HB = (const uint4*)&hb16[cur][0];
    uint4 hh[8];
    #pragma unroll
    for (int s = 0; s < 8; ++s) hh[s] = HB[kh*8 + s];
    float ar = 0.f, az = 0.f, an = 0.f;
    #pragma unroll
    for (int s = 0; s < 8; ++s){
      ar = dot2f(wr_[s].x, hh[s].x, ar); az = dot2f(wz_[s].x, hh[s].x, az); an = dot2f(wn_[s].x, hh[s].x, an);
      ar = dot2f(wr_[s].y, hh[s].y, ar); az = dot2f(wz_[s].y, hh[s].y, az); an = dot2f(wn_[s].y, hh[s].y, an);
      ar = dot2f(wr_[s].z, hh[s].z, ar); az = dot2f(wz_[s].z, hh[s].z, az); an = dot2f(wn_[s].z, hh[s].z, an);
      ar = dot2f(wr_[s].w, hh[s].w, ar); az = dot2f(wz_[s].w, hh[s].w, az); an = dot2f(wn_[s].w, hh[s].w, an);
    }
    // pair-reduce k-halves (partner = lane^1), then add bias
    ar += __shfl_xor(ar, 1); az += __shfl_xor(az, 1); an += __shfl_xor(an, 1);
    ar += br; az += bz; an += bn;
    float r = 1.f / (1.f + expf(-(xr + ar)));
    float z = 1.f / (1.f + expf(-(xz + az)));
    float n = tanhf(xn + r * an);
    float hnew = (1.f - z) * n + z * hprev;
    hprev = hnew;
    if (!kh){
      _Float16 hf = (_Float16)hnew;
      hb16[nxt][j] = __builtin_bit_cast(u16, hf);   // write NEXT buffer
    }
    float s_ = kh ? 0.f : hnew;
    float q_ = kh ? 0.f : hnew * hnew;
    #pragma unroll
    for (int o = 32; o; o >>= 1){ s_ += __shfl_xor(s_, o); q_ += __shfl_xor(q_, o); }
    if (lane == 0){ redS[cur][wv] = s_; redQ[cur][wv] = q_; }
    __syncthreads();            // single barrier: h[nxt] + red[cur] now visible
    if (!kh){
      float S = redS[cur][0] + redS[cur][1] + redS[cur][2] + redS[cur][3];
      float Q = redQ[cur][0] + redQ[cur][1] + redQ[cur][2] + redQ[cur][3];
      float mu  = S * 0.0078125f;
      float var = Q * 0.0078125f - mu*mu;
      float rstd = rsqrtf(var + 1e-5f);
      float o = (hnew - mu) * rstd * gmul + gadd;
      node_out[(size_t)node*128 + j] = (u16)bf16rne(fmaxf(o, 0.f));
    }
    node = nodeN;
  }
}

// ---------------- head: gelu(lin1) -> sigmoid(lin2) ----------------
__global__ __launch_bounds__(256) void k_head(
    const float* __restrict__ h, const u16* __restrict__ node_out,
    const int* __restrict__ grp, const int* __restrict__ cnt,
    const float* __restrict__ l1W, const float* __restrict__ l1b,
    const float* __restrict__ l2W, const float* __restrict__ l2b,
    float* __restrict__ out){
  int node = blockIdx.x * 4 + (threadIdx.x >> 6);
  int lane = threadIdx.x & 63;
  bool single = (cnt[grp[node]] == 1);
  float x0, x1;
  if (single){
    x0 = h[(size_t)node*128 + 2*lane];
    x1 = h[(size_t)node*128 + 2*lane + 1];
  } else {
    x0 = bf2f(node_out[(size_t)node*128 + 2*lane]);
    x1 = bf2f(node_out[(size_t)node*128 + 2*lane + 1]);
  }
  float acc[8];
  #pragma unroll
  for (int j = 0; j < 8; ++j)
    acc[j] = x0 * l1W[(2*lane)*8 + j] + x1 * l1W[(2*lane + 1)*8 + j];
  #pragma unroll
  for (int o = 32; o; o >>= 1)
    #pragma unroll
    for (int j = 0; j < 8; ++j) acc[j] += __shfl_xor(acc[j], o);
  if (lane == 0){
    float zz = l2b[0];
    #pragma unroll
    for (int j = 0; j < 8; ++j){
      float xx = acc[j] + l1b[j];
      float ge = 0.5f * xx * (1.f + erff(xx * 0.7071067811865476f));
      zz += ge * l2W[j];
    }
    out[node] = 1.f / (1.f + expf(-zz));
  }
}

extern "C" void kernel_launch(void* const* d_in, const int* in_sizes, int n_in,
                              void* d_out, int out_size, void* d_ws, size_t ws_size,
                              hipStream_t stream){
  float* out = (float*)d_out;

  // ---- ws-size guard: encode ws MB into output instead of faulting ----
  if (ws_size < WS_NEEDED){
    float code = -(float)(ws_size >> 20);
    k_sentinel<<<(out_size + 255)/256, 256, 0, stream>>>(out, out_size, code);
    return;
  }

  const float* x       = (const float*)d_in[0];
  const int*   tei     = (const int*)d_in[1];
  const int*   callsq  = (const int*)d_in[2];
  const int*   batch   = (const int*)d_in[3];
  const float* Wq      = (const float*)d_in[4];
  const float* bq      = (const float*)d_in[5];
  const float* Wk      = (const float*)d_in[6];
  const float* bk      = (const float*)d_in[7];
  const float* Wv      = (const float*)d_in[8];
  const float* bv      = (const float*)d_in[9];
  const float* Wsk     = (const float*)d_in[10];
  const float* bsk     = (const float*)d_in[11];
  const float* lng     = (const float*)d_in[12];
  const float* lnb     = (const float*)d_in[13];
  const float* centers = (const float*)d_in[14];
  const float* projW   = (const float*)d_in[15];
  const float* projb   = (const float*)d_in[16];
  const float* Wih     = (const float*)d_in[17];
  const float* Whh     = (const float*)d_in[18];
  const float* bih     = (const float*)d_in[19];
  const float* bhh     = (const float*)d_in[20];
  const float* sqg     = (const float*)d_in[21];
  const float* sqb     = (const float*)d_in[22];
  const float* l1W     = (const float*)d_in[23];
  const float* l1b     = (const float*)d_in[24];
  const float* l2W     = (const float*)d_in[25];
  const float* l2b     = (const float*)d_in[26];

  float* wf = (float*)d_ws;
  float* f_h    = wf + F_H;
  float* f_a    = wf + F_A;
  float* f_b    = wf + F_B;
  float* f_elog = wf + F_ELOG;
  float* f_rmax = wf + F_RMAX;
  float* f_cn   = wf + F_CN;
  float* f_cw   = wf + F_CW;
  float* f_pew  = wf + F_PEW;
  float* f_peb  = wf + F_PEB;
  u16*   gi_bf  = (u16*)(wf + F_A);      // N x 384 bf16 (overlay, post-conv)
  u16*   no_bf  = (u16*)(wf + F_NODE);   // N x 128 bf16 node_out (overlay)
  int* wi = (int*)(wf + F_END);
  int* i_rowp = wi + I_ROWP;
  int* i_cur  = wi + I_CUR;
  int* i_col  = wi + I_COL;
  int* i_grp  = wi + I_GRP;
  int* i_inv  = wi + I_INV;
  int* i_pos  = wi + I_POS;
  int* i_gn   = wi + I_GN;
  int* i_cnt  = wi + I_CNT;
  int* i_ch   = wi + I_CH;
  int* i_bs   = wi + I_BS;
  u32* i_wt   = (u32*)(wi + I_WT);

  const int* esrc = tei;
  const int* edst = tei + EE;

  // CSR build
  k_zero<<<NN/256, 256, 0, stream>>>(i_cur);
  k_hist<<<EE/256, 256, 0, stream>>>(edst, i_cur);
  k_s1<<<NCHUNK, 256, 0, stream>>>(i_cur, i_bs);
  k_s2<<<1, 512, 0, stream>>>(i_bs);
  k_s3<<<NCHUNK, 256, 0, stream>>>(i_bs, i_rowp, i_cur);
  k_scatter<<<EE/256, 256, 0, stream>>>(esrc, edst, i_cur, i_col);

  // centers, PE tables, combined weights, packed f16 Whh rows
  k_setup<<<1, 128, 0, stream>>>(centers, f_cn, out + NN);
  k_pe<<<1000, 128, 0, stream>>>(projb, f_peb);
  k_pew<<<dim3(1000, 3), 128, 0, stream>>>(f_peb, Wih, bih, f_pew);
  k_combw<<<dim3(128, 3), 128, 0, stream>>>(projW, Wih, f_cw);
  k_packwhh16<<<dim3(64, 3), 128, 0, stream>>>(Whh, i_wt);

  // 3x TransformerConv + relu(LN); A/B ping-pong keeps peak mem at 2 buffers
  for (int i = 0; i < 3; ++i){
    const float* xin = i ? f_h : x;
    size_t wo = (size_t)i * 128 * 128, bo = (size_t)i * 128;
    k_gemm<<<dim3(NN/64, 1), 256, 0, stream>>>(xin, Wq + wo, 128, bq + bo, nullptr, nullptr, f_a, nullptr, 128);
    k_gemm<<<dim3(NN/64, 1), 256, 0, stream>>>(xin, Wk + wo, 128, bk + bo, nullptr, nullptr, f_b, nullptr, 128);
    k_logits<<<NN/4, 256, 0, stream>>>(f_a, f_b, i_rowp, i_col, f_elog, f_rmax);
    k_gemm<<<dim3(NN/64, 1), 256, 0, stream>>>(xin, Wv + wo, 128, bv + bo, nullptr, nullptr, f_a, nullptr, 128);
    k_gemm<<<dim3(NN/64, 1), 256, 0, stream>>>(xin, Wsk + wo, 128, bsk + bo, nullptr, nullptr, f_b, nullptr, 128);
    k_agg<<<NN/4, 256, 0, stream>>>(f_a, i_rowp, i_col, f_elog, f_rmax, f_b);
    k_lnrelu<<<NN/4, 256, 0, stream>>>(f_b, lng + bo, lnb + bo, f_h);
  }

  // cluster assignment + grouping
  k_classify<<<NN/4, 256, 0, stream>>>(f_h, f_cn, batch, callsq, i_grp, i_inv);
  k_g1<<<NCHUNK, 256, 0, stream>>>(i_inv, i_grp, i_ch);
  k_g2<<<1, 512, 0, stream>>>(i_ch, i_cnt);
  k_g3<<<NCHUNK, 256, 0, stream>>>(i_inv, i_grp, i_ch, i_pos, i_gn);

  // gi = h @ (projW@Wih^T) + PEW[pos]  -> bf16 overlay on A (+ part of B)
  k_gemm<<<dim3(NN/64, 3), 256, 0, stream>>>(f_h, f_cw, 384, nullptr, f_pew, i_pos, nullptr, gi_bf, 384);

  // GRU + LN + ReLU -> node_out (bf16, tail of B); 1 group per block
  k_gru<<<GG, 256, 0, stream>>>(gi_bf, i_wt, bhh, sqg, sqb, i_gn, i_cnt, no_bf);

  // head
  k_head<<<NN/4, 256, 0, stream>>>(f_h, no_bf, i_grp, i_cnt, l1W, l1b, l2W, l2b, out);
}

// Round 9
// 3749.243 us; speedup vs baseline: 1.7933x; 1.1211x over previous
//
#include <hip/hip_runtime.h>

#define NN 128000
#define EE 1024000
#define HH 128
#define GG 512
#define SMAX 1000
#define NCHUNK 500   // 500 * 256 = 128000

typedef unsigned int u32;
typedef unsigned short u16;

// ---------------- workspace layout (floats, then ints) ----------------
// ws budget measured round 3: 256 MiB. This layout: 213.3 MiB.
constexpr size_t NH     = (size_t)NN*HH;              // 16,384,000
constexpr size_t F_H    = 0;                          // h (persist, f32)
constexpr size_t F_A    = NH;                         // work A: q / v
constexpr size_t F_B    = 2*NH;                       // work B: k / skip+agg
constexpr size_t F_NODE = F_A + (size_t)NN*192;       // bf16 node_out overlay
constexpr size_t F_ELOG = 3*NH;                       // E edge logits
constexpr size_t F_RMAX = F_ELOG + EE;                // N per-dst max
constexpr size_t F_CN   = F_RMAX + NN;                // 4*128 normalized centers
constexpr size_t F_CW   = F_CN   + 512;               // 128*384 projW@Wih^T
constexpr size_t F_PEW  = F_CW   + 128*384;           // 1000*384 (pe+projb)@Wih^T + bih
constexpr size_t F_PEB  = F_PEW  + 1000*384;          // 1000*128 pe + projb
constexpr size_t F_END  = F_PEB  + 1000*128;

constexpr size_t I_ROWP = 0;                          // N+8 CSR row ptr
constexpr size_t I_CUR  = I_ROWP + NN + 8;
constexpr size_t I_COL  = I_CUR  + NN;                // E
constexpr size_t I_GRP  = I_COL  + EE;
constexpr size_t I_INV  = I_GRP  + NN;
constexpr size_t I_POS  = I_INV  + NN;
constexpr size_t I_GN   = I_POS  + NN;                // 512*1000
constexpr size_t I_CNT  = I_GN   + (size_t)GG*SMAX;
constexpr size_t I_CH   = I_CNT  + GG;                // 500*512
constexpr size_t I_BS   = I_CH   + (size_t)NCHUNK*GG;
constexpr size_t I_WT   = I_BS   + 512;               // 384*64 packed f16 Whh^T rows
constexpr size_t I_END  = I_WT   + 64*384;

constexpr size_t WS_NEEDED = F_END*4 + I_END*4;       // 213,293,088 B

__device__ inline float wredf(float v){
  #pragma unroll
  for (int o = 32; o; o >>= 1) v += __shfl_xor(v, o);
  return v;
}
__device__ inline u32 bf16rne(float f){
  u32 u = __float_as_uint(f);
  return (u + 0x7fffu + ((u >> 16) & 1u)) >> 16;
}
__device__ inline float bf2f(u16 u){
  return __uint_as_float(((u32)u) << 16);
}
__device__ inline float frcp(float x){
#if __has_builtin(__builtin_amdgcn_rcpf)
  return __builtin_amdgcn_rcpf(x);
#else
  return 1.f / x;
#endif
}

typedef _Float16 h2_t __attribute__((ext_vector_type(2)));
__device__ inline float dot2f(u32 w, u32 h, float acc){
#if __has_builtin(__builtin_amdgcn_fdot2)
  return __builtin_amdgcn_fdot2(__builtin_bit_cast(h2_t, w),
                                __builtin_bit_cast(h2_t, h), acc, false);
#else
  float r;
  asm("v_dot2_f32_f16 %0, %1, %2, %3" : "=v"(r) : "v"(w), "v"(h), "v"(acc));
  return r;
#endif
}
// pin a uint4 into VGPRs: compiler can no longer rematerialize the load
#define PIN4(v) asm volatile("" : "+v"((v).x), "+v"((v).y), "+v"((v).z), "+v"((v).w))

// ---------------- ws-size diagnostic sentinel ----------------
__global__ void k_sentinel(float* __restrict__ out, int n, float val){
  int i = blockIdx.x * 256 + threadIdx.x;
  if (i < n) out[i] = val;
}

// ---------------- CSR build ----------------
__global__ void k_zero(int* __restrict__ p){
  p[blockIdx.x * 256 + threadIdx.x] = 0;
}
__global__ void k_hist(const int* __restrict__ dst, int* __restrict__ deg){
  int e = blockIdx.x * 256 + threadIdx.x;
  atomicAdd(&deg[dst[e]], 1);
}
__global__ void k_s1(const int* __restrict__ deg, int* __restrict__ bsum){
  __shared__ int red[256];
  int t = threadIdx.x;
  red[t] = deg[blockIdx.x * 256 + t];
  __syncthreads();
  for (int s = 128; s; s >>= 1){ if (t < s) red[t] += red[t + s]; __syncthreads(); }
  if (!t) bsum[blockIdx.x] = red[0];
}
__global__ void k_s2(int* __restrict__ bsum){
  __shared__ int arr[512];
  int t = threadIdx.x;
  int v0 = (t < NCHUNK) ? bsum[t] : 0;
  arr[t] = v0; __syncthreads();
  for (int off = 1; off < 512; off <<= 1){
    int v = (t >= off) ? arr[t - off] : 0;
    __syncthreads();
    arr[t] += v;
    __syncthreads();
  }
  if (t < NCHUNK) bsum[t] = arr[t] - v0;   // exclusive
}
__global__ void k_s3(const int* __restrict__ bsum, int* __restrict__ row_ptr,
                     int* __restrict__ cursor){
  __shared__ int arr[256];
  int t = threadIdx.x;
  int i = blockIdx.x * 256 + t;
  int v0 = cursor[i];                      // cursor currently holds deg
  arr[t] = v0; __syncthreads();
  for (int off = 1; off < 256; off <<= 1){
    int v = (t >= off) ? arr[t - off] : 0;
    __syncthreads();
    arr[t] += v;
    __syncthreads();
  }
  int exc = arr[t] - v0 + bsum[blockIdx.x];
  row_ptr[i] = exc;
  cursor[i]  = exc;
  if (i == 0) row_ptr[NN] = EE;
}
__global__ void k_scatter(const int* __restrict__ src, const int* __restrict__ dst,
                          int* __restrict__ cursor, int* __restrict__ col){
  int e = blockIdx.x * 256 + threadIdx.x;
  int idx = atomicAdd(&cursor[dst[e]], 1);
  col[idx] = src[e];
}

// ---------------- centers: normalize + distance ----------------
__global__ void k_setup(const float* __restrict__ centers, float* __restrict__ cn,
                        float* __restrict__ dist_out){
  __shared__ float red[128];
  int t = threadIdx.x;
  for (int l = 0; l < 4; ++l){
    float v = centers[l*128 + t];
    red[t] = v * v; __syncthreads();
    for (int s = 64; s; s >>= 1){ if (t < s) red[t] += red[t + s]; __syncthreads(); }
    float nrm = sqrtf(red[0]);
    __syncthreads();
    cn[l*128 + t] = v / fmaxf(nrm, 1e-8f);
  }
  const int iu0[6] = {0,0,0,1,1,2}, iu1[6] = {1,2,3,2,3,3};
  __shared__ float dv[6];
  for (int p = 0; p < 6; ++p){
    float d = centers[iu0[p]*128 + t] - centers[iu1[p]*128 + t];
    red[t] = d * d; __syncthreads();
    for (int s = 64; s; s >>= 1){ if (t < s) red[t] += red[t + s]; __syncthreads(); }
    if (!t) dv[p] = sqrtf(red[0]);
    __syncthreads();
  }
  if (!t){
    float mean = 0.f;
    for (int p = 0; p < 6; ++p) mean += dv[p];
    mean /= 6.f;
    float var = 0.f;
    for (int p = 0; p < 6; ++p){ float d = dv[p] - mean; var += d * d; }
    var /= 5.f;                              // ddof=1
    dist_out[0] = -var;
  }
}

// ---------------- pos-enc tables ----------------
__global__ void k_pe(const float* __restrict__ projb, float* __restrict__ peb){
  int p = blockIdx.x, t = threadIdx.x;     // 1000 x 128
  float ex  = (float)(t >> 1) * (-2.0f * 9.210340371976184f / 128.0f);
  float ang = (float)p * expf(ex);
  float v = (t & 1) ? cosf(ang) : sinf(ang);
  peb[p*128 + t] = v + projb[t];
}
__global__ void k_pew(const float* __restrict__ peb, const float* __restrict__ Wih,
                      const float* __restrict__ bih, float* __restrict__ pew){
  int p = blockIdx.x;                       // 1000
  int j = blockIdx.y * 128 + threadIdx.x;   // 384
  const float* pb = peb + p*128;
  const float* wr = Wih + (size_t)j*128;
  float acc = bih[j];
  #pragma unroll 4
  for (int m = 0; m < 128; ++m) acc += pb[m] * wr[m];
  pew[(size_t)p*384 + j] = acc;
}
__global__ void k_combw(const float* __restrict__ projW, const float* __restrict__ Wih,
                        float* __restrict__ cw){
  int kk = blockIdx.x;                      // 128
  int j  = blockIdx.y * 128 + threadIdx.x;  // 384
  const float* pr = projW + (size_t)kk*128;
  const float* wr = Wih + (size_t)j*128;
  float acc = 0.f;
  #pragma unroll 4
  for (int m = 0; m < 128; ++m) acc += pr[m] * wr[m];
  cw[(size_t)kk*384 + j] = acc;
}
// pack Whh rows as f16x2 along k: wt[j*64 + kp] = (f16(W[j][2kp+1])<<16)|f16(W[j][2kp])
__global__ void k_packwhh16(const float* __restrict__ Whh, u32* __restrict__ wt){
  int kp = blockIdx.x;                      // 64
  int j  = blockIdx.y * 128 + threadIdx.x;  // 384
  _Float16 a = (_Float16)Whh[(size_t)j*128 + 2*kp];
  _Float16 b = (_Float16)Whh[(size_t)j*128 + 2*kp + 1];
  u32 lo = (u32)__builtin_bit_cast(u16, a);
  u32 hi = (u32)__builtin_bit_cast(u16, b);
  wt[(size_t)j*64 + kp] = (hi << 16) | lo;
}

// ---------------- tiled f32 GEMM: 64-row tiles, 4x8 acc, K staged in 2 halves ------
// LDS = 32KB (Wl) + 33.8KB (Xl) = 65.8KB -> 2 blocks/CU.
__global__ __launch_bounds__(256) void k_gemm(
    const float* __restrict__ X, const float* __restrict__ W, int ldw,
    const float* __restrict__ bias, const float* __restrict__ pew,
    const int* __restrict__ pos, float* __restrict__ out,
    u16* __restrict__ outb, int ldo){
  __shared__ __align__(16) float Wl[64*128];
  __shared__ __align__(16) float Xl[64*132];
  int tid = threadIdx.x;
  int rb = blockIdx.x * 64;
  int cb = blockIdx.y * 128;
  for (int idx = tid; idx < 64*32; idx += 256){
    int r = idx >> 5, c4 = idx & 31;
    *(float4*)&Xl[r*132 + c4*4] = *(const float4*)&X[(size_t)(rb + r)*128 + c4*4];
  }
  int rg = tid >> 4, cg = tid & 15;
  float acc[4][8];
  #pragma unroll
  for (int a = 0; a < 4; ++a)
    #pragma unroll
    for (int b = 0; b < 8; ++b) acc[a][b] = 0.f;
  for (int half = 0; half < 2; ++half){
    __syncthreads();
    for (int idx = tid; idx < 64*32; idx += 256){
      int kk = idx >> 5, c4 = idx & 31;
      *(float4*)&Wl[kk*128 + c4*4] =
          *(const float4*)&W[(size_t)(half*64 + kk)*ldw + cb + c4*4];
    }
    __syncthreads();
    #pragma unroll 4
    for (int kk = 0; kk < 64; ++kk){
      float4 wa = *(const float4*)&Wl[kk*128 + cg*8];
      float4 wb = *(const float4*)&Wl[kk*128 + cg*8 + 4];
      #pragma unroll
      for (int rr = 0; rr < 4; ++rr){
        float xv = Xl[(rg*4 + rr)*132 + half*64 + kk];
        acc[rr][0] += xv * wa.x; acc[rr][1] += xv * wa.y;
        acc[rr][2] += xv * wa.z; acc[rr][3] += xv * wa.w;
        acc[rr][4] += xv * wb.x; acc[rr][5] += xv * wb.y;
        acc[rr][6] += xv * wb.z; acc[rr][7] += xv * wb.w;
      }
    }
  }
  #pragma unroll
  for (int rr = 0; rr < 4; ++rr){
    int r = rb + rg*4 + rr;
    float bv[8];
    if (pos){
      const float* pw = pew + (size_t)pos[r]*384 + cb + cg*8;
      #pragma unroll
      for (int j = 0; j < 8; ++j) bv[j] = pw[j];
    } else {
      #pragma unroll
      for (int j = 0; j < 8; ++j) bv[j] = bias[cb + cg*8 + j];
    }
    if (outb){
      u16* op = outb + (size_t)r*ldo + cb + cg*8;
      #pragma unroll
      for (int j = 0; j < 8; ++j) op[j] = (u16)bf16rne(acc[rr][j] + bv[j]);
    } else {
      float* op = out + (size_t)r*ldo + cb + cg*8;
      #pragma unroll
      for (int j = 0; j < 8; ++j) op[j] = acc[rr][j] + bv[j];
    }
  }
}

// ---------------- edge phase 1: logits + per-dst max (4 dst per block) ----------------
__global__ __launch_bounds__(256) void k_logits(
    const float* __restrict__ q, const float* __restrict__ k,
    const int* __restrict__ row_ptr, const int* __restrict__ col,
    float* __restrict__ elog, float* __restrict__ rmax){
  int d = blockIdx.x * 4 + (threadIdx.x >> 6);
  int lane = threadIdx.x & 63;
  int e0 = row_ptr[d], e1 = row_ptr[d+1];
  if (e0 == e1) return;
  float2 qv = *(const float2*)&q[(size_t)d*128 + 2*lane];
  float m = -INFINITY;
  for (int e = e0; e < e1; ++e){
    int s = col[e];
    float2 kv = *(const float2*)&k[(size_t)s*128 + 2*lane];
    float p = qv.x * kv.x + qv.y * kv.y;
    p = wredf(p) * 0.08838834764831845f;   // 1/sqrt(128)
    if (lane == 0) elog[e] = p;
    m = fmaxf(m, p);
  }
  if (lane == 0) rmax[d] = m;
}

// ---------------- edge phase 2: softmax-weighted aggregation ----------------
__global__ __launch_bounds__(256) void k_agg(
    const float* __restrict__ v, const int* __restrict__ row_ptr,
    const int* __restrict__ col, const float* __restrict__ elog,
    const float* __restrict__ rmax, float* __restrict__ h2){
  int d = blockIdx.x * 4 + (threadIdx.x >> 6);
  int lane = threadIdx.x & 63;
  int e0 = row_ptr[d], e1 = row_ptr[d+1];
  if (e0 == e1) return;                    // h2 keeps skip value
  float m = rmax[d];
  float ssum = 0.f, a0 = 0.f, a1 = 0.f;
  for (int e = e0; e < e1; ++e){
    int s = col[e];
    float el = __expf(elog[e] - m);
    float2 vv = *(const float2*)&v[(size_t)s*128 + 2*lane];
    ssum += el;
    a0 += el * vv.x;
    a1 += el * vv.y;
  }
  float inv = 1.f / ssum;
  float2 hv = *(float2*)&h2[(size_t)d*128 + 2*lane];
  hv.x += a0 * inv;
  hv.y += a1 * inv;
  *(float2*)&h2[(size_t)d*128 + 2*lane] = hv;
}

// ---------------- relu(layernorm) per row (f32 in / f32 out) ----------------
__global__ __launch_bounds__(256) void k_lnrelu(
    const float* __restrict__ in, const float* __restrict__ g,
    const float* __restrict__ b, float* __restrict__ outp){
  int node = blockIdx.x * 4 + (threadIdx.x >> 6);
  int lane = threadIdx.x & 63;
  float x0 = in[(size_t)node*128 + 2*lane], x1 = in[(size_t)node*128 + 2*lane + 1];
  float s = wredf(x0 + x1);
  float qq = wredf(x0*x0 + x1*x1);
  float mu = s * 0.0078125f;
  float var = qq * 0.0078125f - mu*mu;
  float rstd = rsqrtf(var + 1e-5f);
  float y0 = (x0 - mu)*rstd*g[2*lane]   + b[2*lane];
  float y1 = (x1 - mu)*rstd*g[2*lane+1] + b[2*lane+1];
  outp[(size_t)node*128 + 2*lane]     = fmaxf(y0, 0.f);
  outp[(size_t)node*128 + 2*lane + 1] = fmaxf(y1, 0.f);
}

// ---------------- post-GRU relu(layernorm) in-place on bf16 node_out ----------------
__global__ __launch_bounds__(256) void k_postln(
    u16* __restrict__ no, const float* __restrict__ g, const float* __restrict__ b){
  int node = blockIdx.x * 4 + (threadIdx.x >> 6);
  int lane = threadIdx.x & 63;
  float x0 = bf2f(no[(size_t)node*128 + 2*lane]);
  float x1 = bf2f(no[(size_t)node*128 + 2*lane + 1]);
  float s = wredf(x0 + x1);
  float qq = wredf(x0*x0 + x1*x1);
  float mu = s * 0.0078125f;
  float var = qq * 0.0078125f - mu*mu;
  float rstd = rsqrtf(var + 1e-5f);
  float y0 = (x0 - mu)*rstd*g[2*lane]   + b[2*lane];
  float y1 = (x1 - mu)*rstd*g[2*lane+1] + b[2*lane+1];
  no[(size_t)node*128 + 2*lane]     = (u16)bf16rne(fmaxf(y0, 0.f));
  no[(size_t)node*128 + 2*lane + 1] = (u16)bf16rne(fmaxf(y1, 0.f));
}

// ---------------- cluster assignment ----------------
__global__ __launch_bounds__(256) void k_classify(
    const float* __restrict__ h, const float* __restrict__ cn,
    const int* __restrict__ batch, const int* __restrict__ callsq,
    int* __restrict__ grp, int* __restrict__ inv){
  int node = blockIdx.x * 4 + (threadIdx.x >> 6);
  int lane = threadIdx.x & 63;
  float h0 = h[(size_t)node*128 + 2*lane], h1 = h[(size_t)node*128 + 2*lane + 1];
  float p0 = h0*cn[      2*lane] + h1*cn[      2*lane+1];
  float p1 = h0*cn[128 + 2*lane] + h1*cn[128 + 2*lane+1];
  float p2 = h0*cn[256 + 2*lane] + h1*cn[256 + 2*lane+1];
  float p3 = h0*cn[384 + 2*lane] + h1*cn[384 + 2*lane+1];
  p0 = wredf(p0); p1 = wredf(p1); p2 = wredf(p2); p3 = wredf(p3);
  if (lane == 0){
    float best = p0; int bi = 0;
    if (p1 > best){ best = p1; bi = 1; }
    if (p2 > best){ best = p2; bi = 2; }
    if (p3 > best){ best = p3; bi = 3; }
    grp[node] = batch[node]*4 + bi;
    inv[callsq[node]] = node;
  }
}

// ---------------- grouping: chunked multisplit ----------------
__global__ __launch_bounds__(256) void k_g1(const int* __restrict__ inv,
                                            const int* __restrict__ grp,
                                            int* __restrict__ ch){
  __shared__ int hist[GG];
  int c = blockIdx.x, t = threadIdx.x;
  hist[t] = 0; hist[t + 256] = 0;
  __syncthreads();
  int g = grp[inv[c*256 + t]];
  atomicAdd(&hist[g], 1);
  __syncthreads();
  ch[c*GG + t] = hist[t];
  ch[c*GG + 256 + t] = hist[256 + t];
}
__global__ void k_g2(int* __restrict__ ch, int* __restrict__ cnt){
  int g = threadIdx.x;   // 512
  int run = 0;
  for (int c = 0; c < NCHUNK; ++c){
    int idx = c*GG + g;
    int t = ch[idx];
    ch[idx] = run;
    run += t;
  }
  cnt[g] = run;
}
__global__ __launch_bounds__(256) void k_g3(
    const int* __restrict__ inv, const int* __restrict__ grp,
    const int* __restrict__ ch, int* __restrict__ pos, int* __restrict__ gn){
  __shared__ int hist[GG];
  int c = blockIdx.x, t = threadIdx.x;
  hist[t] = 0; hist[t + 256] = 0;
  __syncthreads();
  int node = inv[c*256 + t];
  int g = grp[node];
  int lane = t & 63, w = t >> 6;
  int before = 0, total = 0;
  for (int j = 0; j < 64; ++j){
    int gj = __shfl(g, j);
    if (gj == g){ total++; if (j < lane) before++; }
  }
  int base = 0;
  for (int wv = 0; wv < 4; ++wv){
    if (w == wv){
      base = hist[g];
      if (before == total - 1) hist[g] = base + total;  // last lane of its g
    }
    __syncthreads();
  }
  int p = ch[c*GG + g] + base + before;
  pos[node] = p;
  gn[(size_t)g*SMAX + p] = node;
}

// ---------------- GRU v6: no in-loop LN, fast transcendentals, 3-deep prefetch -----
// Block = 256 threads = 1 group; j = t>>1, kh = t&1 owns k-half.
// Raw h_t written bf16 to node_out each step; LN+ReLU deferred to k_postln.
__global__ __launch_bounds__(256)
__attribute__((amdgpu_waves_per_eu(2, 2)))
void k_gru(
    const u16* __restrict__ gi, const u32* __restrict__ wt,
    const float* __restrict__ bhh, const int* __restrict__ gn,
    const int* __restrict__ cnt, u16* __restrict__ node_out){
  __shared__ __align__(16) u16 hb16[2][128];   // double-buffered h (f16)
  int t = threadIdx.x;
  int j = t >> 1;              // output index 0..127
  int kh = t & 1;              // k-half 0/1
  int g = blockIdx.x;
  int my = cnt[g];
  if (my <= 1) return;
  // ---- load per-thread weight rows into registers (once), then pin ----
  uint4 wr_[8], wz_[8], wn_[8];
  {
    const uint4* wt4 = (const uint4*)wt;
    size_t b0 = (size_t)(0*128 + j)*16 + kh*8;
    size_t b1 = (size_t)(1*128 + j)*16 + kh*8;
    size_t b2 = (size_t)(2*128 + j)*16 + kh*8;
    #pragma unroll
    for (int s = 0; s < 8; ++s){
      wr_[s] = wt4[b0 + s];
      wz_[s] = wt4[b1 + s];
      wn_[s] = wt4[b2 + s];
    }
    #pragma unroll
    for (int s = 0; s < 8; ++s){
      PIN4(wr_[s]); PIN4(wz_[s]); PIN4(wn_[s]);
    }
  }
  if (t < 128) hb16[0][t] = 0;
  float br = bhh[j], bz = bhh[128 + j], bn = bhh[256 + j];
  const int* gnr = gn + (size_t)g*SMAX;
  float hprev = 0.f;
  // ---- 3-deep gi prefetch pipeline: A (consume now), B (+1), C (+2) ----
  int nA = gnr[0];
  int nB = gnr[min(1, my - 1)];
  int nC = gnr[min(2, my - 1)];
  const u16* gA = gi + (size_t)nA*384;
  const u16* gB = gi + (size_t)nB*384;
  const u16* gC = gi + (size_t)nC*384;
  float axr = bf2f(gA[j]), axz = bf2f(gA[128 + j]), axn = bf2f(gA[256 + j]);
  float bxr = bf2f(gB[j]), bxz = bf2f(gB[128 + j]), bxn = bf2f(gB[256 + j]);
  float cxr = bf2f(gC[j]), cxz = bf2f(gC[128 + j]), cxn = bf2f(gC[256 + j]);
  __syncthreads();
  for (int p = 0; p < my; ++p){
    int cur = p & 1, nxt = cur ^ 1;
    float xr = axr, xz = axz, xn = axn;
    int node = nA;
    // shift pipeline and issue load for p+3
    axr = bxr; axz = bxz; axn = bxn; nA = nB;
    bxr = cxr; bxz = cxz; bxn = cxn; nB = nC;
    nC = gnr[min(p + 3, my - 1)];
    const u16* gN = gi + (size_t)nC*384;
    cxr = bf2f(gN[j]); cxz = bf2f(gN[128 + j]); cxn = bf2f(gN[256 + j]);
    // h fragment from LDS
    const uint4* HB = (const uint4*)&hb16[cur][0];
    uint4 hh[8];
    #pragma unroll
    for (int s = 0; s < 8; ++s) hh[s] = HB[kh*8 + s];
    float ar = 0.f, az = 0.f, an = 0.f;
    #pragma unroll
    for (int s = 0; s < 8; ++s){
      ar = dot2f(wr_[s].x, hh[s].x, ar); az = dot2f(wz_[s].x, hh[s].x, az); an = dot2f(wn_[s].x, hh[s].x, an);
      ar = dot2f(wr_[s].y, hh[s].y, ar); az = dot2f(wz_[s].y, hh[s].y, az); an = dot2f(wn_[s].y, hh[s].y, an);
      ar = dot2f(wr_[s].z, hh[s].z, ar); az = dot2f(wz_[s].z, hh[s].z, az); an = dot2f(wn_[s].z, hh[s].z, an);
      ar = dot2f(wr_[s].w, hh[s].w, ar); az = dot2f(wz_[s].w, hh[s].w, az); an = dot2f(wn_[s].w, hh[s].w, an);
    }
    // pair-reduce k-halves (partner = lane^1), then add bias
    ar += __shfl_xor(ar, 1); az += __shfl_xor(az, 1); an += __shfl_xor(an, 1);
    ar += br; az += bz; an += bn;
    // fast gates: sigmoid via __expf+rcp, tanh via one __expf
    float er = __expf(-(xr + ar));
    float r  = frcp(1.f + er);
    float ez = __expf(-(xz + az));
    float z  = frcp(1.f + ez);
    float y  = xn + r * an;
    float e2 = __expf(-2.f * y);
    float n  = (1.f - e2) * frcp(1.f + e2);   // tanh(y)
    float hnew = n + z * (hprev - n);
    hprev = hnew;
    if (!kh){
      _Float16 hf = (_Float16)hnew;
      hb16[nxt][j] = __builtin_bit_cast(u16, hf);       // h for next step
      node_out[(size_t)node*128 + j] = (u16)bf16rne(hnew);  // raw h out (LN later)
    }
    __syncthreads();            // h[nxt] visible before next step's reads
  }
}

// ---------------- head: gelu(lin1) -> sigmoid(lin2) ----------------
__global__ __launch_bounds__(256) void k_head(
    const float* __restrict__ h, const u16* __restrict__ node_out,
    const int* __restrict__ grp, const int* __restrict__ cnt,
    const float* __restrict__ l1W, const float* __restrict__ l1b,
    const float* __restrict__ l2W, const float* __restrict__ l2b,
    float* __restrict__ out){
  int node = blockIdx.x * 4 + (threadIdx.x >> 6);
  int lane = threadIdx.x & 63;
  bool single = (cnt[grp[node]] == 1);
  float x0, x1;
  if (single){
    x0 = h[(size_t)node*128 + 2*lane];
    x1 = h[(size_t)node*128 + 2*lane + 1];
  } else {
    x0 = bf2f(node_out[(size_t)node*128 + 2*lane]);
    x1 = bf2f(node_out[(size_t)node*128 + 2*lane + 1]);
  }
  float acc[8];
  #pragma unroll
  for (int j = 0; j < 8; ++j)
    acc[j] = x0 * l1W[(2*lane)*8 + j] + x1 * l1W[(2*lane + 1)*8 + j];
  #pragma unroll
  for (int o = 32; o; o >>= 1)
    #pragma unroll
    for (int j = 0; j < 8; ++j) acc[j] += __shfl_xor(acc[j], o);
  if (lane == 0){
    float zz = l2b[0];
    #pragma unroll
    for (int j = 0; j < 8; ++j){
      float xx = acc[j] + l1b[j];
      float ge = 0.5f * xx * (1.f + erff(xx * 0.7071067811865476f));
      zz += ge * l2W[j];
    }
    out[node] = 1.f / (1.f + expf(-zz));
  }
}

extern "C" void kernel_launch(void* const* d_in, const int* in_sizes, int n_in,
                              void* d_out, int out_size, void* d_ws, size_t ws_size,
                              hipStream_t stream){
  float* out = (float*)d_out;

  // ---- ws-size guard: encode ws MB into output instead of faulting ----
  if (ws_size < WS_NEEDED){
    float code = -(float)(ws_size >> 20);
    k_sentinel<<<(out_size + 255)/256, 256, 0, stream>>>(out, out_size, code);
    return;
  }

  const float* x       = (const float*)d_in[0];
  const int*   tei     = (const int*)d_in[1];
  const int*   callsq  = (const int*)d_in[2];
  const int*   batch   = (const int*)d_in[3];
  const float* Wq      = (const float*)d_in[4];
  const float* bq      = (const float*)d_in[5];
  const float* Wk      = (const float*)d_in[6];
  const float* bk      = (const float*)d_in[7];
  const float* Wv      = (const float*)d_in[8];
  const float* bv      = (const float*)d_in[9];
  const float* Wsk     = (const float*)d_in[10];
  const float* bsk     = (const float*)d_in[11];
  const float* lng     = (const float*)d_in[12];
  const float* lnb     = (const float*)d_in[13];
  const float* centers = (const float*)d_in[14];
  const float* projW   = (const float*)d_in[15];
  const float* projb   = (const float*)d_in[16];
  const float* Wih     = (const float*)d_in[17];
  const float* Whh     = (const float*)d_in[18];
  const float* bih     = (const float*)d_in[19];
  const float* bhh     = (const float*)d_in[20];
  const float* sqg     = (const float*)d_in[21];
  const float* sqb     = (const float*)d_in[22];
  const float* l1W     = (const float*)d_in[23];
  const float* l1b     = (const float*)d_in[24];
  const float* l2W     = (const float*)d_in[25];
  const float* l2b     = (const float*)d_in[26];

  float* wf = (float*)d_ws;
  float* f_h    = wf + F_H;
  float* f_a    = wf + F_A;
  float* f_b    = wf + F_B;
  float* f_elog = wf + F_ELOG;
  float* f_rmax = wf + F_RMAX;
  float* f_cn   = wf + F_CN;
  float* f_cw   = wf + F_CW;
  float* f_pew  = wf + F_PEW;
  float* f_peb  = wf + F_PEB;
  u16*   gi_bf  = (u16*)(wf + F_A);      // N x 384 bf16 (overlay, post-conv)
  u16*   no_bf  = (u16*)(wf + F_NODE);   // N x 128 bf16 node_out (overlay)
  int* wi = (int*)(wf + F_END);
  int* i_rowp = wi + I_ROWP;
  int* i_cur  = wi + I_CUR;
  int* i_col  = wi + I_COL;
  int* i_grp  = wi + I_GRP;
  int* i_inv  = wi + I_INV;
  int* i_pos  = wi + I_POS;
  int* i_gn   = wi + I_GN;
  int* i_cnt  = wi + I_CNT;
  int* i_ch   = wi + I_CH;
  int* i_bs   = wi + I_BS;
  u32* i_wt   = (u32*)(wi + I_WT);

  const int* esrc = tei;
  const int* edst = tei + EE;

  // CSR build
  k_zero<<<NN/256, 256, 0, stream>>>(i_cur);
  k_hist<<<EE/256, 256, 0, stream>>>(edst, i_cur);
  k_s1<<<NCHUNK, 256, 0, stream>>>(i_cur, i_bs);
  k_s2<<<1, 512, 0, stream>>>(i_bs);
  k_s3<<<NCHUNK, 256, 0, stream>>>(i_bs, i_rowp, i_cur);
  k_scatter<<<EE/256, 256, 0, stream>>>(esrc, edst, i_cur, i_col);

  // centers, PE tables, combined weights, packed f16 Whh rows
  k_setup<<<1, 128, 0, stream>>>(centers, f_cn, out + NN);
  k_pe<<<1000, 128, 0, stream>>>(projb, f_peb);
  k_pew<<<dim3(1000, 3), 128, 0, stream>>>(f_peb, Wih, bih, f_pew);
  k_combw<<<dim3(128, 3), 128, 0, stream>>>(projW, Wih, f_cw);
  k_packwhh16<<<dim3(64, 3), 128, 0, stream>>>(Whh, i_wt);

  // 3x TransformerConv + relu(LN); A/B ping-pong keeps peak mem at 2 buffers
  for (int i = 0; i < 3; ++i){
    const float* xin = i ? f_h : x;
    size_t wo = (size_t)i * 128 * 128, bo = (size_t)i * 128;
    k_gemm<<<dim3(NN/64, 1), 256, 0, stream>>>(xin, Wq + wo, 128, bq + bo, nullptr, nullptr, f_a, nullptr, 128);
    k_gemm<<<dim3(NN/64, 1), 256, 0, stream>>>(xin, Wk + wo, 128, bk + bo, nullptr, nullptr, f_b, nullptr, 128);
    k_logits<<<NN/4, 256, 0, stream>>>(f_a, f_b, i_rowp, i_col, f_elog, f_rmax);
    k_gemm<<<dim3(NN/64, 1), 256, 0, stream>>>(xin, Wv + wo, 128, bv + bo, nullptr, nullptr, f_a, nullptr, 128);
    k_gemm<<<dim3(NN/64, 1), 256, 0, stream>>>(xin, Wsk + wo, 128, bsk + bo, nullptr, nullptr, f_b, nullptr, 128);
    k_agg<<<NN/4, 256, 0, stream>>>(f_a, i_rowp, i_col, f_elog, f_rmax, f_b);
    k_lnrelu<<<NN/4, 256, 0, stream>>>(f_b, lng + bo, lnb + bo, f_h);
  }

  // cluster assignment + grouping
  k_classify<<<NN/4, 256, 0, stream>>>(f_h, f_cn, batch, callsq, i_grp, i_inv);
  k_g1<<<NCHUNK, 256, 0, stream>>>(i_inv, i_grp, i_ch);
  k_g2<<<1, 512, 0, stream>>>(i_ch, i_cnt);
  k_g3<<<NCHUNK, 256, 0, stream>>>(i_inv, i_grp, i_ch, i_pos, i_gn);

  // gi = h @ (projW@Wih^T) + PEW[pos]  -> bf16 overlay on A (+ part of B)
  k_gemm<<<dim3(NN/64, 3), 256, 0, stream>>>(f_h, f_cw, 384, nullptr, f_pew, i_pos, nullptr, gi_bf, 384);

  // GRU (raw h out) -> post LN+ReLU in parallel
  k_gru<<<GG, 256, 0, stream>>>(gi_bf, i_wt, bhh, i_gn, i_cnt, no_bf);
  k_postln<<<NN/4, 256, 0, stream>>>(no_bf, sqg, sqb);

  // head
  k_head<<<NN/4, 256, 0, stream>>>(f_h, no_bf, i_grp, i_cnt, l1W, l1b, l2W, l2b, out);
}

// Round 10
// 2902.579 us; speedup vs baseline: 2.3164x; 1.2917x over previous
//
#include <hip/hip_runtime.h>

#define NN 128000
#define EE 1024000
#define HH 128
#define GG 512
#define SMAX 1000
#define NCHUNK 500   // 500 * 256 = 128000

typedef unsigned int u32;
typedef unsigned short u16;

// ---------------- workspace layout (floats, then ints) ----------------
// ws budget measured round 3: 256 MiB. This layout: 213.3 MiB.
constexpr size_t NH     = (size_t)NN*HH;              // 16,384,000
constexpr size_t F_H    = 0;                          // h (persist, f32)
constexpr size_t F_A    = NH;                         // work A: q / v
constexpr size_t F_B    = 2*NH;                       // work B: k / skip+agg
constexpr size_t F_NODE = F_A + (size_t)NN*192;       // bf16 node_out overlay
constexpr size_t F_ELOG = 3*NH;                       // E edge logits
constexpr size_t F_RMAX = F_ELOG + EE;                // N per-dst max
constexpr size_t F_CN   = F_RMAX + NN;                // 4*128 normalized centers
constexpr size_t F_CW   = F_CN   + 512;               // 128*384 projW@Wih^T
constexpr size_t F_PEW  = F_CW   + 128*384;           // 1000*384 (pe+projb)@Wih^T + bih
constexpr size_t F_PEB  = F_PEW  + 1000*384;          // 1000*128 pe + projb
constexpr size_t F_END  = F_PEB  + 1000*128;

constexpr size_t I_ROWP = 0;                          // N+8 CSR row ptr
constexpr size_t I_CUR  = I_ROWP + NN + 8;
constexpr size_t I_COL  = I_CUR  + NN;                // E
constexpr size_t I_GRP  = I_COL  + EE;
constexpr size_t I_INV  = I_GRP  + NN;
constexpr size_t I_POS  = I_INV  + NN;
constexpr size_t I_GN   = I_POS  + NN;                // 512*1000
constexpr size_t I_CNT  = I_GN   + (size_t)GG*SMAX;
constexpr size_t I_CH   = I_CNT  + GG;                // 500*512
constexpr size_t I_BS   = I_CH   + (size_t)NCHUNK*GG;
constexpr size_t I_WT   = I_BS   + 512;               // 384*64 packed f16 Whh^T rows
constexpr size_t I_END  = I_WT   + 64*384;

constexpr size_t WS_NEEDED = F_END*4 + I_END*4;       // 213,293,088 B

__device__ inline float wredf(float v){
  #pragma unroll
  for (int o = 32; o; o >>= 1) v += __shfl_xor(v, o);
  return v;
}
__device__ inline u32 bf16rne(float f){
  u32 u = __float_as_uint(f);
  return (u + 0x7fffu + ((u >> 16) & 1u)) >> 16;
}
__device__ inline float bf2f(u16 u){
  return __uint_as_float(((u32)u) << 16);
}
__device__ inline float frcp(float x){
#if __has_builtin(__builtin_amdgcn_rcpf)
  return __builtin_amdgcn_rcpf(x);
#else
  return 1.f / x;
#endif
}

typedef _Float16 h2_t __attribute__((ext_vector_type(2)));
__device__ inline float dot2f(u32 w, u32 h, float acc){
#if __has_builtin(__builtin_amdgcn_fdot2)
  return __builtin_amdgcn_fdot2(__builtin_bit_cast(h2_t, w),
                                __builtin_bit_cast(h2_t, h), acc, false);
#else
  float r;
  asm("v_dot2_f32_f16 %0, %1, %2, %3" : "=v"(r) : "v"(w), "v"(h), "v"(acc));
  return r;
#endif
}
// pin a uint4 into VGPRs: compiler can no longer rematerialize the load
#define PIN4(v) asm volatile("" : "+v"((v).x), "+v"((v).y), "+v"((v).z), "+v"((v).w))

// ---------------- ws-size diagnostic sentinel ----------------
__global__ void k_sentinel(float* __restrict__ out, int n, float val){
  int i = blockIdx.x * 256 + threadIdx.x;
  if (i < n) out[i] = val;
}

// ---------------- CSR build ----------------
__global__ void k_zero(int* __restrict__ p){
  p[blockIdx.x * 256 + threadIdx.x] = 0;
}
__global__ void k_hist(const int* __restrict__ dst, int* __restrict__ deg){
  int e = blockIdx.x * 256 + threadIdx.x;
  atomicAdd(&deg[dst[e]], 1);
}
__global__ void k_s1(const int* __restrict__ deg, int* __restrict__ bsum){
  __shared__ int red[256];
  int t = threadIdx.x;
  red[t] = deg[blockIdx.x * 256 + t];
  __syncthreads();
  for (int s = 128; s; s >>= 1){ if (t < s) red[t] += red[t + s]; __syncthreads(); }
  if (!t) bsum[blockIdx.x] = red[0];
}
__global__ void k_s2(int* __restrict__ bsum){
  __shared__ int arr[512];
  int t = threadIdx.x;
  int v0 = (t < NCHUNK) ? bsum[t] : 0;
  arr[t] = v0; __syncthreads();
  for (int off = 1; off < 512; off <<= 1){
    int v = (t >= off) ? arr[t - off] : 0;
    __syncthreads();
    arr[t] += v;
    __syncthreads();
  }
  if (t < NCHUNK) bsum[t] = arr[t] - v0;   // exclusive
}
__global__ void k_s3(const int* __restrict__ bsum, int* __restrict__ row_ptr,
                     int* __restrict__ cursor){
  __shared__ int arr[256];
  int t = threadIdx.x;
  int i = blockIdx.x * 256 + t;
  int v0 = cursor[i];                      // cursor currently holds deg
  arr[t] = v0; __syncthreads();
  for (int off = 1; off < 256; off <<= 1){
    int v = (t >= off) ? arr[t - off] : 0;
    __syncthreads();
    arr[t] += v;
    __syncthreads();
  }
  int exc = arr[t] - v0 + bsum[blockIdx.x];
  row_ptr[i] = exc;
  cursor[i]  = exc;
  if (i == 0) row_ptr[NN] = EE;
}
__global__ void k_scatter(const int* __restrict__ src, const int* __restrict__ dst,
                          int* __restrict__ cursor, int* __restrict__ col){
  int e = blockIdx.x * 256 + threadIdx.x;
  int idx = atomicAdd(&cursor[dst[e]], 1);
  col[idx] = src[e];
}

// ---------------- centers: normalize + distance ----------------
__global__ void k_setup(const float* __restrict__ centers, float* __restrict__ cn,
                        float* __restrict__ dist_out){
  __shared__ float red[128];
  int t = threadIdx.x;
  for (int l = 0; l < 4; ++l){
    float v = centers[l*128 + t];
    red[t] = v * v; __syncthreads();
    for (int s = 64; s; s >>= 1){ if (t < s) red[t] += red[t + s]; __syncthreads(); }
    float nrm = sqrtf(red[0]);
    __syncthreads();
    cn[l*128 + t] = v / fmaxf(nrm, 1e-8f);
  }
  const int iu0[6] = {0,0,0,1,1,2}, iu1[6] = {1,2,3,2,3,3};
  __shared__ float dv[6];
  for (int p = 0; p < 6; ++p){
    float d = centers[iu0[p]*128 + t] - centers[iu1[p]*128 + t];
    red[t] = d * d; __syncthreads();
    for (int s = 64; s; s >>= 1){ if (t < s) red[t] += red[t + s]; __syncthreads(); }
    if (!t) dv[p] = sqrtf(red[0]);
    __syncthreads();
  }
  if (!t){
    float mean = 0.f;
    for (int p = 0; p < 6; ++p) mean += dv[p];
    mean /= 6.f;
    float var = 0.f;
    for (int p = 0; p < 6; ++p){ float d = dv[p] - mean; var += d * d; }
    var /= 5.f;                              // ddof=1
    dist_out[0] = -var;
  }
}

// ---------------- pos-enc tables ----------------
__global__ void k_pe(const float* __restrict__ projb, float* __restrict__ peb){
  int p = blockIdx.x, t = threadIdx.x;     // 1000 x 128
  float ex  = (float)(t >> 1) * (-2.0f * 9.210340371976184f / 128.0f);
  float ang = (float)p * expf(ex);
  float v = (t & 1) ? cosf(ang) : sinf(ang);
  peb[p*128 + t] = v + projb[t];
}
__global__ void k_pew(const float* __restrict__ peb, const float* __restrict__ Wih,
                      const float* __restrict__ bih, float* __restrict__ pew){
  int p = blockIdx.x;                       // 1000
  int j = blockIdx.y * 128 + threadIdx.x;   // 384
  const float* pb = peb + p*128;
  const float* wr = Wih + (size_t)j*128;
  float acc = bih[j];
  #pragma unroll 4
  for (int m = 0; m < 128; ++m) acc += pb[m] * wr[m];
  pew[(size_t)p*384 + j] = acc;
}
__global__ void k_combw(const float* __restrict__ projW, const float* __restrict__ Wih,
                        float* __restrict__ cw){
  int kk = blockIdx.x;                      // 128
  int j  = blockIdx.y * 128 + threadIdx.x;  // 384
  const float* pr = projW + (size_t)kk*128;
  const float* wr = Wih + (size_t)j*128;
  float acc = 0.f;
  #pragma unroll 4
  for (int m = 0; m < 128; ++m) acc += pr[m] * wr[m];
  cw[(size_t)kk*384 + j] = acc;
}
// pack Whh rows as f16x2 along k: wt[j*64 + kp] = (f16(W[j][2kp+1])<<16)|f16(W[j][2kp])
__global__ void k_packwhh16(const float* __restrict__ Whh, u32* __restrict__ wt){
  int kp = blockIdx.x;                      // 64
  int j  = blockIdx.y * 128 + threadIdx.x;  // 384
  _Float16 a = (_Float16)Whh[(size_t)j*128 + 2*kp];
  _Float16 b = (_Float16)Whh[(size_t)j*128 + 2*kp + 1];
  u32 lo = (u32)__builtin_bit_cast(u16, a);
  u32 hi = (u32)__builtin_bit_cast(u16, b);
  wt[(size_t)j*64 + kp] = (hi << 16) | lo;
}

// ---------------- GEMM v3: 128x128 tile, 8x8 acc, transposed-X LDS ----------------
// Wl[64][132] + Xl[64][132] (X transposed: Xl[k][r]) = 67.6KB -> 2 blocks/CU.
// Per-lane XOR k-reorder (kx = kk ^ ((cg>>2)&3)) de-conflicts the W b128 reads;
// X reads are conflict-free by layout. Sum order over k is free to permute.
__global__ __launch_bounds__(256, 2) void k_gemm(
    const float* __restrict__ X, const float* __restrict__ W, int ldw,
    const float* __restrict__ bias, const float* __restrict__ pew,
    const int* __restrict__ pos, float* __restrict__ out,
    u16* __restrict__ outb, int ldo){
  __shared__ __align__(16) float Wl[64*132];
  __shared__ __align__(16) float Xl[64*132];
  int tid = threadIdx.x;
  int rb = blockIdx.x * 128;
  int cb = blockIdx.y * 128;
  int rg = tid >> 4;           // 0..15 -> rows rg*8..+7
  int cg = tid & 15;           // cols cg*8..+7
  int kxor = (cg >> 2) & 3;
  float acc[8][8];
  #pragma unroll
  for (int a = 0; a < 8; ++a)
    #pragma unroll
    for (int b = 0; b < 8; ++b) acc[a][b] = 0.f;
  for (int half = 0; half < 2; ++half){
    __syncthreads();           // previous compute done / first entry
    // stage W: 64 k-rows x 128 cols
    #pragma unroll
    for (int it = 0; it < 8; ++it){
      int idx = it*256 + tid;
      int kk = idx >> 5, c4 = idx & 31;
      *(float4*)&Wl[kk*132 + c4*4] =
          *(const float4*)&W[(size_t)(half*64 + kk)*ldw + cb + c4*4];
    }
    // stage X transposed: Xl[k][r], 128 rows x 64 k (this half)
    #pragma unroll
    for (int it = 0; it < 8; ++it){
      int idx = it*256 + tid;
      int r = idx >> 4, c4 = idx & 15;
      float4 xv = *(const float4*)&X[(size_t)(rb + r)*128 + half*64 + c4*4];
      Xl[(c4*4+0)*132 + r] = xv.x;
      Xl[(c4*4+1)*132 + r] = xv.y;
      Xl[(c4*4+2)*132 + r] = xv.z;
      Xl[(c4*4+3)*132 + r] = xv.w;
    }
    __syncthreads();
    #pragma unroll 2
    for (int kk = 0; kk < 64; ++kk){
      int kx = kk ^ kxor;
      float4 wa = *(const float4*)&Wl[kx*132 + cg*8];
      float4 wb = *(const float4*)&Wl[kx*132 + cg*8 + 4];
      float4 xa = *(const float4*)&Xl[kx*132 + rg*8];
      float4 xb = *(const float4*)&Xl[kx*132 + rg*8 + 4];
      float xs[8] = {xa.x, xa.y, xa.z, xa.w, xb.x, xb.y, xb.z, xb.w};
      float ws[8] = {wa.x, wa.y, wa.z, wa.w, wb.x, wb.y, wb.z, wb.w};
      #pragma unroll
      for (int rr = 0; rr < 8; ++rr)
        #pragma unroll
        for (int j = 0; j < 8; ++j) acc[rr][j] += xs[rr] * ws[j];
    }
  }
  #pragma unroll
  for (int rr = 0; rr < 8; ++rr){
    int r = rb + rg*8 + rr;
    float bv[8];
    if (pos){
      const float* pw = pew + (size_t)pos[r]*384 + cb + cg*8;
      #pragma unroll
      for (int j = 0; j < 8; ++j) bv[j] = pw[j];
    } else {
      #pragma unroll
      for (int j = 0; j < 8; ++j) bv[j] = bias[cb + cg*8 + j];
    }
    if (outb){
      u16 ob[8];
      #pragma unroll
      for (int j = 0; j < 8; ++j) ob[j] = (u16)bf16rne(acc[rr][j] + bv[j]);
      *(uint4*)(outb + (size_t)r*ldo + cb + cg*8) = *(const uint4*)ob;
    } else {
      float ov[8];
      #pragma unroll
      for (int j = 0; j < 8; ++j) ov[j] = acc[rr][j] + bv[j];
      float* op = out + (size_t)r*ldo + cb + cg*8;
      *(float4*)op       = *(const float4*)&ov[0];
      *(float4*)(op + 4) = *(const float4*)&ov[4];
    }
  }
}

// ---------------- edge phase 1: logits + per-dst max (4 dst per block) ----------------
__global__ __launch_bounds__(256) void k_logits(
    const float* __restrict__ q, const float* __restrict__ k,
    const int* __restrict__ row_ptr, const int* __restrict__ col,
    float* __restrict__ elog, float* __restrict__ rmax){
  int d = blockIdx.x * 4 + (threadIdx.x >> 6);
  int lane = threadIdx.x & 63;
  int e0 = row_ptr[d], e1 = row_ptr[d+1];
  if (e0 == e1) return;
  float2 qv = *(const float2*)&q[(size_t)d*128 + 2*lane];
  float m = -INFINITY;
  for (int e = e0; e < e1; ++e){
    int s = col[e];
    float2 kv = *(const float2*)&k[(size_t)s*128 + 2*lane];
    float p = qv.x * kv.x + qv.y * kv.y;
    p = wredf(p) * 0.08838834764831845f;   // 1/sqrt(128)
    if (lane == 0) elog[e] = p;
    m = fmaxf(m, p);
  }
  if (lane == 0) rmax[d] = m;
}

// ---------------- edge phase 2: softmax-weighted aggregation ----------------
__global__ __launch_bounds__(256) void k_agg(
    const float* __restrict__ v, const int* __restrict__ row_ptr,
    const int* __restrict__ col, const float* __restrict__ elog,
    const float* __restrict__ rmax, float* __restrict__ h2){
  int d = blockIdx.x * 4 + (threadIdx.x >> 6);
  int lane = threadIdx.x & 63;
  int e0 = row_ptr[d], e1 = row_ptr[d+1];
  if (e0 == e1) return;                    // h2 keeps skip value
  float m = rmax[d];
  float ssum = 0.f, a0 = 0.f, a1 = 0.f;
  for (int e = e0; e < e1; ++e){
    int s = col[e];
    float el = __expf(elog[e] - m);
    float2 vv = *(const float2*)&v[(size_t)s*128 + 2*lane];
    ssum += el;
    a0 += el * vv.x;
    a1 += el * vv.y;
  }
  float inv = 1.f / ssum;
  float2 hv = *(float2*)&h2[(size_t)d*128 + 2*lane];
  hv.x += a0 * inv;
  hv.y += a1 * inv;
  *(float2*)&h2[(size_t)d*128 + 2*lane] = hv;
}

// ---------------- relu(layernorm) per row (f32 in / f32 out) ----------------
__global__ __launch_bounds__(256) void k_lnrelu(
    const float* __restrict__ in, const float* __restrict__ g,
    const float* __restrict__ b, float* __restrict__ outp){
  int node = blockIdx.x * 4 + (threadIdx.x >> 6);
  int lane = threadIdx.x & 63;
  float x0 = in[(size_t)node*128 + 2*lane], x1 = in[(size_t)node*128 + 2*lane + 1];
  float s = wredf(x0 + x1);
  float qq = wredf(x0*x0 + x1*x1);
  float mu = s * 0.0078125f;
  float var = qq * 0.0078125f - mu*mu;
  float rstd = rsqrtf(var + 1e-5f);
  float y0 = (x0 - mu)*rstd*g[2*lane]   + b[2*lane];
  float y1 = (x1 - mu)*rstd*g[2*lane+1] + b[2*lane+1];
  outp[(size_t)node*128 + 2*lane]     = fmaxf(y0, 0.f);
  outp[(size_t)node*128 + 2*lane + 1] = fmaxf(y1, 0.f);
}

// ---------------- post-GRU relu(layernorm) in-place on bf16 node_out ----------------
__global__ __launch_bounds__(256) void k_postln(
    u16* __restrict__ no, const float* __restrict__ g, const float* __restrict__ b){
  int node = blockIdx.x * 4 + (threadIdx.x >> 6);
  int lane = threadIdx.x & 63;
  float x0 = bf2f(no[(size_t)node*128 + 2*lane]);
  float x1 = bf2f(no[(size_t)node*128 + 2*lane + 1]);
  float s = wredf(x0 + x1);
  float qq = wredf(x0*x0 + x1*x1);
  float mu = s * 0.0078125f;
  float var = qq * 0.0078125f - mu*mu;
  float rstd = rsqrtf(var + 1e-5f);
  float y0 = (x0 - mu)*rstd*g[2*lane]   + b[2*lane];
  float y1 = (x1 - mu)*rstd*g[2*lane+1] + b[2*lane+1];
  no[(size_t)node*128 + 2*lane]     = (u16)bf16rne(fmaxf(y0, 0.f));
  no[(size_t)node*128 + 2*lane + 1] = (u16)bf16rne(fmaxf(y1, 0.f));
}

// ---------------- cluster assignment ----------------
__global__ __launch_bounds__(256) void k_classify(
    const float* __restrict__ h, const float* __restrict__ cn,
    const int* __restrict__ batch, const int* __restrict__ callsq,
    int* __restrict__ grp, int* __restrict__ inv){
  int node = blockIdx.x * 4 + (threadIdx.x >> 6);
  int lane = threadIdx.x & 63;
  float h0 = h[(size_t)node*128 + 2*lane], h1 = h[(size_t)node*128 + 2*lane + 1];
  float p0 = h0*cn[      2*lane] + h1*cn[      2*lane+1];
  float p1 = h0*cn[128 + 2*lane] + h1*cn[128 + 2*lane+1];
  float p2 = h0*cn[256 + 2*lane] + h1*cn[256 + 2*lane+1];
  float p3 = h0*cn[384 + 2*lane] + h1*cn[384 + 2*lane+1];
  p0 = wredf(p0); p1 = wredf(p1); p2 = wredf(p2); p3 = wredf(p3);
  if (lane == 0){
    float best = p0; int bi = 0;
    if (p1 > best){ best = p1; bi = 1; }
    if (p2 > best){ best = p2; bi = 2; }
    if (p3 > best){ best = p3; bi = 3; }
    grp[node] = batch[node]*4 + bi;
    inv[callsq[node]] = node;
  }
}

// ---------------- grouping: chunked multisplit ----------------
__global__ __launch_bounds__(256) void k_g1(const int* __restrict__ inv,
                                            const int* __restrict__ grp,
                                            int* __restrict__ ch){
  __shared__ int hist[GG];
  int c = blockIdx.x, t = threadIdx.x;
  hist[t] = 0; hist[t + 256] = 0;
  __syncthreads();
  int g = grp[inv[c*256 + t]];
  atomicAdd(&hist[g], 1);
  __syncthreads();
  ch[c*GG + t] = hist[t];
  ch[c*GG + 256 + t] = hist[256 + t];
}
// parallel per-group scan over chunks: one block per group (was 1-block serial)
__global__ void k_g2(int* __restrict__ ch, int* __restrict__ cnt){
  __shared__ int arr[512];
  int g = blockIdx.x, t = threadIdx.x;
  int v0 = (t < NCHUNK) ? ch[(size_t)t*GG + g] : 0;
  arr[t] = v0; __syncthreads();
  for (int off = 1; off < 512; off <<= 1){
    int v = (t >= off) ? arr[t - off] : 0;
    __syncthreads();
    arr[t] += v;
    __syncthreads();
  }
  if (t < NCHUNK) ch[(size_t)t*GG + g] = arr[t] - v0;   // exclusive
  if (t == 511) cnt[g] = arr[511];
}
__global__ __launch_bounds__(256) void k_g3(
    const int* __restrict__ inv, const int* __restrict__ grp,
    const int* __restrict__ ch, int* __restrict__ pos, int* __restrict__ gn){
  __shared__ int hist[GG];
  int c = blockIdx.x, t = threadIdx.x;
  hist[t] = 0; hist[t + 256] = 0;
  __syncthreads();
  int node = inv[c*256 + t];
  int g = grp[node];
  int lane = t & 63, w = t >> 6;
  int before = 0, total = 0;
  for (int j = 0; j < 64; ++j){
    int gj = __shfl(g, j);
    if (gj == g){ total++; if (j < lane) before++; }
  }
  int base = 0;
  for (int wv = 0; wv < 4; ++wv){
    if (w == wv){
      base = hist[g];
      if (before == total - 1) hist[g] = base + total;  // last lane of its g
    }
    __syncthreads();
  }
  int p = ch[c*GG + g] + base + before;
  pos[node] = p;
  gn[(size_t)g*SMAX + p] = node;
}

// ---------------- GRU v7: v6 + split dot chains (2 partial accs per gate) ----------
__global__ __launch_bounds__(256)
__attribute__((amdgpu_waves_per_eu(2, 2)))
void k_gru(
    const u16* __restrict__ gi, const u32* __restrict__ wt,
    const float* __restrict__ bhh, const int* __restrict__ gn,
    const int* __restrict__ cnt, u16* __restrict__ node_out){
  __shared__ __align__(16) u16 hb16[2][128];   // double-buffered h (f16)
  int t = threadIdx.x;
  int j = t >> 1;              // output index 0..127
  int kh = t & 1;              // k-half 0/1
  int g = blockIdx.x;
  int my = cnt[g];
  if (my <= 1) return;
  // ---- load per-thread weight rows into registers (once), then pin ----
  uint4 wr_[8], wz_[8], wn_[8];
  {
    const uint4* wt4 = (const uint4*)wt;
    size_t b0 = (size_t)(0*128 + j)*16 + kh*8;
    size_t b1 = (size_t)(1*128 + j)*16 + kh*8;
    size_t b2 = (size_t)(2*128 + j)*16 + kh*8;
    #pragma unroll
    for (int s = 0; s < 8; ++s){
      wr_[s] = wt4[b0 + s];
      wz_[s] = wt4[b1 + s];
      wn_[s] = wt4[b2 + s];
    }
    #pragma unroll
    for (int s = 0; s < 8; ++s){
      PIN4(wr_[s]); PIN4(wz_[s]); PIN4(wn_[s]);
    }
  }
  if (t < 128) hb16[0][t] = 0;
  float br = bhh[j], bz = bhh[128 + j], bn = bhh[256 + j];
  const int* gnr = gn + (size_t)g*SMAX;
  float hprev = 0.f;
  // ---- 3-deep gi prefetch pipeline ----
  int nA = gnr[0];
  int nB = gnr[min(1, my - 1)];
  int nC = gnr[min(2, my - 1)];
  const u16* gA = gi + (size_t)nA*384;
  const u16* gB = gi + (size_t)nB*384;
  const u16* gC = gi + (size_t)nC*384;
  float axr = bf2f(gA[j]), axz = bf2f(gA[128 + j]), axn = bf2f(gA[256 + j]);
  float bxr = bf2f(gB[j]), bxz = bf2f(gB[128 + j]), bxn = bf2f(gB[256 + j]);
  float cxr = bf2f(gC[j]), cxz = bf2f(gC[128 + j]), cxn = bf2f(gC[256 + j]);
  __syncthreads();
  for (int p = 0; p < my; ++p){
    int cur = p & 1, nxt = cur ^ 1;
    float xr = axr, xz = axz, xn = axn;
    int node = nA;
    // shift pipeline and issue load for p+3
    axr = bxr; axz = bxz; axn = bxn; nA = nB;
    bxr = cxr; bxz = cxz; bxn = cxn; nB = nC;
    nC = gnr[min(p + 3, my - 1)];
    const u16* gN = gi + (size_t)nC*384;
    cxr = bf2f(gN[j]); cxz = bf2f(gN[128 + j]); cxn = bf2f(gN[256 + j]);
    // h fragment from LDS
    const uint4* HB = (const uint4*)&hb16[cur][0];
    uint4 hh[8];
    #pragma unroll
    for (int s = 0; s < 8; ++s) hh[s] = HB[kh*8 + s];
    // split dot chains: even s -> acc0, odd s -> acc1 (halves dep depth)
    float ar0 = 0.f, ar1 = 0.f, az0 = 0.f, az1 = 0.f, an0 = 0.f, an1 = 0.f;
    #pragma unroll
    for (int s = 0; s < 8; s += 2){
      uint4 h0 = hh[s], h1 = hh[s + 1];
      uint4 r0 = wr_[s], r1 = wr_[s + 1];
      uint4 z0 = wz_[s], z1 = wz_[s + 1];
      uint4 n0 = wn_[s], n1 = wn_[s + 1];
      ar0 = dot2f(r0.x, h0.x, ar0); ar1 = dot2f(r1.x, h1.x, ar1);
      az0 = dot2f(z0.x, h0.x, az0); az1 = dot2f(z1.x, h1.x, az1);
      an0 = dot2f(n0.x, h0.x, an0); an1 = dot2f(n1.x, h1.x, an1);
      ar0 = dot2f(r0.y, h0.y, ar0); ar1 = dot2f(r1.y, h1.y, ar1);
      az0 = dot2f(z0.y, h0.y, az0); az1 = dot2f(z1.y, h1.y, az1);
      an0 = dot2f(n0.y, h0.y, an0); an1 = dot2f(n1.y, h1.y, an1);
      ar0 = dot2f(r0.z, h0.z, ar0); ar1 = dot2f(r1.z, h1.z, ar1);
      az0 = dot2f(z0.z, h0.z, az0); az1 = dot2f(z1.z, h1.z, az1);
      an0 = dot2f(n0.z, h0.z, an0); an1 = dot2f(n1.z, h1.z, an1);
      ar0 = dot2f(r0.w, h0.w, ar0); ar1 = dot2f(r1.w, h1.w, ar1);
      az0 = dot2f(z0.w, h0.w, az0); az1 = dot2f(z1.w, h1.w, az1);
      an0 = dot2f(n0.w, h0.w, an0); an1 = dot2f(n1.w, h1.w, an1);
    }
    float ar = ar0 + ar1, az = az0 + az1, an = an0 + an1;
    // pair-reduce k-halves (partner = lane^1), then add bias
    ar += __shfl_xor(ar, 1); az += __shfl_xor(az, 1); an += __shfl_xor(an, 1);
    ar += br; az += bz; an += bn;
    // fast gates: sigmoid via __expf+rcp, tanh via one __expf
    float er = __expf(-(xr + ar));
    float r  = frcp(1.f + er);
    float ez = __expf(-(xz + az));
    float z  = frcp(1.f + ez);
    float y  = xn + r * an;
    float e2 = __expf(-2.f * y);
    float n  = (1.f - e2) * frcp(1.f + e2);   // tanh(y)
    float hnew = n + z * (hprev - n);
    hprev = hnew;
    if (!kh){
      _Float16 hf = (_Float16)hnew;
      hb16[nxt][j] = __builtin_bit_cast(u16, hf);       // h for next step
      node_out[(size_t)node*128 + j] = (u16)bf16rne(hnew);  // raw h out (LN later)
    }
    __syncthreads();            // h[nxt] visible before next step's reads
  }
}

// ---------------- head: gelu(lin1) -> sigmoid(lin2) ----------------
__global__ __launch_bounds__(256) void k_head(
    const float* __restrict__ h, const u16* __restrict__ node_out,
    const int* __restrict__ grp, const int* __restrict__ cnt,
    const float* __restrict__ l1W, const float* __restrict__ l1b,
    const float* __restrict__ l2W, const float* __restrict__ l2b,
    float* __restrict__ out){
  int node = blockIdx.x * 4 + (threadIdx.x >> 6);
  int lane = threadIdx.x & 63;
  bool single = (cnt[grp[node]] == 1);
  float x0, x1;
  if (single){
    x0 = h[(size_t)node*128 + 2*lane];
    x1 = h[(size_t)node*128 + 2*lane + 1];
  } else {
    x0 = bf2f(node_out[(size_t)node*128 + 2*lane]);
    x1 = bf2f(node_out[(size_t)node*128 + 2*lane + 1]);
  }
  float acc[8];
  #pragma unroll
  for (int j = 0; j < 8; ++j)
    acc[j] = x0 * l1W[(2*lane)*8 + j] + x1 * l1W[(2*lane + 1)*8 + j];
  #pragma unroll
  for (int o = 32; o; o >>= 1)
    #pragma unroll
    for (int j = 0; j < 8; ++j) acc[j] += __shfl_xor(acc[j], o);
  if (lane == 0){
    float zz = l2b[0];
    #pragma unroll
    for (int j = 0; j < 8; ++j){
      float xx = acc[j] + l1b[j];
      float ge = 0.5f * xx * (1.f + erff(xx * 0.7071067811865476f));
      zz += ge * l2W[j];
    }
    out[node] = 1.f / (1.f + expf(-zz));
  }
}

extern "C" void kernel_launch(void* const* d_in, const int* in_sizes, int n_in,
                              void* d_out, int out_size, void* d_ws, size_t ws_size,
                              hipStream_t stream){
  float* out = (float*)d_out;

  // ---- ws-size guard: encode ws MB into output instead of faulting ----
  if (ws_size < WS_NEEDED){
    float code = -(float)(ws_size >> 20);
    k_sentinel<<<(out_size + 255)/256, 256, 0, stream>>>(out, out_size, code);
    return;
  }

  const float* x       = (const float*)d_in[0];
  const int*   tei     = (const int*)d_in[1];
  const int*   callsq  = (const int*)d_in[2];
  const int*   batch   = (const int*)d_in[3];
  const float* Wq      = (const float*)d_in[4];
  const float* bq      = (const float*)d_in[5];
  const float* Wk      = (const float*)d_in[6];
  const float* bk      = (const float*)d_in[7];
  const float* Wv      = (const float*)d_in[8];
  const float* bv      = (const float*)d_in[9];
  const float* Wsk     = (const float*)d_in[10];
  const float* bsk     = (const float*)d_in[11];
  const float* lng     = (const float*)d_in[12];
  const float* lnb     = (const float*)d_in[13];
  const float* centers = (const float*)d_in[14];
  const float* projW   = (const float*)d_in[15];
  const float* projb   = (const float*)d_in[16];
  const float* Wih     = (const float*)d_in[17];
  const float* Whh     = (const float*)d_in[18];
  const float* bih     = (const float*)d_in[19];
  const float* bhh     = (const float*)d_in[20];
  const float* sqg     = (const float*)d_in[21];
  const float* sqb     = (const float*)d_in[22];
  const float* l1W     = (const float*)d_in[23];
  const float* l1b     = (const float*)d_in[24];
  const float* l2W     = (const float*)d_in[25];
  const float* l2b     = (const float*)d_in[26];

  float* wf = (float*)d_ws;
  float* f_h    = wf + F_H;
  float* f_a    = wf + F_A;
  float* f_b    = wf + F_B;
  float* f_elog = wf + F_ELOG;
  float* f_rmax = wf + F_RMAX;
  float* f_cn   = wf + F_CN;
  float* f_cw   = wf + F_CW;
  float* f_pew  = wf + F_PEW;
  float* f_peb  = wf + F_PEB;
  u16*   gi_bf  = (u16*)(wf + F_A);      // N x 384 bf16 (overlay, post-conv)
  u16*   no_bf  = (u16*)(wf + F_NODE);   // N x 128 bf16 node_out (overlay)
  int* wi = (int*)(wf + F_END);
  int* i_rowp = wi + I_ROWP;
  int* i_cur  = wi + I_CUR;
  int* i_col  = wi + I_COL;
  int* i_grp  = wi + I_GRP;
  int* i_inv  = wi + I_INV;
  int* i_pos  = wi + I_POS;
  int* i_gn   = wi + I_GN;
  int* i_cnt  = wi + I_CNT;
  int* i_ch   = wi + I_CH;
  int* i_bs   = wi + I_BS;
  u32* i_wt   = (u32*)(wi + I_WT);

  const int* esrc = tei;
  const int* edst = tei + EE;

  // CSR build
  k_zero<<<NN/256, 256, 0, stream>>>(i_cur);
  k_hist<<<EE/256, 256, 0, stream>>>(edst, i_cur);
  k_s1<<<NCHUNK, 256, 0, stream>>>(i_cur, i_bs);
  k_s2<<<1, 512, 0, stream>>>(i_bs);
  k_s3<<<NCHUNK, 256, 0, stream>>>(i_bs, i_rowp, i_cur);
  k_scatter<<<EE/256, 256, 0, stream>>>(esrc, edst, i_cur, i_col);

  // centers, PE tables, combined weights, packed f16 Whh rows
  k_setup<<<1, 128, 0, stream>>>(centers, f_cn, out + NN);
  k_pe<<<1000, 128, 0, stream>>>(projb, f_peb);
  k_pew<<<dim3(1000, 3), 128, 0, stream>>>(f_peb, Wih, bih, f_pew);
  k_combw<<<dim3(128, 3), 128, 0, stream>>>(projW, Wih, f_cw);
  k_packwhh16<<<dim3(64, 3), 128, 0, stream>>>(Whh, i_wt);

  // 3x TransformerConv + relu(LN); A/B ping-pong keeps peak mem at 2 buffers
  for (int i = 0; i < 3; ++i){
    const float* xin = i ? f_h : x;
    size_t wo = (size_t)i * 128 * 128, bo = (size_t)i * 128;
    k_gemm<<<dim3(NN/128, 1), 256, 0, stream>>>(xin, Wq + wo, 128, bq + bo, nullptr, nullptr, f_a, nullptr, 128);
    k_gemm<<<dim3(NN/128, 1), 256, 0, stream>>>(xin, Wk + wo, 128, bk + bo, nullptr, nullptr, f_b, nullptr, 128);
    k_logits<<<NN/4, 256, 0, stream>>>(f_a, f_b, i_rowp, i_col, f_elog, f_rmax);
    k_gemm<<<dim3(NN/128, 1), 256, 0, stream>>>(xin, Wv + wo, 128, bv + bo, nullptr, nullptr, f_a, nullptr, 128);
    k_gemm<<<dim3(NN/128, 1), 256, 0, stream>>>(xin, Wsk + wo, 128, bsk + bo, nullptr, nullptr, f_b, nullptr, 128);
    k_agg<<<NN/4, 256, 0, stream>>>(f_a, i_rowp, i_col, f_elog, f_rmax, f_b);
    k_lnrelu<<<NN/4, 256, 0, stream>>>(f_b, lng + bo, lnb + bo, f_h);
  }

  // cluster assignment + grouping
  k_classify<<<NN/4, 256, 0, stream>>>(f_h, f_cn, batch, callsq, i_grp, i_inv);
  k_g1<<<NCHUNK, 256, 0, stream>>>(i_inv, i_grp, i_ch);
  k_g2<<<GG, 512, 0, stream>>>(i_ch, i_cnt);
  k_g3<<<NCHUNK, 256, 0, stream>>>(i_inv, i_grp, i_ch, i_pos, i_gn);

  // gi = h @ (projW@Wih^T) + PEW[pos]  -> bf16 overlay on A (+ part of B)
  k_gemm<<<dim3(NN/128, 3), 256, 0, stream>>>(f_h, f_cw, 384, nullptr, f_pew, i_pos, nullptr, gi_bf, 384);

  // GRU (raw h out) -> post LN+ReLU in parallel
  k_gru<<<GG, 256, 0, stream>>>(gi_bf, i_wt, bhh, i_gn, i_cnt, no_bf);
  k_postln<<<NN/4, 256, 0, stream>>>(no_bf, sqg, sqb);

  // head
  k_head<<<NN/4, 256, 0, stream>>>(f_h, no_bf, i_grp, i_cnt, l1W, l1b, l2W, l2b, out);
}

// Round 11
// 2568.604 us; speedup vs baseline: 2.6176x; 1.1300x over previous
//
#include <hip/hip_runtime.h>

#define NN 128000
#define EE 1024000
#define HH 128
#define GG 512
#define SMAX 1000
#define NCHUNK 500   // 500 * 256 = 128000

typedef unsigned int u32;
typedef unsigned short u16;

// ---------------- workspace layout (floats, then ints) ----------------
// ws budget measured round 3: 256 MiB. This layout: 209.4 MB.
// Edge phase v2 needs only TWO N*128 work buffers (A,B): k folded into qt=q@Wk^T,
// v folded out of aggregation (agg x rows, then @Wv).
constexpr size_t NH     = (size_t)NN*HH;              // 16,384,000
constexpr size_t F_H    = 0;                          // h (persist, f32)
constexpr size_t F_A    = NH;                         // work A: q / xagg
constexpr size_t F_B    = 2*NH;                       // work B: qt / h2
constexpr size_t F_NODE = F_A + (size_t)NN*192;       // bf16 node_out overlay (in B)
constexpr size_t F_QB   = 3*NH;                       // N: qb_d = q_d . bk
constexpr size_t F_CN   = F_QB  + NN;                 // 4*128 normalized centers
constexpr size_t F_WKT  = F_CN  + 512;                // 3*128*128 Wk^T per layer
constexpr size_t F_CW   = F_WKT + 3*16384;            // 128*384 projW@Wih^T
constexpr size_t F_PEW  = F_CW  + 128*384;            // 1000*384 (pe+projb)@Wih^T + bih
constexpr size_t F_PEB  = F_PEW + 1000*384;           // 1000*128 pe + projb
constexpr size_t F_END  = F_PEB + 1000*128;

constexpr size_t I_ROWP = 0;                          // N+8 CSR row ptr
constexpr size_t I_CUR  = I_ROWP + NN + 8;
constexpr size_t I_COL  = I_CUR  + NN;                // E
constexpr size_t I_GRP  = I_COL  + EE;
constexpr size_t I_INV  = I_GRP  + NN;
constexpr size_t I_POS  = I_INV  + NN;
constexpr size_t I_GN   = I_POS  + NN;                // 512*1000
constexpr size_t I_CNT  = I_GN   + (size_t)GG*SMAX;
constexpr size_t I_CH   = I_CNT  + GG;                // 500*512
constexpr size_t I_BS   = I_CH   + (size_t)NCHUNK*GG;
constexpr size_t I_WT   = I_BS   + 512;               // 384*64 packed f16 Whh^T rows
constexpr size_t I_END  = I_WT   + 64*384;

constexpr size_t WS_NEEDED = F_END*4 + I_END*4;       // 209,393,696 B

__device__ inline float wredf(float v){
  #pragma unroll
  for (int o = 32; o; o >>= 1) v += __shfl_xor(v, o);
  return v;
}
__device__ inline u32 bf16rne(float f){
  u32 u = __float_as_uint(f);
  return (u + 0x7fffu + ((u >> 16) & 1u)) >> 16;
}
__device__ inline float bf2f(u16 u){
  return __uint_as_float(((u32)u) << 16);
}
__device__ inline float frcp(float x){
#if __has_builtin(__builtin_amdgcn_rcpf)
  return __builtin_amdgcn_rcpf(x);
#else
  return 1.f / x;
#endif
}

typedef _Float16 h2_t __attribute__((ext_vector_type(2)));
__device__ inline float dot2f(u32 w, u32 h, float acc){
#if __has_builtin(__builtin_amdgcn_fdot2)
  return __builtin_amdgcn_fdot2(__builtin_bit_cast(h2_t, w),
                                __builtin_bit_cast(h2_t, h), acc, false);
#else
  float r;
  asm("v_dot2_f32_f16 %0, %1, %2, %3" : "=v"(r) : "v"(w), "v"(h), "v"(acc));
  return r;
#endif
}
// pin a uint4 into VGPRs
#define PIN4(v) asm volatile("" : "+v"((v).x), "+v"((v).y), "+v"((v).z), "+v"((v).w))

// ---------------- ws-size diagnostic sentinel ----------------
__global__ void k_sentinel(float* __restrict__ out, int n, float val){
  int i = blockIdx.x * 256 + threadIdx.x;
  if (i < n) out[i] = val;
}

// ---------------- CSR build ----------------
__global__ void k_zero(int* __restrict__ p){
  p[blockIdx.x * 256 + threadIdx.x] = 0;
}
__global__ void k_hist(const int* __restrict__ dst, int* __restrict__ deg){
  int e = blockIdx.x * 256 + threadIdx.x;
  atomicAdd(&deg[dst[e]], 1);
}
__global__ void k_s1(const int* __restrict__ deg, int* __restrict__ bsum){
  __shared__ int red[256];
  int t = threadIdx.x;
  red[t] = deg[blockIdx.x * 256 + t];
  __syncthreads();
  for (int s = 128; s; s >>= 1){ if (t < s) red[t] += red[t + s]; __syncthreads(); }
  if (!t) bsum[blockIdx.x] = red[0];
}
__global__ void k_s2(int* __restrict__ bsum){
  __shared__ int arr[512];
  int t = threadIdx.x;
  int v0 = (t < NCHUNK) ? bsum[t] : 0;
  arr[t] = v0; __syncthreads();
  for (int off = 1; off < 512; off <<= 1){
    int v = (t >= off) ? arr[t - off] : 0;
    __syncthreads();
    arr[t] += v;
    __syncthreads();
  }
  if (t < NCHUNK) bsum[t] = arr[t] - v0;   // exclusive
}
__global__ void k_s3(const int* __restrict__ bsum, int* __restrict__ row_ptr,
                     int* __restrict__ cursor){
  __shared__ int arr[256];
  int t = threadIdx.x;
  int i = blockIdx.x * 256 + t;
  int v0 = cursor[i];                      // cursor currently holds deg
  arr[t] = v0; __syncthreads();
  for (int off = 1; off < 256; off <<= 1){
    int v = (t >= off) ? arr[t - off] : 0;
    __syncthreads();
    arr[t] += v;
    __syncthreads();
  }
  int exc = arr[t] - v0 + bsum[blockIdx.x];
  row_ptr[i] = exc;
  cursor[i]  = exc;
  if (i == 0) row_ptr[NN] = EE;
}
__global__ void k_scatter(const int* __restrict__ src, const int* __restrict__ dst,
                          int* __restrict__ cursor, int* __restrict__ col){
  int e = blockIdx.x * 256 + threadIdx.x;
  int idx = atomicAdd(&cursor[dst[e]], 1);
  col[idx] = src[e];
}

// ---------------- centers: normalize + distance ----------------
__global__ void k_setup(const float* __restrict__ centers, float* __restrict__ cn,
                        float* __restrict__ dist_out){
  __shared__ float red[128];
  int t = threadIdx.x;
  for (int l = 0; l < 4; ++l){
    float v = centers[l*128 + t];
    red[t] = v * v; __syncthreads();
    for (int s = 64; s; s >>= 1){ if (t < s) red[t] += red[t + s]; __syncthreads(); }
    float nrm = sqrtf(red[0]);
    __syncthreads();
    cn[l*128 + t] = v / fmaxf(nrm, 1e-8f);
  }
  const int iu0[6] = {0,0,0,1,1,2}, iu1[6] = {1,2,3,2,3,3};
  __shared__ float dv[6];
  for (int p = 0; p < 6; ++p){
    float d = centers[iu0[p]*128 + t] - centers[iu1[p]*128 + t];
    red[t] = d * d; __syncthreads();
    for (int s = 64; s; s >>= 1){ if (t < s) red[t] += red[t + s]; __syncthreads(); }
    if (!t) dv[p] = sqrtf(red[0]);
    __syncthreads();
  }
  if (!t){
    float mean = 0.f;
    for (int p = 0; p < 6; ++p) mean += dv[p];
    mean /= 6.f;
    float var = 0.f;
    for (int p = 0; p < 6; ++p){ float d = dv[p] - mean; var += d * d; }
    var /= 5.f;                              // ddof=1
    dist_out[0] = -var;
  }
}

// ---------------- pos-enc tables + weight transforms ----------------
__global__ void k_pe(const float* __restrict__ projb, float* __restrict__ peb){
  int p = blockIdx.x, t = threadIdx.x;     // 1000 x 128
  float ex  = (float)(t >> 1) * (-2.0f * 9.210340371976184f / 128.0f);
  float ang = (float)p * expf(ex);
  float v = (t & 1) ? cosf(ang) : sinf(ang);
  peb[p*128 + t] = v + projb[t];
}
__global__ void k_pew(const float* __restrict__ peb, const float* __restrict__ Wih,
                      const float* __restrict__ bih, float* __restrict__ pew){
  int p = blockIdx.x;                       // 1000
  int j = blockIdx.y * 128 + threadIdx.x;   // 384
  const float* pb = peb + p*128;
  const float* wr = Wih + (size_t)j*128;
  float acc = bih[j];
  #pragma unroll 4
  for (int m = 0; m < 128; ++m) acc += pb[m] * wr[m];
  pew[(size_t)p*384 + j] = acc;
}
__global__ void k_combw(const float* __restrict__ projW, const float* __restrict__ Wih,
                        float* __restrict__ cw){
  int kk = blockIdx.x;                      // 128
  int j  = blockIdx.y * 128 + threadIdx.x;  // 384
  const float* pr = projW + (size_t)kk*128;
  const float* wr = Wih + (size_t)j*128;
  float acc = 0.f;
  #pragma unroll 4
  for (int m = 0; m < 128; ++m) acc += pr[m] * wr[m];
  cw[(size_t)kk*384 + j] = acc;
}
// Wk^T per layer: wkt[l][k][c] = Wk[l][c][k]
__global__ void k_tr(const float* __restrict__ Wk, float* __restrict__ wkt){
  int kk = blockIdx.x, l = blockIdx.y, c = threadIdx.x;
  wkt[(size_t)l*16384 + kk*128 + c] = Wk[(size_t)l*16384 + c*128 + kk];
}
// pack Whh rows as f16x2 along k
__global__ void k_packwhh16(const float* __restrict__ Whh, u32* __restrict__ wt){
  int kp = blockIdx.x;                      // 64
  int j  = blockIdx.y * 128 + threadIdx.x;  // 384
  _Float16 a = (_Float16)Whh[(size_t)j*128 + 2*kp];
  _Float16 b = (_Float16)Whh[(size_t)j*128 + 2*kp + 1];
  u32 lo = (u32)__builtin_bit_cast(u16, a);
  u32 hi = (u32)__builtin_bit_cast(u16, b);
  wt[(size_t)j*64 + kp] = (hi << 16) | lo;
}

// ---------------- GEMM v4: 128x128 tile, 8x8 acc; optional second K=128 source ----
// out = X@W [+ X2@W2] + bias. X2!=null -> K=256 fused (halves 2,3 from X2/W2, ldw=128).
__global__ __launch_bounds__(256, 2) void k_gemm(
    const float* __restrict__ X, const float* __restrict__ W, int ldw,
    const float* __restrict__ X2, const float* __restrict__ W2,
    const float* __restrict__ bias, const float* __restrict__ pew,
    const int* __restrict__ pos, float* __restrict__ out,
    u16* __restrict__ outb, int ldo){
  __shared__ __align__(16) float Wl[64*132];
  __shared__ __align__(16) float Xl[64*132];
  int tid = threadIdx.x;
  int rb = blockIdx.x * 128;
  int cb = blockIdx.y * 128;
  int rg = tid >> 4;           // 0..15 -> rows rg*8..+7
  int cg = tid & 15;           // cols cg*8..+7
  int kxor = (cg >> 2) & 3;
  float acc[8][8];
  #pragma unroll
  for (int a = 0; a < 8; ++a)
    #pragma unroll
    for (int b = 0; b < 8; ++b) acc[a][b] = 0.f;
  int nhalf = X2 ? 4 : 2;
  for (int half = 0; half < nhalf; ++half){
    const float* Xs = (half < 2) ? X : X2;
    const float* Ws = (half < 2) ? W : W2;
    int ldws = (half < 2) ? ldw : 128;
    int hk = half & 1;
    __syncthreads();           // previous compute done / first entry
    #pragma unroll
    for (int it = 0; it < 8; ++it){
      int idx = it*256 + tid;
      int kk = idx >> 5, c4 = idx & 31;
      *(float4*)&Wl[kk*132 + c4*4] =
          *(const float4*)&Ws[(size_t)(hk*64 + kk)*ldws + cb + c4*4];
    }
    #pragma unroll
    for (int it = 0; it < 8; ++it){
      int idx = it*256 + tid;
      int r = idx >> 4, c4 = idx & 15;
      float4 xv = *(const float4*)&Xs[(size_t)(rb + r)*128 + hk*64 + c4*4];
      Xl[(c4*4+0)*132 + r] = xv.x;
      Xl[(c4*4+1)*132 + r] = xv.y;
      Xl[(c4*4+2)*132 + r] = xv.z;
      Xl[(c4*4+3)*132 + r] = xv.w;
    }
    __syncthreads();
    #pragma unroll 2
    for (int kk = 0; kk < 64; ++kk){
      int kx = kk ^ kxor;
      float4 wa = *(const float4*)&Wl[kx*132 + cg*8];
      float4 wb = *(const float4*)&Wl[kx*132 + cg*8 + 4];
      float4 xa = *(const float4*)&Xl[kx*132 + rg*8];
      float4 xb = *(const float4*)&Xl[kx*132 + rg*8 + 4];
      float xs[8] = {xa.x, xa.y, xa.z, xa.w, xb.x, xb.y, xb.z, xb.w};
      float ws[8] = {wa.x, wa.y, wa.z, wa.w, wb.x, wb.y, wb.z, wb.w};
      #pragma unroll
      for (int rr = 0; rr < 8; ++rr)
        #pragma unroll
        for (int j = 0; j < 8; ++j) acc[rr][j] += xs[rr] * ws[j];
    }
  }
  #pragma unroll
  for (int rr = 0; rr < 8; ++rr){
    int r = rb + rg*8 + rr;
    float bv[8];
    if (pos){
      const float* pw = pew + (size_t)pos[r]*384 + cb + cg*8;
      #pragma unroll
      for (int j = 0; j < 8; ++j) bv[j] = pw[j];
    } else if (bias){
      #pragma unroll
      for (int j = 0; j < 8; ++j) bv[j] = bias[cb + cg*8 + j];
    } else {
      #pragma unroll
      for (int j = 0; j < 8; ++j) bv[j] = 0.f;
    }
    if (outb){
      u16 ob[8];
      #pragma unroll
      for (int j = 0; j < 8; ++j) ob[j] = (u16)bf16rne(acc[rr][j] + bv[j]);
      *(uint4*)(outb + (size_t)r*ldo + cb + cg*8) = *(const uint4*)ob;
    } else {
      float ov[8];
      #pragma unroll
      for (int j = 0; j < 8; ++j) ov[j] = acc[rr][j] + bv[j];
      float* op = out + (size_t)r*ldo + cb + cg*8;
      *(float4*)op       = *(const float4*)&ov[0];
      *(float4*)(op + 4) = *(const float4*)&ov[4];
    }
  }
}

// ---------------- qb_d = q_d . bk (per-row dot) ----------------
__global__ __launch_bounds__(256) void k_rowdot(
    const float* __restrict__ q, const float* __restrict__ bk,
    float* __restrict__ qb){
  int d = blockIdx.x * 4 + (threadIdx.x >> 6);
  int lane = threadIdx.x & 63;
  float2 qv = *(const float2*)&q[(size_t)d*128 + 2*lane];
  float2 bv = *(const float2*)&bk[2*lane];
  float p = wredf(qv.x * bv.x + qv.y * bv.y);
  if (lane == 0) qb[d] = p;
}

// ---------------- fused edge: one x_s gather per edge ----------------
// logit = (qt_d . x_s + qb_d)/sqrt(128); xagg_d = sum alpha x_s (no-max softmax:
// logits bounded |.|<~3, exact rescale). Empty dst -> zeros.
__global__ __launch_bounds__(256) void k_edge(
    const float* __restrict__ qt, const float* __restrict__ qb,
    const float* __restrict__ xsrc, const int* __restrict__ row_ptr,
    const int* __restrict__ col, float* __restrict__ xagg){
  int d = blockIdx.x * 4 + (threadIdx.x >> 6);
  int lane = threadIdx.x & 63;
  int e0 = row_ptr[d], e1 = row_ptr[d+1];
  if (e0 == e1){
    *(float2*)&xagg[(size_t)d*128 + 2*lane] = make_float2(0.f, 0.f);
    return;
  }
  float2 qv = *(const float2*)&qt[(size_t)d*128 + 2*lane];
  float qbd = qb[d];
  float ssum = 0.f, a0 = 0.f, a1 = 0.f;
  for (int e = e0; e < e1; ++e){
    int s = col[e];
    float2 xv = *(const float2*)&xsrc[(size_t)s*128 + 2*lane];
    float p = wredf(qv.x * xv.x + qv.y * xv.y);
    float el = __expf((p + qbd) * 0.08838834764831845f);
    ssum += el;
    a0 += el * xv.x;
    a1 += el * xv.y;
  }
  float inv = 1.f / ssum;
  *(float2*)&xagg[(size_t)d*128 + 2*lane] = make_float2(a0 * inv, a1 * inv);
}

// ---------------- relu(layernorm); optional +bv for deg>0 rows ----------------
__global__ __launch_bounds__(256) void k_lnrelu(
    const float* __restrict__ in, const float* __restrict__ g,
    const float* __restrict__ b, const float* __restrict__ bvv,
    const int* __restrict__ rowp, float* __restrict__ outp){
  int node = blockIdx.x * 4 + (threadIdx.x >> 6);
  int lane = threadIdx.x & 63;
  float x0 = in[(size_t)node*128 + 2*lane], x1 = in[(size_t)node*128 + 2*lane + 1];
  if (bvv && rowp[node+1] > rowp[node]){
    x0 += bvv[2*lane];
    x1 += bvv[2*lane + 1];
  }
  float s = wredf(x0 + x1);
  float qq = wredf(x0*x0 + x1*x1);
  float mu = s * 0.0078125f;
  float var = qq * 0.0078125f - mu*mu;
  float rstd = rsqrtf(var + 1e-5f);
  float y0 = (x0 - mu)*rstd*g[2*lane]   + b[2*lane];
  float y1 = (x1 - mu)*rstd*g[2*lane+1] + b[2*lane+1];
  outp[(size_t)node*128 + 2*lane]     = fmaxf(y0, 0.f);
  outp[(size_t)node*128 + 2*lane + 1] = fmaxf(y1, 0.f);
}

// ---------------- post-GRU relu(layernorm) in-place on bf16 node_out ----------------
__global__ __launch_bounds__(256) void k_postln(
    u16* __restrict__ no, const float* __restrict__ g, const float* __restrict__ b){
  int node = blockIdx.x * 4 + (threadIdx.x >> 6);
  int lane = threadIdx.x & 63;
  float x0 = bf2f(no[(size_t)node*128 + 2*lane]);
  float x1 = bf2f(no[(size_t)node*128 + 2*lane + 1]);
  float s = wredf(x0 + x1);
  float qq = wredf(x0*x0 + x1*x1);
  float mu = s * 0.0078125f;
  float var = qq * 0.0078125f - mu*mu;
  float rstd = rsqrtf(var + 1e-5f);
  float y0 = (x0 - mu)*rstd*g[2*lane]   + b[2*lane];
  float y1 = (x1 - mu)*rstd*g[2*lane+1] + b[2*lane+1];
  no[(size_t)node*128 + 2*lane]     = (u16)bf16rne(fmaxf(y0, 0.f));
  no[(size_t)node*128 + 2*lane + 1] = (u16)bf16rne(fmaxf(y1, 0.f));
}

// ---------------- cluster assignment ----------------
__global__ __launch_bounds__(256) void k_classify(
    const float* __restrict__ h, const float* __restrict__ cn,
    const int* __restrict__ batch, const int* __restrict__ callsq,
    int* __restrict__ grp, int* __restrict__ inv){
  int node = blockIdx.x * 4 + (threadIdx.x >> 6);
  int lane = threadIdx.x & 63;
  float h0 = h[(size_t)node*128 + 2*lane], h1 = h[(size_t)node*128 + 2*lane + 1];
  float p0 = h0*cn[      2*lane] + h1*cn[      2*lane+1];
  float p1 = h0*cn[128 + 2*lane] + h1*cn[128 + 2*lane+1];
  float p2 = h0*cn[256 + 2*lane] + h1*cn[256 + 2*lane+1];
  float p3 = h0*cn[384 + 2*lane] + h1*cn[384 + 2*lane+1];
  p0 = wredf(p0); p1 = wredf(p1); p2 = wredf(p2); p3 = wredf(p3);
  if (lane == 0){
    float best = p0; int bi = 0;
    if (p1 > best){ best = p1; bi = 1; }
    if (p2 > best){ best = p2; bi = 2; }
    if (p3 > best){ best = p3; bi = 3; }
    grp[node] = batch[node]*4 + bi;
    inv[callsq[node]] = node;
  }
}

// ---------------- grouping: chunked multisplit ----------------
__global__ __launch_bounds__(256) void k_g1(const int* __restrict__ inv,
                                            const int* __restrict__ grp,
                                            int* __restrict__ ch){
  __shared__ int hist[GG];
  int c = blockIdx.x, t = threadIdx.x;
  hist[t] = 0; hist[t + 256] = 0;
  __syncthreads();
  int g = grp[inv[c*256 + t]];
  atomicAdd(&hist[g], 1);
  __syncthreads();
  ch[c*GG + t] = hist[t];
  ch[c*GG + 256 + t] = hist[256 + t];
}
// parallel per-group scan over chunks: one block per group
__global__ void k_g2(int* __restrict__ ch, int* __restrict__ cnt){
  __shared__ int arr[512];
  int g = blockIdx.x, t = threadIdx.x;
  int v0 = (t < NCHUNK) ? ch[(size_t)t*GG + g] : 0;
  arr[t] = v0; __syncthreads();
  for (int off = 1; off < 512; off <<= 1){
    int v = (t >= off) ? arr[t - off] : 0;
    __syncthreads();
    arr[t] += v;
    __syncthreads();
  }
  if (t < NCHUNK) ch[(size_t)t*GG + g] = arr[t] - v0;   // exclusive
  if (t == 511) cnt[g] = arr[511];
}
__global__ __launch_bounds__(256) void k_g3(
    const int* __restrict__ inv, const int* __restrict__ grp,
    const int* __restrict__ ch, int* __restrict__ pos, int* __restrict__ gn){
  __shared__ int hist[GG];
  int c = blockIdx.x, t = threadIdx.x;
  hist[t] = 0; hist[t + 256] = 0;
  __syncthreads();
  int node = inv[c*256 + t];
  int g = grp[node];
  int lane = t & 63, w = t >> 6;
  int before = 0, total = 0;
  for (int j = 0; j < 64; ++j){
    int gj = __shfl(g, j);
    if (gj == g){ total++; if (j < lane) before++; }
  }
  int base = 0;
  for (int wv = 0; wv < 4; ++wv){
    if (w == wv){
      base = hist[g];
      if (before == total - 1) hist[g] = base + total;  // last lane of its g
    }
    __syncthreads();
  }
  int p = ch[c*GG + g] + base + before;
  pos[node] = p;
  gn[(size_t)g*SMAX + p] = node;
}

// ---------------- GRU v6 (r9 form): no in-loop LN, fast gates, 3-deep prefetch ----
__global__ __launch_bounds__(256)
__attribute__((amdgpu_waves_per_eu(2, 2)))
void k_gru(
    const u16* __restrict__ gi, const u32* __restrict__ wt,
    const float* __restrict__ bhh, const int* __restrict__ gn,
    const int* __restrict__ cnt, u16* __restrict__ node_out){
  __shared__ __align__(16) u16 hb16[2][128];   // double-buffered h (f16)
  int t = threadIdx.x;
  int j = t >> 1;              // output index 0..127
  int kh = t & 1;              // k-half 0/1
  int g = blockIdx.x;
  int my = cnt[g];
  if (my <= 1) return;
  uint4 wr_[8], wz_[8], wn_[8];
  {
    const uint4* wt4 = (const uint4*)wt;
    size_t b0 = (size_t)(0*128 + j)*16 + kh*8;
    size_t b1 = (size_t)(1*128 + j)*16 + kh*8;
    size_t b2 = (size_t)(2*128 + j)*16 + kh*8;
    #pragma unroll
    for (int s = 0; s < 8; ++s){
      wr_[s] = wt4[b0 + s];
      wz_[s] = wt4[b1 + s];
      wn_[s] = wt4[b2 + s];
    }
    #pragma unroll
    for (int s = 0; s < 8; ++s){
      PIN4(wr_[s]); PIN4(wz_[s]); PIN4(wn_[s]);
    }
  }
  if (t < 128) hb16[0][t] = 0;
  float br = bhh[j], bz = bhh[128 + j], bn = bhh[256 + j];
  const int* gnr = gn + (size_t)g*SMAX;
  float hprev = 0.f;
  int nA = gnr[0];
  int nB = gnr[min(1, my - 1)];
  int nC = gnr[min(2, my - 1)];
  const u16* gA = gi + (size_t)nA*384;
  const u16* gB = gi + (size_t)nB*384;
  const u16* gC = gi + (size_t)nC*384;
  float axr = bf2f(gA[j]), axz = bf2f(gA[128 + j]), axn = bf2f(gA[256 + j]);
  float bxr = bf2f(gB[j]), bxz = bf2f(gB[128 + j]), bxn = bf2f(gB[256 + j]);
  float cxr = bf2f(gC[j]), cxz = bf2f(gC[128 + j]), cxn = bf2f(gC[256 + j]);
  __syncthreads();
  for (int p = 0; p < my; ++p){
    int cur = p & 1, nxt = cur ^ 1;
    float xr = axr, xz = axz, xn = axn;
    int node = nA;
    axr = bxr; axz = bxz; axn = bxn; nA = nB;
    bxr = cxr; bxz = cxz; bxn = cxn; nB = nC;
    nC = gnr[min(p + 3, my - 1)];
    const u16* gN = gi + (size_t)nC*384;
    cxr = bf2f(gN[j]); cxz = bf2f(gN[128 + j]); cxn = bf2f(gN[256 + j]);
    const uint4* HB = (const uint4*)&hb16[cur][0];
    uint4 hh[8];
    #pragma unroll
    for (int s = 0; s < 8; ++s) hh[s] = HB[kh*8 + s];
    float ar = 0.f, az = 0.f, an = 0.f;
    #pragma unroll
    for (int s = 0; s < 8; ++s){
      ar = dot2f(wr_[s].x, hh[s].x, ar); az = dot2f(wz_[s].x, hh[s].x, az); an = dot2f(wn_[s].x, hh[s].x, an);
      ar = dot2f(wr_[s].y, hh[s].y, ar); az = dot2f(wz_[s].y, hh[s].y, az); an = dot2f(wn_[s].y, hh[s].y, an);
      ar = dot2f(wr_[s].z, hh[s].z, ar); az = dot2f(wz_[s].z, hh[s].z, az); an = dot2f(wn_[s].z, hh[s].z, an);
      ar = dot2f(wr_[s].w, hh[s].w, ar); az = dot2f(wz_[s].w, hh[s].w, az); an = dot2f(wn_[s].w, hh[s].w, an);
    }
    ar += __shfl_xor(ar, 1); az += __shfl_xor(az, 1); an += __shfl_xor(an, 1);
    ar += br; az += bz; an += bn;
    float er = __expf(-(xr + ar));
    float r  = frcp(1.f + er);
    float ez = __expf(-(xz + az));
    float z  = frcp(1.f + ez);
    float y  = xn + r * an;
    float e2 = __expf(-2.f * y);
    float n  = (1.f - e2) * frcp(1.f + e2);   // tanh(y)
    float hnew = n + z * (hprev - n);
    hprev = hnew;
    if (!kh){
      _Float16 hf = (_Float16)hnew;
      hb16[nxt][j] = __builtin_bit_cast(u16, hf);
      node_out[(size_t)node*128 + j] = (u16)bf16rne(hnew);
    }
    __syncthreads();
  }
}

// ---------------- head: gelu(lin1) -> sigmoid(lin2) ----------------
__global__ __launch_bounds__(256) void k_head(
    const float* __restrict__ h, const u16* __restrict__ node_out,
    const int* __restrict__ grp, const int* __restrict__ cnt,
    const float* __restrict__ l1W, const float* __restrict__ l1b,
    const float* __restrict__ l2W, const float* __restrict__ l2b,
    float* __restrict__ out){
  int node = blockIdx.x * 4 + (threadIdx.x >> 6);
  int lane = threadIdx.x & 63;
  bool single = (cnt[grp[node]] == 1);
  float x0, x1;
  if (single){
    x0 = h[(size_t)node*128 + 2*lane];
    x1 = h[(size_t)node*128 + 2*lane + 1];
  } else {
    x0 = bf2f(node_out[(size_t)node*128 + 2*lane]);
    x1 = bf2f(node_out[(size_t)node*128 + 2*lane + 1]);
  }
  float acc[8];
  #pragma unroll
  for (int j = 0; j < 8; ++j)
    acc[j] = x0 * l1W[(2*lane)*8 + j] + x1 * l1W[(2*lane + 1)*8 + j];
  #pragma unroll
  for (int o = 32; o; o >>= 1)
    #pragma unroll
    for (int j = 0; j < 8; ++j) acc[j] += __shfl_xor(acc[j], o);
  if (lane == 0){
    float zz = l2b[0];
    #pragma unroll
    for (int j = 0; j < 8; ++j){
      float xx = acc[j] + l1b[j];
      float ge = 0.5f * xx * (1.f + erff(xx * 0.7071067811865476f));
      zz += ge * l2W[j];
    }
    out[node] = 1.f / (1.f + expf(-zz));
  }
}

extern "C" void kernel_launch(void* const* d_in, const int* in_sizes, int n_in,
                              void* d_out, int out_size, void* d_ws, size_t ws_size,
                              hipStream_t stream){
  float* out = (float*)d_out;

  // ---- ws-size guard ----
  if (ws_size < WS_NEEDED){
    float code = -(float)(ws_size >> 20);
    k_sentinel<<<(out_size + 255)/256, 256, 0, stream>>>(out, out_size, code);
    return;
  }

  const float* x       = (const float*)d_in[0];
  const int*   tei     = (const int*)d_in[1];
  const int*   callsq  = (const int*)d_in[2];
  const int*   batch   = (const int*)d_in[3];
  const float* Wq      = (const float*)d_in[4];
  const float* bq      = (const float*)d_in[5];
  const float* Wk      = (const float*)d_in[6];
  const float* bk      = (const float*)d_in[7];
  const float* Wv      = (const float*)d_in[8];
  const float* bv      = (const float*)d_in[9];
  const float* Wsk     = (const float*)d_in[10];
  const float* bsk     = (const float*)d_in[11];
  const float* lng     = (const float*)d_in[12];
  const float* lnb     = (const float*)d_in[13];
  const float* centers = (const float*)d_in[14];
  const float* projW   = (const float*)d_in[15];
  const float* projb   = (const float*)d_in[16];
  const float* Wih     = (const float*)d_in[17];
  const float* Whh     = (const float*)d_in[18];
  const float* bih     = (const float*)d_in[19];
  const float* bhh     = (const float*)d_in[20];
  const float* sqg     = (const float*)d_in[21];
  const float* sqb     = (const float*)d_in[22];
  const float* l1W     = (const float*)d_in[23];
  const float* l1b     = (const float*)d_in[24];
  const float* l2W     = (const float*)d_in[25];
  const float* l2b     = (const float*)d_in[26];

  float* wf = (float*)d_ws;
  float* f_h    = wf + F_H;
  float* f_a    = wf + F_A;
  float* f_b    = wf + F_B;
  float* f_qb   = wf + F_QB;
  float* f_cn   = wf + F_CN;
  float* f_wkt  = wf + F_WKT;
  float* f_cw   = wf + F_CW;
  float* f_pew  = wf + F_PEW;
  float* f_peb  = wf + F_PEB;
  u16*   gi_bf  = (u16*)(wf + F_A);      // N x 384 bf16 (overlay, post-conv)
  u16*   no_bf  = (u16*)(wf + F_NODE);   // N x 128 bf16 node_out (overlay)
  int* wi = (int*)(wf + F_END);
  int* i_rowp = wi + I_ROWP;
  int* i_cur  = wi + I_CUR;
  int* i_col  = wi + I_COL;
  int* i_grp  = wi + I_GRP;
  int* i_inv  = wi + I_INV;
  int* i_pos  = wi + I_POS;
  int* i_gn   = wi + I_GN;
  int* i_cnt  = wi + I_CNT;
  int* i_ch   = wi + I_CH;
  int* i_bs   = wi + I_BS;
  u32* i_wt   = (u32*)(wi + I_WT);

  const int* esrc = tei;
  const int* edst = tei + EE;

  // CSR build
  k_zero<<<NN/256, 256, 0, stream>>>(i_cur);
  k_hist<<<EE/256, 256, 0, stream>>>(edst, i_cur);
  k_s1<<<NCHUNK, 256, 0, stream>>>(i_cur, i_bs);
  k_s2<<<1, 512, 0, stream>>>(i_bs);
  k_s3<<<NCHUNK, 256, 0, stream>>>(i_bs, i_rowp, i_cur);
  k_scatter<<<EE/256, 256, 0, stream>>>(esrc, edst, i_cur, i_col);

  // centers, PE tables, Wk^T, combined weights, packed f16 Whh rows
  k_setup<<<1, 128, 0, stream>>>(centers, f_cn, out + NN);
  k_pe<<<1000, 128, 0, stream>>>(projb, f_peb);
  k_pew<<<dim3(1000, 3), 128, 0, stream>>>(f_peb, Wih, bih, f_pew);
  k_tr<<<dim3(128, 3), 128, 0, stream>>>(Wk, f_wkt);
  k_combw<<<dim3(128, 3), 128, 0, stream>>>(projW, Wih, f_cw);
  k_packwhh16<<<dim3(64, 3), 128, 0, stream>>>(Whh, i_wt);

  // 3x TransformerConv + relu(LN) — edge phase v2 (single-gather fused)
  for (int i = 0; i < 3; ++i){
    const float* xin = i ? f_h : x;
    size_t wo = (size_t)i * 128 * 128, bo = (size_t)i * 128;
    // q = xin@Wq + bq -> A
    k_gemm<<<dim3(NN/128, 1), 256, 0, stream>>>(xin, Wq + wo, 128, nullptr, nullptr,
        bq + bo, nullptr, nullptr, f_a, nullptr, 128);
    // qb_d = q_d . bk
    k_rowdot<<<NN/4, 256, 0, stream>>>(f_a, bk + bo, f_qb);
    // qt = q@Wk^T -> B
    k_gemm<<<dim3(NN/128, 1), 256, 0, stream>>>(f_a, f_wkt + (size_t)i*16384, 128,
        nullptr, nullptr, nullptr, nullptr, nullptr, f_b, nullptr, 128);
    // fused edge: xagg -> A (one x_s gather per edge)
    k_edge<<<NN/4, 256, 0, stream>>>(f_b, f_qb, xin, i_rowp, i_col, f_a);
    // h2 = xagg@Wv + xin@Wsk + bsk -> B (K=256 fused GEMM)
    k_gemm<<<dim3(NN/128, 1), 256, 0, stream>>>(f_a, Wv + wo, 128, xin, Wsk + wo,
        bsk + bo, nullptr, nullptr, f_b, nullptr, 128);
    // h = relu(LN(h2 + bv[deg>0]))
    k_lnrelu<<<NN/4, 256, 0, stream>>>(f_b, lng + bo, lnb + bo, bv + bo, i_rowp, f_h);
  }

  // cluster assignment + grouping
  k_classify<<<NN/4, 256, 0, stream>>>(f_h, f_cn, batch, callsq, i_grp, i_inv);
  k_g1<<<NCHUNK, 256, 0, stream>>>(i_inv, i_grp, i_ch);
  k_g2<<<GG, 512, 0, stream>>>(i_ch, i_cnt);
  k_g3<<<NCHUNK, 256, 0, stream>>>(i_inv, i_grp, i_ch, i_pos, i_gn);

  // gi = h @ (projW@Wih^T) + PEW[pos] -> bf16 overlay on A (+ part of B)
  k_gemm<<<dim3(NN/128, 3), 256, 0, stream>>>(f_h, f_cw, 384, nullptr, nullptr,
      nullptr, f_pew, i_pos, nullptr, gi_bf, 384);

  // GRU (raw h out) -> post LN+ReLU in parallel
  k_gru<<<GG, 256, 0, stream>>>(gi_bf, i_wt, bhh, i_gn, i_cnt, no_bf);
  k_postln<<<NN/4, 256, 0, stream>>>(no_bf, sqg, sqb);

  // head
  k_head<<<NN/4, 256, 0, stream>>>(f_h, no_bf, i_grp, i_cnt, l1W, l1b, l2W, l2b, out);
}

// Round 12
// 2258.202 us; speedup vs baseline: 2.9774x; 1.1375x over previous
//
#include <hip/hip_runtime.h>

#define NN 128000
#define EE 1024000
#define HH 128
#define GG 512
#define SMAX 1000
#define NCHUNK 500   // 500 * 256 = 128000

typedef unsigned int u32;
typedef unsigned short u16;

// ---------------- workspace layout (floats, then ints) ----------------
// ws budget 256 MiB (measured r3). This layout: ~209.6 MB.
constexpr size_t NH     = (size_t)NN*HH;              // 16,384,000
constexpr size_t F_H    = 0;                          // h (persist, f32)
constexpr size_t F_A    = NH;                         // work A: xagg / gi overlay
constexpr size_t F_B    = 2*NH;                       // work B: qt / h2
constexpr size_t F_NODE = F_A + (size_t)NN*192;       // bf16 node_out overlay (in B)
constexpr size_t F_QB   = 3*NH;                       // N: qb_d
constexpr size_t F_CN   = F_QB   + NN;                // 4*128 normalized centers
constexpr size_t F_WKT  = F_CN   + 512;               // 3*128*128 Wk^T
constexpr size_t F_WQK  = F_WKT  + 3*16384;           // 3*128*128 Wq@Wk^T
constexpr size_t F_BQK  = F_WQK  + 3*16384;           // 3*128  Wk@bq
constexpr size_t F_WQBK = F_BQK  + 3*128;             // 3*128  Wq@bk
constexpr size_t F_QBB  = F_WQBK + 3*128;             // 8 (3 used) bq.bk
constexpr size_t F_CW   = F_QBB  + 8;                 // 128*384 projW@Wih^T
constexpr size_t F_PEW  = F_CW   + 128*384;           // 1000*384
constexpr size_t F_PEB  = F_PEW  + 1000*384;          // 1000*128
constexpr size_t F_END  = F_PEB  + 1000*128;

constexpr size_t I_ROWP = 0;                          // N+8 CSR row ptr
constexpr size_t I_CUR  = I_ROWP + NN + 8;
constexpr size_t I_COL  = I_CUR  + NN;                // E
constexpr size_t I_GRP  = I_COL  + EE;
constexpr size_t I_INV  = I_GRP  + NN;
constexpr size_t I_POS  = I_INV  + NN;
constexpr size_t I_GN   = I_POS  + NN;                // 512*1000
constexpr size_t I_CNT  = I_GN   + (size_t)GG*SMAX;
constexpr size_t I_CH   = I_CNT  + GG;                // 500*512
constexpr size_t I_BS   = I_CH   + (size_t)NCHUNK*GG;
constexpr size_t I_WT   = I_BS   + 512;               // 384*64 packed f16 Whh^T rows
constexpr size_t I_END  = I_WT   + 64*384;

constexpr size_t WS_NEEDED = F_END*4 + I_END*4;

__device__ inline float wredf(float v){
  #pragma unroll
  for (int o = 32; o; o >>= 1) v += __shfl_xor(v, o);
  return v;
}
__device__ inline u32 bf16rne(float f){
  u32 u = __float_as_uint(f);
  return (u + 0x7fffu + ((u >> 16) & 1u)) >> 16;
}
__device__ inline float bf2f(u16 u){
  return __uint_as_float(((u32)u) << 16);
}
__device__ inline float frcp(float x){
#if __has_builtin(__builtin_amdgcn_rcpf)
  return __builtin_amdgcn_rcpf(x);
#else
  return 1.f / x;
#endif
}

typedef _Float16 h2_t __attribute__((ext_vector_type(2)));
__device__ inline float dot2f(u32 w, u32 h, float acc){
#if __has_builtin(__builtin_amdgcn_fdot2)
  return __builtin_amdgcn_fdot2(__builtin_bit_cast(h2_t, w),
                                __builtin_bit_cast(h2_t, h), acc, false);
#else
  float r;
  asm("v_dot2_f32_f16 %0, %1, %2, %3" : "=v"(r) : "v"(w), "v"(h), "v"(acc));
  return r;
#endif
}
#define PIN4(v) asm volatile("" : "+v"((v).x), "+v"((v).y), "+v"((v).z), "+v"((v).w))

// ---------------- ws-size diagnostic sentinel ----------------
__global__ void k_sentinel(float* __restrict__ out, int n, float val){
  int i = blockIdx.x * 256 + threadIdx.x;
  if (i < n) out[i] = val;
}

// ---------------- CSR build ----------------
__global__ void k_zero(int* __restrict__ p){
  p[blockIdx.x * 256 + threadIdx.x] = 0;
}
__global__ void k_hist(const int* __restrict__ dst, int* __restrict__ deg){
  int e = blockIdx.x * 256 + threadIdx.x;
  atomicAdd(&deg[dst[e]], 1);
}
__global__ void k_s1(const int* __restrict__ deg, int* __restrict__ bsum){
  __shared__ int red[256];
  int t = threadIdx.x;
  red[t] = deg[blockIdx.x * 256 + t];
  __syncthreads();
  for (int s = 128; s; s >>= 1){ if (t < s) red[t] += red[t + s]; __syncthreads(); }
  if (!t) bsum[blockIdx.x] = red[0];
}
__global__ void k_s2(int* __restrict__ bsum){
  __shared__ int arr[512];
  int t = threadIdx.x;
  int v0 = (t < NCHUNK) ? bsum[t] : 0;
  arr[t] = v0; __syncthreads();
  for (int off = 1; off < 512; off <<= 1){
    int v = (t >= off) ? arr[t - off] : 0;
    __syncthreads();
    arr[t] += v;
    __syncthreads();
  }
  if (t < NCHUNK) bsum[t] = arr[t] - v0;   // exclusive
}
__global__ void k_s3(const int* __restrict__ bsum, int* __restrict__ row_ptr,
                     int* __restrict__ cursor){
  __shared__ int arr[256];
  int t = threadIdx.x;
  int i = blockIdx.x * 256 + t;
  int v0 = cursor[i];
  arr[t] = v0; __syncthreads();
  for (int off = 1; off < 256; off <<= 1){
    int v = (t >= off) ? arr[t - off] : 0;
    __syncthreads();
    arr[t] += v;
    __syncthreads();
  }
  int exc = arr[t] - v0 + bsum[blockIdx.x];
  row_ptr[i] = exc;
  cursor[i]  = exc;
  if (i == 0) row_ptr[NN] = EE;
}
__global__ void k_scatter(const int* __restrict__ src, const int* __restrict__ dst,
                          int* __restrict__ cursor, int* __restrict__ col){
  int e = blockIdx.x * 256 + threadIdx.x;
  int idx = atomicAdd(&cursor[dst[e]], 1);
  col[idx] = src[e];
}

// ---------------- centers: normalize + distance ----------------
__global__ void k_setup(const float* __restrict__ centers, float* __restrict__ cn,
                        float* __restrict__ dist_out){
  __shared__ float red[128];
  int t = threadIdx.x;
  for (int l = 0; l < 4; ++l){
    float v = centers[l*128 + t];
    red[t] = v * v; __syncthreads();
    for (int s = 64; s; s >>= 1){ if (t < s) red[t] += red[t + s]; __syncthreads(); }
    float nrm = sqrtf(red[0]);
    __syncthreads();
    cn[l*128 + t] = v / fmaxf(nrm, 1e-8f);
  }
  const int iu0[6] = {0,0,0,1,1,2}, iu1[6] = {1,2,3,2,3,3};
  __shared__ float dv[6];
  for (int p = 0; p < 6; ++p){
    float d = centers[iu0[p]*128 + t] - centers[iu1[p]*128 + t];
    red[t] = d * d; __syncthreads();
    for (int s = 64; s; s >>= 1){ if (t < s) red[t] += red[t + s]; __syncthreads(); }
    if (!t) dv[p] = sqrtf(red[0]);
    __syncthreads();
  }
  if (!t){
    float mean = 0.f;
    for (int p = 0; p < 6; ++p) mean += dv[p];
    mean /= 6.f;
    float var = 0.f;
    for (int p = 0; p < 6; ++p){ float d = dv[p] - mean; var += d * d; }
    var /= 5.f;                              // ddof=1
    dist_out[0] = -var;
  }
}

// ---------------- pos-enc tables + weight transforms ----------------
__global__ void k_pe(const float* __restrict__ projb, float* __restrict__ peb){
  int p = blockIdx.x, t = threadIdx.x;     // 1000 x 128
  float ex  = (float)(t >> 1) * (-2.0f * 9.210340371976184f / 128.0f);
  float ang = (float)p * expf(ex);
  float v = (t & 1) ? cosf(ang) : sinf(ang);
  peb[p*128 + t] = v + projb[t];
}
__global__ void k_pew(const float* __restrict__ peb, const float* __restrict__ Wih,
                      const float* __restrict__ bih, float* __restrict__ pew){
  int p = blockIdx.x;                       // 1000
  int j = blockIdx.y * 128 + threadIdx.x;   // 384
  const float* pb = peb + p*128;
  const float* wr = Wih + (size_t)j*128;
  float acc = bih[j];
  #pragma unroll 4
  for (int m = 0; m < 128; ++m) acc += pb[m] * wr[m];
  pew[(size_t)p*384 + j] = acc;
}
__global__ void k_combw(const float* __restrict__ projW, const float* __restrict__ Wih,
                        float* __restrict__ cw){
  int kk = blockIdx.x;                      // 128
  int j  = blockIdx.y * 128 + threadIdx.x;  // 384
  const float* pr = projW + (size_t)kk*128;
  const float* wr = Wih + (size_t)j*128;
  float acc = 0.f;
  #pragma unroll 4
  for (int m = 0; m < 128; ++m) acc += pr[m] * wr[m];
  cw[(size_t)kk*384 + j] = acc;
}
// Wk^T per layer
__global__ void k_tr(const float* __restrict__ Wk, float* __restrict__ wkt){
  int kk = blockIdx.x, l = blockIdx.y, c = threadIdx.x;
  wkt[(size_t)l*16384 + kk*128 + c] = Wk[(size_t)l*16384 + c*128 + kk];
}
// out[l][i] = row_i(M_l) . v_l   (M row-major 128x128 per layer)
__global__ void k_mv(const float* __restrict__ M, const float* __restrict__ v,
                     float* __restrict__ out){
  int l = blockIdx.x, i = threadIdx.x;
  const float* row = M + (size_t)l*16384 + (size_t)i*128;
  const float* vv = v + l*128;
  float acc = 0.f;
  #pragma unroll 4
  for (int j = 0; j < 128; ++j) acc += row[j] * vv[j];
  out[l*128 + i] = acc;
}
// qbb[l] = bq_l . bk_l
__global__ void k_bb(const float* __restrict__ bq, const float* __restrict__ bk,
                     float* __restrict__ qbb){
  __shared__ float red[128];
  int l = blockIdx.x, t = threadIdx.x;
  red[t] = bq[l*128 + t] * bk[l*128 + t];
  __syncthreads();
  for (int s = 64; s; s >>= 1){ if (t < s) red[t] += red[t + s]; __syncthreads(); }
  if (!t) qbb[l] = red[0];
}
// pack Whh rows as f16x2 along k
__global__ void k_packwhh16(const float* __restrict__ Whh, u32* __restrict__ wt){
  int kp = blockIdx.x;                      // 64
  int j  = blockIdx.y * 128 + threadIdx.x;  // 384
  _Float16 a = (_Float16)Whh[(size_t)j*128 + 2*kp];
  _Float16 b = (_Float16)Whh[(size_t)j*128 + 2*kp + 1];
  u32 lo = (u32)__builtin_bit_cast(u16, a);
  u32 hi = (u32)__builtin_bit_cast(u16, b);
  wt[(size_t)j*64 + kp] = (hi << 16) | lo;
}

// ---------------- GEMM v4: 128x128 tile, 8x8 acc; optional second K=128 source ----
__global__ __launch_bounds__(256, 2) void k_gemm(
    const float* __restrict__ X, const float* __restrict__ W, int ldw,
    const float* __restrict__ X2, const float* __restrict__ W2,
    const float* __restrict__ bias, const float* __restrict__ pew,
    const int* __restrict__ pos, float* __restrict__ out,
    u16* __restrict__ outb, int ldo){
  __shared__ __align__(16) float Wl[64*132];
  __shared__ __align__(16) float Xl[64*132];
  int tid = threadIdx.x;
  int rb = blockIdx.x * 128;
  int cb = blockIdx.y * 128;
  int rg = tid >> 4;
  int cg = tid & 15;
  int kxor = (cg >> 2) & 3;
  float acc[8][8];
  #pragma unroll
  for (int a = 0; a < 8; ++a)
    #pragma unroll
    for (int b = 0; b < 8; ++b) acc[a][b] = 0.f;
  int nhalf = X2 ? 4 : 2;
  for (int half = 0; half < nhalf; ++half){
    const float* Xs = (half < 2) ? X : X2;
    const float* Ws = (half < 2) ? W : W2;
    int ldws = (half < 2) ? ldw : 128;
    int hk = half & 1;
    __syncthreads();
    #pragma unroll
    for (int it = 0; it < 8; ++it){
      int idx = it*256 + tid;
      int kk = idx >> 5, c4 = idx & 31;
      *(float4*)&Wl[kk*132 + c4*4] =
          *(const float4*)&Ws[(size_t)(hk*64 + kk)*ldws + cb + c4*4];
    }
    #pragma unroll
    for (int it = 0; it < 8; ++it){
      int idx = it*256 + tid;
      int r = idx >> 4, c4 = idx & 15;
      float4 xv = *(const float4*)&Xs[(size_t)(rb + r)*128 + hk*64 + c4*4];
      Xl[(c4*4+0)*132 + r] = xv.x;
      Xl[(c4*4+1)*132 + r] = xv.y;
      Xl[(c4*4+2)*132 + r] = xv.z;
      Xl[(c4*4+3)*132 + r] = xv.w;
    }
    __syncthreads();
    #pragma unroll 2
    for (int kk = 0; kk < 64; ++kk){
      int kx = kk ^ kxor;
      float4 wa = *(const float4*)&Wl[kx*132 + cg*8];
      float4 wb = *(const float4*)&Wl[kx*132 + cg*8 + 4];
      float4 xa = *(const float4*)&Xl[kx*132 + rg*8];
      float4 xb = *(const float4*)&Xl[kx*132 + rg*8 + 4];
      float xs[8] = {xa.x, xa.y, xa.z, xa.w, xb.x, xb.y, xb.z, xb.w};
      float ws[8] = {wa.x, wa.y, wa.z, wa.w, wb.x, wb.y, wb.z, wb.w};
      #pragma unroll
      for (int rr = 0; rr < 8; ++rr)
        #pragma unroll
        for (int j = 0; j < 8; ++j) acc[rr][j] += xs[rr] * ws[j];
    }
  }
  #pragma unroll
  for (int rr = 0; rr < 8; ++rr){
    int r = rb + rg*8 + rr;
    float bv[8];
    if (pos){
      const float* pw = pew + (size_t)pos[r]*384 + cb + cg*8;
      #pragma unroll
      for (int j = 0; j < 8; ++j) bv[j] = pw[j];
    } else if (bias){
      #pragma unroll
      for (int j = 0; j < 8; ++j) bv[j] = bias[cb + cg*8 + j];
    } else {
      #pragma unroll
      for (int j = 0; j < 8; ++j) bv[j] = 0.f;
    }
    if (outb){
      u16 ob[8];
      #pragma unroll
      for (int j = 0; j < 8; ++j) ob[j] = (u16)bf16rne(acc[rr][j] + bv[j]);
      *(uint4*)(outb + (size_t)r*ldo + cb + cg*8) = *(const uint4*)ob;
    } else {
      float ov[8];
      #pragma unroll
      for (int j = 0; j < 8; ++j) ov[j] = acc[rr][j] + bv[j];
      float* op = out + (size_t)r*ldo + cb + cg*8;
      *(float4*)op       = *(const float4*)&ov[0];
      *(float4*)(op + 4) = *(const float4*)&ov[4];
    }
  }
}

// ---------------- qb_d = xin_d . wqbk + bqbk ----------------
__global__ __launch_bounds__(256) void k_rowdot(
    const float* __restrict__ x, const float* __restrict__ w,
    const float* __restrict__ scal, float* __restrict__ qb){
  int d = blockIdx.x * 4 + (threadIdx.x >> 6);
  int lane = threadIdx.x & 63;
  float2 xv = *(const float2*)&x[(size_t)d*128 + 2*lane];
  float2 wv = *(const float2*)&w[2*lane];
  float p = wredf(xv.x * wv.x + xv.y * wv.y);
  if (lane == 0) qb[d] = p + scal[0];
}

// ---------------- fused edge v3: 32 lanes/dst, float4 rows, prefetch ----------------
__global__ __launch_bounds__(256) void k_edge(
    const float* __restrict__ qt, const float* __restrict__ qb,
    const float* __restrict__ xsrc, const int* __restrict__ row_ptr,
    const int* __restrict__ col, float* __restrict__ xagg){
  int d = blockIdx.x * 8 + (threadIdx.x >> 5);
  int lane = threadIdx.x & 31;
  int e0 = row_ptr[d], e1 = row_ptr[d+1];
  if (e0 == e1){
    *(float4*)&xagg[(size_t)d*128 + lane*4] = make_float4(0.f, 0.f, 0.f, 0.f);
    return;
  }
  float4 qv = *(const float4*)&qt[(size_t)d*128 + lane*4];
  float qbd = qb[d];
  float ssum = 0.f, a0 = 0.f, a1 = 0.f, a2 = 0.f, a3 = 0.f;
  float4 xc = *(const float4*)&xsrc[(size_t)col[e0]*128 + lane*4];
  for (int e = e0; e < e1; ++e){
    float4 xn = xc;
    if (e + 1 < e1)
      xn = *(const float4*)&xsrc[(size_t)col[e+1]*128 + lane*4];
    float p = qv.x*xc.x + qv.y*xc.y + qv.z*xc.z + qv.w*xc.w;
    #pragma unroll
    for (int o = 16; o; o >>= 1) p += __shfl_xor(p, o);   // 32-lane reduce
    float el = __expf((p + qbd) * 0.08838834764831845f);
    ssum += el;
    a0 += el * xc.x; a1 += el * xc.y; a2 += el * xc.z; a3 += el * xc.w;
    xc = xn;
  }
  float inv = 1.f / ssum;
  *(float4*)&xagg[(size_t)d*128 + lane*4] =
      make_float4(a0*inv, a1*inv, a2*inv, a3*inv);
}

// ---------------- relu(layernorm); optional +bv for deg>0 rows ----------------
__global__ __launch_bounds__(256) void k_lnrelu(
    const float* __restrict__ in, const float* __restrict__ g,
    const float* __restrict__ b, const float* __restrict__ bvv,
    const int* __restrict__ rowp, float* __restrict__ outp){
  int node = blockIdx.x * 4 + (threadIdx.x >> 6);
  int lane = threadIdx.x & 63;
  float x0 = in[(size_t)node*128 + 2*lane], x1 = in[(size_t)node*128 + 2*lane + 1];
  if (bvv && rowp[node+1] > rowp[node]){
    x0 += bvv[2*lane];
    x1 += bvv[2*lane + 1];
  }
  float s = wredf(x0 + x1);
  float qq = wredf(x0*x0 + x1*x1);
  float mu = s * 0.0078125f;
  float var = qq * 0.0078125f - mu*mu;
  float rstd = rsqrtf(var + 1e-5f);
  float y0 = (x0 - mu)*rstd*g[2*lane]   + b[2*lane];
  float y1 = (x1 - mu)*rstd*g[2*lane+1] + b[2*lane+1];
  outp[(size_t)node*128 + 2*lane]     = fmaxf(y0, 0.f);
  outp[(size_t)node*128 + 2*lane + 1] = fmaxf(y1, 0.f);
}

// ---------------- conv-3 lnrelu fused with cluster assignment ----------------
__global__ __launch_bounds__(256) void k_lnrelu_cls(
    const float* __restrict__ in, const float* __restrict__ g,
    const float* __restrict__ b, const float* __restrict__ bvv,
    const int* __restrict__ rowp, float* __restrict__ outp,
    const float* __restrict__ cn, const int* __restrict__ batch,
    const int* __restrict__ callsq, int* __restrict__ grp, int* __restrict__ inv){
  int node = blockIdx.x * 4 + (threadIdx.x >> 6);
  int lane = threadIdx.x & 63;
  float x0 = in[(size_t)node*128 + 2*lane], x1 = in[(size_t)node*128 + 2*lane + 1];
  if (rowp[node+1] > rowp[node]){
    x0 += bvv[2*lane];
    x1 += bvv[2*lane + 1];
  }
  float s = wredf(x0 + x1);
  float qq = wredf(x0*x0 + x1*x1);
  float mu = s * 0.0078125f;
  float var = qq * 0.0078125f - mu*mu;
  float rstd = rsqrtf(var + 1e-5f);
  float y0 = fmaxf((x0 - mu)*rstd*g[2*lane]   + b[2*lane],   0.f);
  float y1 = fmaxf((x1 - mu)*rstd*g[2*lane+1] + b[2*lane+1], 0.f);
  outp[(size_t)node*128 + 2*lane]     = y0;
  outp[(size_t)node*128 + 2*lane + 1] = y1;
  // fused classify on (y0,y1)
  float p0 = y0*cn[      2*lane] + y1*cn[      2*lane+1];
  float p1 = y0*cn[128 + 2*lane] + y1*cn[128 + 2*lane+1];
  float p2 = y0*cn[256 + 2*lane] + y1*cn[256 + 2*lane+1];
  float p3 = y0*cn[384 + 2*lane] + y1*cn[384 + 2*lane+1];
  p0 = wredf(p0); p1 = wredf(p1); p2 = wredf(p2); p3 = wredf(p3);
  if (lane == 0){
    float best = p0; int bi = 0;
    if (p1 > best){ best = p1; bi = 1; }
    if (p2 > best){ best = p2; bi = 2; }
    if (p3 > best){ best = p3; bi = 3; }
    grp[node] = batch[node]*4 + bi;
    inv[callsq[node]] = node;
  }
}

// ---------------- grouping: chunked multisplit ----------------
__global__ __launch_bounds__(256) void k_g1(const int* __restrict__ inv,
                                            const int* __restrict__ grp,
                                            int* __restrict__ ch){
  __shared__ int hist[GG];
  int c = blockIdx.x, t = threadIdx.x;
  hist[t] = 0; hist[t + 256] = 0;
  __syncthreads();
  int g = grp[inv[c*256 + t]];
  atomicAdd(&hist[g], 1);
  __syncthreads();
  ch[c*GG + t] = hist[t];
  ch[c*GG + 256 + t] = hist[256 + t];
}
__global__ void k_g2(int* __restrict__ ch, int* __restrict__ cnt){
  __shared__ int arr[512];
  int g = blockIdx.x, t = threadIdx.x;
  int v0 = (t < NCHUNK) ? ch[(size_t)t*GG + g] : 0;
  arr[t] = v0; __syncthreads();
  for (int off = 1; off < 512; off <<= 1){
    int v = (t >= off) ? arr[t - off] : 0;
    __syncthreads();
    arr[t] += v;
    __syncthreads();
  }
  if (t < NCHUNK) ch[(size_t)t*GG + g] = arr[t] - v0;
  if (t == 511) cnt[g] = arr[511];
}
__global__ __launch_bounds__(256) void k_g3(
    const int* __restrict__ inv, const int* __restrict__ grp,
    const int* __restrict__ ch, int* __restrict__ pos, int* __restrict__ gn){
  __shared__ int hist[GG];
  int c = blockIdx.x, t = threadIdx.x;
  hist[t] = 0; hist[t + 256] = 0;
  __syncthreads();
  int node = inv[c*256 + t];
  int g = grp[node];
  int lane = t & 63, w = t >> 6;
  int before = 0, total = 0;
  for (int j = 0; j < 64; ++j){
    int gj = __shfl(g, j);
    if (gj == g){ total++; if (j < lane) before++; }
  }
  int base = 0;
  for (int wv = 0; wv < 4; ++wv){
    if (w == wv){
      base = hist[g];
      if (before == total - 1) hist[g] = base + total;
    }
    __syncthreads();
  }
  int p = ch[c*GG + g] + base + before;
  pos[node] = p;
  gn[(size_t)g*SMAX + p] = node;
}

// ---------------- GRU v8: v6 + s_setprio around the serial core ----------------
__global__ __launch_bounds__(256)
__attribute__((amdgpu_waves_per_eu(2, 2)))
void k_gru(
    const u16* __restrict__ gi, const u32* __restrict__ wt,
    const float* __restrict__ bhh, const int* __restrict__ gn,
    const int* __restrict__ cnt, u16* __restrict__ node_out){
  __shared__ __align__(16) u16 hb16[2][128];
  int t = threadIdx.x;
  int j = t >> 1;
  int kh = t & 1;
  int g = blockIdx.x;
  int my = cnt[g];
  if (my <= 1) return;
  uint4 wr_[8], wz_[8], wn_[8];
  {
    const uint4* wt4 = (const uint4*)wt;
    size_t b0 = (size_t)(0*128 + j)*16 + kh*8;
    size_t b1 = (size_t)(1*128 + j)*16 + kh*8;
    size_t b2 = (size_t)(2*128 + j)*16 + kh*8;
    #pragma unroll
    for (int s = 0; s < 8; ++s){
      wr_[s] = wt4[b0 + s];
      wz_[s] = wt4[b1 + s];
      wn_[s] = wt4[b2 + s];
    }
    #pragma unroll
    for (int s = 0; s < 8; ++s){
      PIN4(wr_[s]); PIN4(wz_[s]); PIN4(wn_[s]);
    }
  }
  if (t < 128) hb16[0][t] = 0;
  float br = bhh[j], bz = bhh[128 + j], bn = bhh[256 + j];
  const int* gnr = gn + (size_t)g*SMAX;
  float hprev = 0.f;
  int nA = gnr[0];
  int nB = gnr[min(1, my - 1)];
  int nC = gnr[min(2, my - 1)];
  const u16* gA = gi + (size_t)nA*384;
  const u16* gB = gi + (size_t)nB*384;
  const u16* gC = gi + (size_t)nC*384;
  float axr = bf2f(gA[j]), axz = bf2f(gA[128 + j]), axn = bf2f(gA[256 + j]);
  float bxr = bf2f(gB[j]), bxz = bf2f(gB[128 + j]), bxn = bf2f(gB[256 + j]);
  float cxr = bf2f(gC[j]), cxz = bf2f(gC[128 + j]), cxn = bf2f(gC[256 + j]);
  __syncthreads();
  for (int p = 0; p < my; ++p){
    int cur = p & 1, nxt = cur ^ 1;
    float xr = axr, xz = axz, xn = axn;
    int node = nA;
    axr = bxr; axz = bxz; axn = bxn; nA = nB;
    bxr = cxr; bxz = cxz; bxn = cxn; nB = nC;
    nC = gnr[min(p + 3, my - 1)];
    const u16* gN = gi + (size_t)nC*384;
    cxr = bf2f(gN[j]); cxz = bf2f(gN[128 + j]); cxn = bf2f(gN[256 + j]);
    const uint4* HB = (const uint4*)&hb16[cur][0];
    uint4 hh[8];
    #pragma unroll
    for (int s = 0; s < 8; ++s) hh[s] = HB[kh*8 + s];
    __builtin_amdgcn_s_setprio(1);
    float ar = 0.f, az = 0.f, an = 0.f;
    #pragma unroll
    for (int s = 0; s < 8; ++s){
      ar = dot2f(wr_[s].x, hh[s].x, ar); az = dot2f(wz_[s].x, hh[s].x, az); an = dot2f(wn_[s].x, hh[s].x, an);
      ar = dot2f(wr_[s].y, hh[s].y, ar); az = dot2f(wz_[s].y, hh[s].y, az); an = dot2f(wn_[s].y, hh[s].y, an);
      ar = dot2f(wr_[s].z, hh[s].z, ar); az = dot2f(wz_[s].z, hh[s].z, az); an = dot2f(wn_[s].z, hh[s].z, an);
      ar = dot2f(wr_[s].w, hh[s].w, ar); az = dot2f(wz_[s].w, hh[s].w, az); an = dot2f(wn_[s].w, hh[s].w, an);
    }
    ar += __shfl_xor(ar, 1); az += __shfl_xor(az, 1); an += __shfl_xor(an, 1);
    ar += br; az += bz; an += bn;
    float er = __expf(-(xr + ar));
    float r  = frcp(1.f + er);
    float ez = __expf(-(xz + az));
    float z  = frcp(1.f + ez);
    float y  = xn + r * an;
    float e2 = __expf(-2.f * y);
    float n  = (1.f - e2) * frcp(1.f + e2);
    float hnew = n + z * (hprev - n);
    __builtin_amdgcn_s_setprio(0);
    hprev = hnew;
    if (!kh){
      _Float16 hf = (_Float16)hnew;
      hb16[nxt][j] = __builtin_bit_cast(u16, hf);
      node_out[(size_t)node*128 + j] = (u16)bf16rne(hnew);
    }
    __syncthreads();
  }
}

// ---------------- head fused with post-GRU LN+ReLU ----------------
__global__ __launch_bounds__(256) void k_head(
    const float* __restrict__ h, const u16* __restrict__ node_out,
    const int* __restrict__ grp, const int* __restrict__ cnt,
    const float* __restrict__ sqg, const float* __restrict__ sqb,
    const float* __restrict__ l1W, const float* __restrict__ l1b,
    const float* __restrict__ l2W, const float* __restrict__ l2b,
    float* __restrict__ out){
  int node = blockIdx.x * 4 + (threadIdx.x >> 6);
  int lane = threadIdx.x & 63;
  bool single = (cnt[grp[node]] == 1);   // wave-uniform
  float x0, x1;
  if (single){
    x0 = h[(size_t)node*128 + 2*lane];
    x1 = h[(size_t)node*128 + 2*lane + 1];
  } else {
    float r0 = bf2f(node_out[(size_t)node*128 + 2*lane]);
    float r1 = bf2f(node_out[(size_t)node*128 + 2*lane + 1]);
    float s = wredf(r0 + r1);
    float qq = wredf(r0*r0 + r1*r1);
    float mu = s * 0.0078125f;
    float var = qq * 0.0078125f - mu*mu;
    float rstd = rsqrtf(var + 1e-5f);
    x0 = fmaxf((r0 - mu)*rstd*sqg[2*lane]   + sqb[2*lane],   0.f);
    x1 = fmaxf((r1 - mu)*rstd*sqg[2*lane+1] + sqb[2*lane+1], 0.f);
  }
  float acc[8];
  #pragma unroll
  for (int j = 0; j < 8; ++j)
    acc[j] = x0 * l1W[(2*lane)*8 + j] + x1 * l1W[(2*lane + 1)*8 + j];
  #pragma unroll
  for (int o = 32; o; o >>= 1)
    #pragma unroll
    for (int j = 0; j < 8; ++j) acc[j] += __shfl_xor(acc[j], o);
  if (lane == 0){
    float zz = l2b[0];
    #pragma unroll
    for (int j = 0; j < 8; ++j){
      float xx = acc[j] + l1b[j];
      float ge = 0.5f * xx * (1.f + erff(xx * 0.7071067811865476f));
      zz += ge * l2W[j];
    }
    out[node] = 1.f / (1.f + expf(-zz));
  }
}

extern "C" void kernel_launch(void* const* d_in, const int* in_sizes, int n_in,
                              void* d_out, int out_size, void* d_ws, size_t ws_size,
                              hipStream_t stream){
  float* out = (float*)d_out;

  // ---- ws-size guard ----
  if (ws_size < WS_NEEDED){
    float code = -(float)(ws_size >> 20);
    k_sentinel<<<(out_size + 255)/256, 256, 0, stream>>>(out, out_size, code);
    return;
  }

  const float* x       = (const float*)d_in[0];
  const int*   tei     = (const int*)d_in[1];
  const int*   callsq  = (const int*)d_in[2];
  const int*   batch   = (const int*)d_in[3];
  const float* Wq      = (const float*)d_in[4];
  const float* bq      = (const float*)d_in[5];
  const float* Wk      = (const float*)d_in[6];
  const float* bk      = (const float*)d_in[7];
  const float* Wv      = (const float*)d_in[8];
  const float* bv      = (const float*)d_in[9];
  const float* Wsk     = (const float*)d_in[10];
  const float* bsk     = (const float*)d_in[11];
  const float* lng     = (const float*)d_in[12];
  const float* lnb     = (const float*)d_in[13];
  const float* centers = (const float*)d_in[14];
  const float* projW   = (const float*)d_in[15];
  const float* projb   = (const float*)d_in[16];
  const float* Wih     = (const float*)d_in[17];
  const float* Whh     = (const float*)d_in[18];
  const float* bih     = (const float*)d_in[19];
  const float* bhh     = (const float*)d_in[20];
  const float* sqg     = (const float*)d_in[21];
  const float* sqb     = (const float*)d_in[22];
  const float* l1W     = (const float*)d_in[23];
  const float* l1b     = (const float*)d_in[24];
  const float* l2W     = (const float*)d_in[25];
  const float* l2b     = (const float*)d_in[26];

  float* wf = (float*)d_ws;
  float* f_h    = wf + F_H;
  float* f_a    = wf + F_A;
  float* f_b    = wf + F_B;
  float* f_qb   = wf + F_QB;
  float* f_cn   = wf + F_CN;
  float* f_wkt  = wf + F_WKT;
  float* f_wqk  = wf + F_WQK;
  float* f_bqk  = wf + F_BQK;
  float* f_wqbk = wf + F_WQBK;
  float* f_qbb  = wf + F_QBB;
  float* f_cw   = wf + F_CW;
  float* f_pew  = wf + F_PEW;
  float* f_peb  = wf + F_PEB;
  u16*   gi_bf  = (u16*)(wf + F_A);
  u16*   no_bf  = (u16*)(wf + F_NODE);
  int* wi = (int*)(wf + F_END);
  int* i_rowp = wi + I_ROWP;
  int* i_cur  = wi + I_CUR;
  int* i_col  = wi + I_COL;
  int* i_grp  = wi + I_GRP;
  int* i_inv  = wi + I_INV;
  int* i_pos  = wi + I_POS;
  int* i_gn   = wi + I_GN;
  int* i_cnt  = wi + I_CNT;
  int* i_ch   = wi + I_CH;
  int* i_bs   = wi + I_BS;
  u32* i_wt   = (u32*)(wi + I_WT);

  const int* esrc = tei;
  const int* edst = tei + EE;

  // CSR build
  k_zero<<<NN/256, 256, 0, stream>>>(i_cur);
  k_hist<<<EE/256, 256, 0, stream>>>(edst, i_cur);
  k_s1<<<NCHUNK, 256, 0, stream>>>(i_cur, i_bs);
  k_s2<<<1, 512, 0, stream>>>(i_bs);
  k_s3<<<NCHUNK, 256, 0, stream>>>(i_bs, i_rowp, i_cur);
  k_scatter<<<EE/256, 256, 0, stream>>>(esrc, edst, i_cur, i_col);

  // centers, PE tables, folded conv weights, packed f16 Whh rows
  k_setup<<<1, 128, 0, stream>>>(centers, f_cn, out + NN);
  k_pe<<<1000, 128, 0, stream>>>(projb, f_peb);
  k_pew<<<dim3(1000, 3), 128, 0, stream>>>(f_peb, Wih, bih, f_pew);
  k_tr<<<dim3(128, 3), 128, 0, stream>>>(Wk, f_wkt);
  for (int i = 0; i < 3; ++i)
    k_gemm<<<dim3(1, 1), 256, 0, stream>>>(Wq + (size_t)i*16384, f_wkt + (size_t)i*16384,
        128, nullptr, nullptr, nullptr, nullptr, nullptr, f_wqk + (size_t)i*16384,
        nullptr, 128);                              // Wqk = Wq@Wk^T
  k_mv<<<3, 128, 0, stream>>>(Wq, bk, f_wqbk);      // wqbk = Wq@bk
  k_mv<<<3, 128, 0, stream>>>(Wk, bq, f_bqk);       // bqk  = Wk@bq
  k_bb<<<3, 128, 0, stream>>>(bq, bk, f_qbb);       // bq.bk
  k_combw<<<dim3(128, 3), 128, 0, stream>>>(projW, Wih, f_cw);
  k_packwhh16<<<dim3(64, 3), 128, 0, stream>>>(Whh, i_wt);

  // 3x TransformerConv + relu(LN) — one GEMM + one matvec per conv for attention
  for (int i = 0; i < 3; ++i){
    const float* xin = i ? f_h : x;
    size_t wo = (size_t)i * 128 * 128, bo = (size_t)i * 128;
    // qt = xin@Wqk + bqk -> B
    k_gemm<<<dim3(NN/128, 1), 256, 0, stream>>>(xin, f_wqk + (size_t)i*16384, 128,
        nullptr, nullptr, f_bqk + bo, nullptr, nullptr, f_b, nullptr, 128);
    // qb_d = xin_d . wqbk + bq.bk
    k_rowdot<<<NN/4, 256, 0, stream>>>(xin, f_wqbk + bo, f_qbb + i, f_qb);
    // fused edge: xagg -> A
    k_edge<<<NN/8, 256, 0, stream>>>(f_b, f_qb, xin, i_rowp, i_col, f_a);
    // h2 = xagg@Wv + xin@Wsk + bsk -> B
    k_gemm<<<dim3(NN/128, 1), 256, 0, stream>>>(f_a, Wv + wo, 128, xin, Wsk + wo,
        bsk + bo, nullptr, nullptr, f_b, nullptr, 128);
    // h = relu(LN(h2 + bv[deg>0])); conv 3 also classifies
    if (i < 2)
      k_lnrelu<<<NN/4, 256, 0, stream>>>(f_b, lng + bo, lnb + bo, bv + bo, i_rowp, f_h);
    else
      k_lnrelu_cls<<<NN/4, 256, 0, stream>>>(f_b, lng + bo, lnb + bo, bv + bo, i_rowp,
          f_h, f_cn, batch, callsq, i_grp, i_inv);
  }

  // grouping
  k_g1<<<NCHUNK, 256, 0, stream>>>(i_inv, i_grp, i_ch);
  k_g2<<<GG, 512, 0, stream>>>(i_ch, i_cnt);
  k_g3<<<NCHUNK, 256, 0, stream>>>(i_inv, i_grp, i_ch, i_pos, i_gn);

  // gi = h @ (projW@Wih^T) + PEW[pos] -> bf16 overlay
  k_gemm<<<dim3(NN/128, 3), 256, 0, stream>>>(f_h, f_cw, 384, nullptr, nullptr,
      nullptr, f_pew, i_pos, nullptr, gi_bf, 384);

  // GRU (raw h out); LN+ReLU deferred into head
  k_gru<<<GG, 256, 0, stream>>>(gi_bf, i_wt, bhh, i_gn, i_cnt, no_bf);

  // head (fused post-LN)
  k_head<<<NN/4, 256, 0, stream>>>(f_h, no_bf, i_grp, i_cnt, sqg, sqb,
                                   l1W, l1b, l2W, l2b, out);
}

// Round 13
// 2118.272 us; speedup vs baseline: 3.1741x; 1.0661x over previous
//
#include <hip/hip_runtime.h>

#define NN 128000
#define EE 1024000
#define HH 128
#define GG 512
#define SMAX 1000
#define NCHUNK 500   // 500 * 256 = 128000

typedef unsigned int u32;
typedef unsigned short u16;

// ---------------- workspace layout (floats, then ints) ----------------
constexpr size_t NH     = (size_t)NN*HH;              // 16,384,000
constexpr size_t F_H    = 0;                          // h (persist, f32)
constexpr size_t F_A    = NH;                         // work A: xagg / gi overlay
constexpr size_t F_B    = 2*NH;                       // work B: qt / h2
constexpr size_t F_NODE = F_A + (size_t)NN*192;       // bf16 node_out overlay
constexpr size_t F_CN   = 3*NH;                       // 4*128 normalized centers
constexpr size_t F_WKT  = F_CN   + 512;               // 3*128*128 Wk^T
constexpr size_t F_WQK  = F_WKT  + 3*16384;           // 3*128*128 Wq@Wk^T
constexpr size_t F_BQK  = F_WQK  + 3*16384;           // 3*128  Wk@bq
constexpr size_t F_CW   = F_BQK  + 3*128;             // 128*384 projW@Wih^T
constexpr size_t F_PEW  = F_CW   + 128*384;           // 1000*384
constexpr size_t F_PEB  = F_PEW  + 1000*384;          // 1000*128
constexpr size_t F_END  = F_PEB  + 1000*128;

constexpr size_t I_ROWP = 0;                          // N+8 CSR row ptr
constexpr size_t I_CUR  = I_ROWP + NN + 8;
constexpr size_t I_COL  = I_CUR  + NN;                // E
constexpr size_t I_GRP  = I_COL  + EE;
constexpr size_t I_INV  = I_GRP  + NN;
constexpr size_t I_POS  = I_INV  + NN;
constexpr size_t I_GN   = I_POS  + NN;                // 512*1000
constexpr size_t I_CNT  = I_GN   + (size_t)GG*SMAX;
constexpr size_t I_CH   = I_CNT  + GG;                // 500*512
constexpr size_t I_BS   = I_CH   + (size_t)NCHUNK*GG;
constexpr size_t I_WT   = I_BS   + 512;               // 384*64 packed f16 Whh^T rows
constexpr size_t I_END  = I_WT   + 64*384;

constexpr size_t WS_NEEDED = F_END*4 + I_END*4;

__device__ inline float wredf(float v){
  #pragma unroll
  for (int o = 32; o; o >>= 1) v += __shfl_xor(v, o);
  return v;
}
__device__ inline u32 bf16rne(float f){
  u32 u = __float_as_uint(f);
  return (u + 0x7fffu + ((u >> 16) & 1u)) >> 16;
}
__device__ inline float bf2f(u16 u){
  return __uint_as_float(((u32)u) << 16);
}
__device__ inline float frcp(float x){
#if __has_builtin(__builtin_amdgcn_rcpf)
  return __builtin_amdgcn_rcpf(x);
#else
  return 1.f / x;
#endif
}

typedef _Float16 h2_t __attribute__((ext_vector_type(2)));
__device__ inline float dot2f(u32 w, u32 h, float acc){
#if __has_builtin(__builtin_amdgcn_fdot2)
  return __builtin_amdgcn_fdot2(__builtin_bit_cast(h2_t, w),
                                __builtin_bit_cast(h2_t, h), acc, false);
#else
  float r;
  asm("v_dot2_f32_f16 %0, %1, %2, %3" : "=v"(r) : "v"(w), "v"(h), "v"(acc));
  return r;
#endif
}
#define PIN4(v) asm volatile("" : "+v"((v).x), "+v"((v).y), "+v"((v).z), "+v"((v).w))

// ---------------- ws-size diagnostic sentinel ----------------
__global__ void k_sentinel(float* __restrict__ out, int n, float val){
  int i = blockIdx.x * 256 + threadIdx.x;
  if (i < n) out[i] = val;
}

// ---------------- CSR build ----------------
__global__ void k_zero(int* __restrict__ p){
  p[blockIdx.x * 256 + threadIdx.x] = 0;
}
__global__ void k_hist(const int* __restrict__ dst, int* __restrict__ deg){
  int e = blockIdx.x * 256 + threadIdx.x;
  atomicAdd(&deg[dst[e]], 1);
}
__global__ void k_s1(const int* __restrict__ deg, int* __restrict__ bsum){
  __shared__ int red[256];
  int t = threadIdx.x;
  red[t] = deg[blockIdx.x * 256 + t];
  __syncthreads();
  for (int s = 128; s; s >>= 1){ if (t < s) red[t] += red[t + s]; __syncthreads(); }
  if (!t) bsum[blockIdx.x] = red[0];
}
__global__ void k_s2(int* __restrict__ bsum){
  __shared__ int arr[512];
  int t = threadIdx.x;
  int v0 = (t < NCHUNK) ? bsum[t] : 0;
  arr[t] = v0; __syncthreads();
  for (int off = 1; off < 512; off <<= 1){
    int v = (t >= off) ? arr[t - off] : 0;
    __syncthreads();
    arr[t] += v;
    __syncthreads();
  }
  if (t < NCHUNK) bsum[t] = arr[t] - v0;   // exclusive
}
__global__ void k_s3(const int* __restrict__ bsum, int* __restrict__ row_ptr,
                     int* __restrict__ cursor){
  __shared__ int arr[256];
  int t = threadIdx.x;
  int i = blockIdx.x * 256 + t;
  int v0 = cursor[i];
  arr[t] = v0; __syncthreads();
  for (int off = 1; off < 256; off <<= 1){
    int v = (t >= off) ? arr[t - off] : 0;
    __syncthreads();
    arr[t] += v;
    __syncthreads();
  }
  int exc = arr[t] - v0 + bsum[blockIdx.x];
  row_ptr[i] = exc;
  cursor[i]  = exc;
  if (i == 0) row_ptr[NN] = EE;
}
__global__ void k_scatter(const int* __restrict__ src, const int* __restrict__ dst,
                          int* __restrict__ cursor, int* __restrict__ col){
  int e = blockIdx.x * 256 + threadIdx.x;
  int idx = atomicAdd(&cursor[dst[e]], 1);
  col[idx] = src[e];
}

// ---------------- centers: normalize + distance ----------------
__global__ void k_setup(const float* __restrict__ centers, float* __restrict__ cn,
                        float* __restrict__ dist_out){
  __shared__ float red[128];
  int t = threadIdx.x;
  for (int l = 0; l < 4; ++l){
    float v = centers[l*128 + t];
    red[t] = v * v; __syncthreads();
    for (int s = 64; s; s >>= 1){ if (t < s) red[t] += red[t + s]; __syncthreads(); }
    float nrm = sqrtf(red[0]);
    __syncthreads();
    cn[l*128 + t] = v / fmaxf(nrm, 1e-8f);
  }
  const int iu0[6] = {0,0,0,1,1,2}, iu1[6] = {1,2,3,2,3,3};
  __shared__ float dv[6];
  for (int p = 0; p < 6; ++p){
    float d = centers[iu0[p]*128 + t] - centers[iu1[p]*128 + t];
    red[t] = d * d; __syncthreads();
    for (int s = 64; s; s >>= 1){ if (t < s) red[t] += red[t + s]; __syncthreads(); }
    if (!t) dv[p] = sqrtf(red[0]);
    __syncthreads();
  }
  if (!t){
    float mean = 0.f;
    for (int p = 0; p < 6; ++p) mean += dv[p];
    mean /= 6.f;
    float var = 0.f;
    for (int p = 0; p < 6; ++p){ float d = dv[p] - mean; var += d * d; }
    var /= 5.f;                              // ddof=1
    dist_out[0] = -var;
  }
}

// ---------------- pos-enc tables + weight transforms ----------------
__global__ void k_pe(const float* __restrict__ projb, float* __restrict__ peb){
  int p = blockIdx.x, t = threadIdx.x;     // 1000 x 128
  float ex  = (float)(t >> 1) * (-2.0f * 9.210340371976184f / 128.0f);
  float ang = (float)p * expf(ex);
  float v = (t & 1) ? cosf(ang) : sinf(ang);
  peb[p*128 + t] = v + projb[t];
}
__global__ void k_pew(const float* __restrict__ peb, const float* __restrict__ Wih,
                      const float* __restrict__ bih, float* __restrict__ pew){
  int p = blockIdx.x;                       // 1000
  int j = blockIdx.y * 128 + threadIdx.x;   // 384
  const float* pb = peb + p*128;
  const float* wr = Wih + (size_t)j*128;
  float acc = bih[j];
  #pragma unroll 4
  for (int m = 0; m < 128; ++m) acc += pb[m] * wr[m];
  pew[(size_t)p*384 + j] = acc;
}
__global__ void k_combw(const float* __restrict__ projW, const float* __restrict__ Wih,
                        float* __restrict__ cw){
  int kk = blockIdx.x;                      // 128
  int j  = blockIdx.y * 128 + threadIdx.x;  // 384
  const float* pr = projW + (size_t)kk*128;
  const float* wr = Wih + (size_t)j*128;
  float acc = 0.f;
  #pragma unroll 4
  for (int m = 0; m < 128; ++m) acc += pr[m] * wr[m];
  cw[(size_t)kk*384 + j] = acc;
}
// Wk^T per layer
__global__ void k_tr(const float* __restrict__ Wk, float* __restrict__ wkt){
  int kk = blockIdx.x, l = blockIdx.y, c = threadIdx.x;
  wkt[(size_t)l*16384 + kk*128 + c] = Wk[(size_t)l*16384 + c*128 + kk];
}
// out[l][i] = row_i(M_l) . v_l
__global__ void k_mv(const float* __restrict__ M, const float* __restrict__ v,
                     float* __restrict__ out){
  int l = blockIdx.x, i = threadIdx.x;
  const float* row = M + (size_t)l*16384 + (size_t)i*128;
  const float* vv = v + l*128;
  float acc = 0.f;
  #pragma unroll 4
  for (int j = 0; j < 128; ++j) acc += row[j] * vv[j];
  out[l*128 + i] = acc;
}
// pack Whh rows as f16x2 along k
__global__ void k_packwhh16(const float* __restrict__ Whh, u32* __restrict__ wt){
  int kp = blockIdx.x;                      // 64
  int j  = blockIdx.y * 128 + threadIdx.x;  // 384
  _Float16 a = (_Float16)Whh[(size_t)j*128 + 2*kp];
  _Float16 b = (_Float16)Whh[(size_t)j*128 + 2*kp + 1];
  u32 lo = (u32)__builtin_bit_cast(u16, a);
  u32 hi = (u32)__builtin_bit_cast(u16, b);
  wt[(size_t)j*64 + kp] = (hi << 16) | lo;
}

// ---------------- GEMM v5: 128x128 tile, 8x8 acc; optional K=256; optional LN ----
// lng!=null (requires blockIdx.y==0, ldo==128): epilogue does +bias(+bvv if deg>0),
// row LN (16-lane shfl), ReLU, writes f32 out. Saves a full N*128 pass.
__global__ __launch_bounds__(256, 2) void k_gemm(
    const float* __restrict__ X, const float* __restrict__ W, int ldw,
    const float* __restrict__ X2, const float* __restrict__ W2,
    const float* __restrict__ bias, const float* __restrict__ pew,
    const int* __restrict__ pos, float* __restrict__ out,
    u16* __restrict__ outb, int ldo,
    const float* __restrict__ lng, const float* __restrict__ lnb,
    const float* __restrict__ bvv, const int* __restrict__ rowp){
  __shared__ __align__(16) float Wl[64*132];
  __shared__ __align__(16) float Xl[64*132];
  int tid = threadIdx.x;
  int rb = blockIdx.x * 128;
  int cb = blockIdx.y * 128;
  int rg = tid >> 4;
  int cg = tid & 15;
  int kxor = (cg >> 2) & 3;
  float acc[8][8];
  #pragma unroll
  for (int a = 0; a < 8; ++a)
    #pragma unroll
    for (int b = 0; b < 8; ++b) acc[a][b] = 0.f;
  int nhalf = X2 ? 4 : 2;
  for (int half = 0; half < nhalf; ++half){
    const float* Xs = (half < 2) ? X : X2;
    const float* Ws = (half < 2) ? W : W2;
    int ldws = (half < 2) ? ldw : 128;
    int hk = half & 1;
    __syncthreads();
    #pragma unroll
    for (int it = 0; it < 8; ++it){
      int idx = it*256 + tid;
      int kk = idx >> 5, c4 = idx & 31;
      *(float4*)&Wl[kk*132 + c4*4] =
          *(const float4*)&Ws[(size_t)(hk*64 + kk)*ldws + cb + c4*4];
    }
    #pragma unroll
    for (int it = 0; it < 8; ++it){
      int idx = it*256 + tid;
      int r = idx >> 4, c4 = idx & 15;
      float4 xv = *(const float4*)&Xs[(size_t)(rb + r)*128 + hk*64 + c4*4];
      Xl[(c4*4+0)*132 + r] = xv.x;
      Xl[(c4*4+1)*132 + r] = xv.y;
      Xl[(c4*4+2)*132 + r] = xv.z;
      Xl[(c4*4+3)*132 + r] = xv.w;
    }
    __syncthreads();
    #pragma unroll 2
    for (int kk = 0; kk < 64; ++kk){
      int kx = kk ^ kxor;
      float4 wa = *(const float4*)&Wl[kx*132 + cg*8];
      float4 wb = *(const float4*)&Wl[kx*132 + cg*8 + 4];
      float4 xa = *(const float4*)&Xl[kx*132 + rg*8];
      float4 xb = *(const float4*)&Xl[kx*132 + rg*8 + 4];
      float xs[8] = {xa.x, xa.y, xa.z, xa.w, xb.x, xb.y, xb.z, xb.w};
      float ws[8] = {wa.x, wa.y, wa.z, wa.w, wb.x, wb.y, wb.z, wb.w};
      #pragma unroll
      for (int rr = 0; rr < 8; ++rr)
        #pragma unroll
        for (int j = 0; j < 8; ++j) acc[rr][j] += xs[rr] * ws[j];
    }
  }
  if (lng){
    // fused +bias(+bv) -> LN -> ReLU -> store (full-width rows, cb==0)
    float gv[8], bl[8], bb[8], vv[8];
    #pragma unroll
    for (int j = 0; j < 8; ++j){
      int c = cg*8 + j;
      gv[j] = lng[c]; bl[j] = lnb[c]; bb[j] = bias[c]; vv[j] = bvv[c];
    }
    #pragma unroll
    for (int rr = 0; rr < 8; ++rr){
      int r = rb + rg*8 + rr;
      bool deg = rowp[r+1] > rowp[r];
      float rs = 0.f, rq = 0.f;
      #pragma unroll
      for (int j = 0; j < 8; ++j){
        float v = acc[rr][j] + bb[j] + (deg ? vv[j] : 0.f);
        acc[rr][j] = v;
        rs += v; rq += v*v;
      }
      #pragma unroll
      for (int o = 8; o; o >>= 1){ rs += __shfl_xor(rs, o); rq += __shfl_xor(rq, o); }
      float mu = rs * 0.0078125f;
      float var = rq * 0.0078125f - mu*mu;
      float rstd = rsqrtf(var + 1e-5f);
      float ov[8];
      #pragma unroll
      for (int j = 0; j < 8; ++j)
        ov[j] = fmaxf((acc[rr][j] - mu)*rstd*gv[j] + bl[j], 0.f);
      float* op = out + (size_t)r*128 + cg*8;
      *(float4*)op       = *(const float4*)&ov[0];
      *(float4*)(op + 4) = *(const float4*)&ov[4];
    }
    return;
  }
  #pragma unroll
  for (int rr = 0; rr < 8; ++rr){
    int r = rb + rg*8 + rr;
    float bv[8];
    if (pos){
      const float* pw = pew + (size_t)pos[r]*384 + cb + cg*8;
      #pragma unroll
      for (int j = 0; j < 8; ++j) bv[j] = pw[j];
    } else if (bias){
      #pragma unroll
      for (int j = 0; j < 8; ++j) bv[j] = bias[cb + cg*8 + j];
    } else {
      #pragma unroll
      for (int j = 0; j < 8; ++j) bv[j] = 0.f;
    }
    if (outb){
      u16 ob[8];
      #pragma unroll
      for (int j = 0; j < 8; ++j) ob[j] = (u16)bf16rne(acc[rr][j] + bv[j]);
      *(uint4*)(outb + (size_t)r*ldo + cb + cg*8) = *(const uint4*)ob;
    } else {
      float ov[8];
      #pragma unroll
      for (int j = 0; j < 8; ++j) ov[j] = acc[rr][j] + bv[j];
      float* op = out + (size_t)r*ldo + cb + cg*8;
      *(float4*)op       = *(const float4*)&ov[0];
      *(float4*)(op + 4) = *(const float4*)&ov[4];
    }
  }
}

// ---------------- fused edge v4: no qb (softmax shift-invariance), pair-unrolled ---
__global__ __launch_bounds__(256) void k_edge(
    const float* __restrict__ qt, const float* __restrict__ xsrc,
    const int* __restrict__ row_ptr, const int* __restrict__ col,
    float* __restrict__ xagg){
  int d = blockIdx.x * 8 + (threadIdx.x >> 5);
  int lane = threadIdx.x & 31;
  int e0 = row_ptr[d], e1 = row_ptr[d+1];
  if (e0 == e1){
    *(float4*)&xagg[(size_t)d*128 + lane*4] = make_float4(0.f, 0.f, 0.f, 0.f);
    return;
  }
  const float S = 0.08838834764831845f;   // 1/sqrt(128)
  float4 qv = *(const float4*)&qt[(size_t)d*128 + lane*4];
  float ss0 = 0.f, ss1 = 0.f;
  float4 A0 = make_float4(0.f,0.f,0.f,0.f), A1 = make_float4(0.f,0.f,0.f,0.f);
  int e = e0;
  for (; e + 1 < e1; e += 2){
    float4 x0 = *(const float4*)&xsrc[(size_t)col[e]  *128 + lane*4];
    float4 x1 = *(const float4*)&xsrc[(size_t)col[e+1]*128 + lane*4];
    float p0 = qv.x*x0.x + qv.y*x0.y + qv.z*x0.z + qv.w*x0.w;
    float p1 = qv.x*x1.x + qv.y*x1.y + qv.z*x1.z + qv.w*x1.w;
    #pragma unroll
    for (int o = 16; o; o >>= 1){ p0 += __shfl_xor(p0, o); p1 += __shfl_xor(p1, o); }
    float el0 = __expf(p0 * S);
    float el1 = __expf(p1 * S);
    ss0 += el0; ss1 += el1;
    A0.x += el0*x0.x; A0.y += el0*x0.y; A0.z += el0*x0.z; A0.w += el0*x0.w;
    A1.x += el1*x1.x; A1.y += el1*x1.y; A1.z += el1*x1.z; A1.w += el1*x1.w;
  }
  if (e < e1){
    float4 x0 = *(const float4*)&xsrc[(size_t)col[e]*128 + lane*4];
    float p0 = qv.x*x0.x + qv.y*x0.y + qv.z*x0.z + qv.w*x0.w;
    #pragma unroll
    for (int o = 16; o; o >>= 1) p0 += __shfl_xor(p0, o);
    float el0 = __expf(p0 * S);
    ss0 += el0;
    A0.x += el0*x0.x; A0.y += el0*x0.y; A0.z += el0*x0.z; A0.w += el0*x0.w;
  }
  float inv = 1.f / (ss0 + ss1);
  *(float4*)&xagg[(size_t)d*128 + lane*4] =
      make_float4((A0.x+A1.x)*inv, (A0.y+A1.y)*inv, (A0.z+A1.z)*inv, (A0.w+A1.w)*inv);
}

// ---------------- conv-3 lnrelu fused with cluster assignment ----------------
__global__ __launch_bounds__(256) void k_lnrelu_cls(
    const float* __restrict__ in, const float* __restrict__ g,
    const float* __restrict__ b, const float* __restrict__ bvv,
    const int* __restrict__ rowp, float* __restrict__ outp,
    const float* __restrict__ cn, const int* __restrict__ batch,
    const int* __restrict__ callsq, int* __restrict__ grp, int* __restrict__ inv){
  int node = blockIdx.x * 4 + (threadIdx.x >> 6);
  int lane = threadIdx.x & 63;
  float x0 = in[(size_t)node*128 + 2*lane], x1 = in[(size_t)node*128 + 2*lane + 1];
  if (rowp[node+1] > rowp[node]){
    x0 += bvv[2*lane];
    x1 += bvv[2*lane + 1];
  }
  float s = wredf(x0 + x1);
  float qq = wredf(x0*x0 + x1*x1);
  float mu = s * 0.0078125f;
  float var = qq * 0.0078125f - mu*mu;
  float rstd = rsqrtf(var + 1e-5f);
  float y0 = fmaxf((x0 - mu)*rstd*g[2*lane]   + b[2*lane],   0.f);
  float y1 = fmaxf((x1 - mu)*rstd*g[2*lane+1] + b[2*lane+1], 0.f);
  outp[(size_t)node*128 + 2*lane]     = y0;
  outp[(size_t)node*128 + 2*lane + 1] = y1;
  float p0 = y0*cn[      2*lane] + y1*cn[      2*lane+1];
  float p1 = y0*cn[128 + 2*lane] + y1*cn[128 + 2*lane+1];
  float p2 = y0*cn[256 + 2*lane] + y1*cn[256 + 2*lane+1];
  float p3 = y0*cn[384 + 2*lane] + y1*cn[384 + 2*lane+1];
  p0 = wredf(p0); p1 = wredf(p1); p2 = wredf(p2); p3 = wredf(p3);
  if (lane == 0){
    float best = p0; int bi = 0;
    if (p1 > best){ best = p1; bi = 1; }
    if (p2 > best){ best = p2; bi = 2; }
    if (p3 > best){ best = p3; bi = 3; }
    grp[node] = batch[node]*4 + bi;
    inv[callsq[node]] = node;
  }
}

// ---------------- grouping: chunked multisplit ----------------
__global__ __launch_bounds__(256) void k_g1(const int* __restrict__ inv,
                                            const int* __restrict__ grp,
                                            int* __restrict__ ch){
  __shared__ int hist[GG];
  int c = blockIdx.x, t = threadIdx.x;
  hist[t] = 0; hist[t + 256] = 0;
  __syncthreads();
  int g = grp[inv[c*256 + t]];
  atomicAdd(&hist[g], 1);
  __syncthreads();
  ch[c*GG + t] = hist[t];
  ch[c*GG + 256 + t] = hist[256 + t];
}
__global__ void k_g2(int* __restrict__ ch, int* __restrict__ cnt){
  __shared__ int arr[512];
  int g = blockIdx.x, t = threadIdx.x;
  int v0 = (t < NCHUNK) ? ch[(size_t)t*GG + g] : 0;
  arr[t] = v0; __syncthreads();
  for (int off = 1; off < 512; off <<= 1){
    int v = (t >= off) ? arr[t - off] : 0;
    __syncthreads();
    arr[t] += v;
    __syncthreads();
  }
  if (t < NCHUNK) ch[(size_t)t*GG + g] = arr[t] - v0;
  if (t == 511) cnt[g] = arr[511];
}
__global__ __launch_bounds__(256) void k_g3(
    const int* __restrict__ inv, const int* __restrict__ grp,
    const int* __restrict__ ch, int* __restrict__ pos, int* __restrict__ gn){
  __shared__ int hist[GG];
  int c = blockIdx.x, t = threadIdx.x;
  hist[t] = 0; hist[t + 256] = 0;
  __syncthreads();
  int node = inv[c*256 + t];
  int g = grp[node];
  int lane = t & 63, w = t >> 6;
  int before = 0, total = 0;
  for (int j = 0; j < 64; ++j){
    int gj = __shfl(g, j);
    if (gj == g){ total++; if (j < lane) before++; }
  }
  int base = 0;
  for (int wv = 0; wv < 4; ++wv){
    if (w == wv){
      base = hist[g];
      if (before == total - 1) hist[g] = base + total;
    }
    __syncthreads();
  }
  int p = ch[c*GG + g] + base + before;
  pos[node] = p;
  gn[(size_t)g*SMAX + p] = node;
}

// ---------------- GRU v8: pinned VGPR weights, 1 barrier/step, setprio ----------
__global__ __launch_bounds__(256)
__attribute__((amdgpu_waves_per_eu(2, 2)))
void k_gru(
    const u16* __restrict__ gi, const u32* __restrict__ wt,
    const float* __restrict__ bhh, const int* __restrict__ gn,
    const int* __restrict__ cnt, u16* __restrict__ node_out){
  __shared__ __align__(16) u16 hb16[2][128];
  int t = threadIdx.x;
  int j = t >> 1;
  int kh = t & 1;
  int g = blockIdx.x;
  int my = cnt[g];
  if (my <= 1) return;
  uint4 wr_[8], wz_[8], wn_[8];
  {
    const uint4* wt4 = (const uint4*)wt;
    size_t b0 = (size_t)(0*128 + j)*16 + kh*8;
    size_t b1 = (size_t)(1*128 + j)*16 + kh*8;
    size_t b2 = (size_t)(2*128 + j)*16 + kh*8;
    #pragma unroll
    for (int s = 0; s < 8; ++s){
      wr_[s] = wt4[b0 + s];
      wz_[s] = wt4[b1 + s];
      wn_[s] = wt4[b2 + s];
    }
    #pragma unroll
    for (int s = 0; s < 8; ++s){
      PIN4(wr_[s]); PIN4(wz_[s]); PIN4(wn_[s]);
    }
  }
  if (t < 128) hb16[0][t] = 0;
  float br = bhh[j], bz = bhh[128 + j], bn = bhh[256 + j];
  const int* gnr = gn + (size_t)g*SMAX;
  float hprev = 0.f;
  int nA = gnr[0];
  int nB = gnr[min(1, my - 1)];
  int nC = gnr[min(2, my - 1)];
  const u16* gA = gi + (size_t)nA*384;
  const u16* gB = gi + (size_t)nB*384;
  const u16* gC = gi + (size_t)nC*384;
  float axr = bf2f(gA[j]), axz = bf2f(gA[128 + j]), axn = bf2f(gA[256 + j]);
  float bxr = bf2f(gB[j]), bxz = bf2f(gB[128 + j]), bxn = bf2f(gB[256 + j]);
  float cxr = bf2f(gC[j]), cxz = bf2f(gC[128 + j]), cxn = bf2f(gC[256 + j]);
  __syncthreads();
  for (int p = 0; p < my; ++p){
    int cur = p & 1, nxt = cur ^ 1;
    float xr = axr, xz = axz, xn = axn;
    int node = nA;
    axr = bxr; axz = bxz; axn = bxn; nA = nB;
    bxr = cxr; bxz = cxz; bxn = cxn; nB = nC;
    nC = gnr[min(p + 3, my - 1)];
    const u16* gN = gi + (size_t)nC*384;
    cxr = bf2f(gN[j]); cxz = bf2f(gN[128 + j]); cxn = bf2f(gN[256 + j]);
    const uint4* HB = (const uint4*)&hb16[cur][0];
    uint4 hh[8];
    #pragma unroll
    for (int s = 0; s < 8; ++s) hh[s] = HB[kh*8 + s];
    __builtin_amdgcn_s_setprio(1);
    float ar = 0.f, az = 0.f, an = 0.f;
    #pragma unroll
    for (int s = 0; s < 8; ++s){
      ar = dot2f(wr_[s].x, hh[s].x, ar); az = dot2f(wz_[s].x, hh[s].x, az); an = dot2f(wn_[s].x, hh[s].x, an);
      ar = dot2f(wr_[s].y, hh[s].y, ar); az = dot2f(wz_[s].y, hh[s].y, az); an = dot2f(wn_[s].y, hh[s].y, an);
      ar = dot2f(wr_[s].z, hh[s].z, ar); az = dot2f(wz_[s].z, hh[s].z, az); an = dot2f(wn_[s].z, hh[s].z, an);
      ar = dot2f(wr_[s].w, hh[s].w, ar); az = dot2f(wz_[s].w, hh[s].w, az); an = dot2f(wn_[s].w, hh[s].w, an);
    }
    ar += __shfl_xor(ar, 1); az += __shfl_xor(az, 1); an += __shfl_xor(an, 1);
    ar += br; az += bz; an += bn;
    float er = __expf(-(xr + ar));
    float r  = frcp(1.f + er);
    float ez = __expf(-(xz + az));
    float z  = frcp(1.f + ez);
    float y  = xn + r * an;
    float e2 = __expf(-2.f * y);
    float n  = (1.f - e2) * frcp(1.f + e2);
    float hnew = n + z * (hprev - n);
    __builtin_amdgcn_s_setprio(0);
    hprev = hnew;
    if (!kh){
      _Float16 hf = (_Float16)hnew;
      hb16[nxt][j] = __builtin_bit_cast(u16, hf);
      node_out[(size_t)node*128 + j] = (u16)bf16rne(hnew);
    }
    __syncthreads();
  }
}

// ---------------- head fused with post-GRU LN+ReLU ----------------
__global__ __launch_bounds__(256) void k_head(
    const float* __restrict__ h, const u16* __restrict__ node_out,
    const int* __restrict__ grp, const int* __restrict__ cnt,
    const float* __restrict__ sqg, const float* __restrict__ sqb,
    const float* __restrict__ l1W, const float* __restrict__ l1b,
    const float* __restrict__ l2W, const float* __restrict__ l2b,
    float* __restrict__ out){
  int node = blockIdx.x * 4 + (threadIdx.x >> 6);
  int lane = threadIdx.x & 63;
  bool single = (cnt[grp[node]] == 1);   // wave-uniform
  float x0, x1;
  if (single){
    x0 = h[(size_t)node*128 + 2*lane];
    x1 = h[(size_t)node*128 + 2*lane + 1];
  } else {
    float r0 = bf2f(node_out[(size_t)node*128 + 2*lane]);
    float r1 = bf2f(node_out[(size_t)node*128 + 2*lane + 1]);
    float s = wredf(r0 + r1);
    float qq = wredf(r0*r0 + r1*r1);
    float mu = s * 0.0078125f;
    float var = qq * 0.0078125f - mu*mu;
    float rstd = rsqrtf(var + 1e-5f);
    x0 = fmaxf((r0 - mu)*rstd*sqg[2*lane]   + sqb[2*lane],   0.f);
    x1 = fmaxf((r1 - mu)*rstd*sqg[2*lane+1] + sqb[2*lane+1], 0.f);
  }
  float acc[8];
  #pragma unroll
  for (int j = 0; j < 8; ++j)
    acc[j] = x0 * l1W[(2*lane)*8 + j] + x1 * l1W[(2*lane + 1)*8 + j];
  #pragma unroll
  for (int o = 32; o; o >>= 1)
    #pragma unroll
    for (int j = 0; j < 8; ++j) acc[j] += __shfl_xor(acc[j], o);
  if (lane == 0){
    float zz = l2b[0];
    #pragma unroll
    for (int j = 0; j < 8; ++j){
      float xx = acc[j] + l1b[j];
      float ge = 0.5f * xx * (1.f + erff(xx * 0.7071067811865476f));
      zz += ge * l2W[j];
    }
    out[node] = 1.f / (1.f + expf(-zz));
  }
}

extern "C" void kernel_launch(void* const* d_in, const int* in_sizes, int n_in,
                              void* d_out, int out_size, void* d_ws, size_t ws_size,
                              hipStream_t stream){
  float* out = (float*)d_out;

  // ---- ws-size guard ----
  if (ws_size < WS_NEEDED){
    float code = -(float)(ws_size >> 20);
    k_sentinel<<<(out_size + 255)/256, 256, 0, stream>>>(out, out_size, code);
    return;
  }

  const float* x       = (const float*)d_in[0];
  const int*   tei     = (const int*)d_in[1];
  const int*   callsq  = (const int*)d_in[2];
  const int*   batch   = (const int*)d_in[3];
  const float* Wq      = (const float*)d_in[4];
  const float* bq      = (const float*)d_in[5];
  const float* Wk      = (const float*)d_in[6];
  const float* bk      = (const float*)d_in[7];
  const float* Wv      = (const float*)d_in[8];
  const float* bv      = (const float*)d_in[9];
  const float* Wsk     = (const float*)d_in[10];
  const float* bsk     = (const float*)d_in[11];
  const float* lng     = (const float*)d_in[12];
  const float* lnb     = (const float*)d_in[13];
  const float* centers = (const float*)d_in[14];
  const float* projW   = (const float*)d_in[15];
  const float* projb   = (const float*)d_in[16];
  const float* Wih     = (const float*)d_in[17];
  const float* Whh     = (const float*)d_in[18];
  const float* bih     = (const float*)d_in[19];
  const float* bhh     = (const float*)d_in[20];
  const float* sqg     = (const float*)d_in[21];
  const float* sqb     = (const float*)d_in[22];
  const float* l1W     = (const float*)d_in[23];
  const float* l1b     = (const float*)d_in[24];
  const float* l2W     = (const float*)d_in[25];
  const float* l2b     = (const float*)d_in[26];

  float* wf = (float*)d_ws;
  float* f_h    = wf + F_H;
  float* f_a    = wf + F_A;
  float* f_b    = wf + F_B;
  float* f_cn   = wf + F_CN;
  float* f_wkt  = wf + F_WKT;
  float* f_wqk  = wf + F_WQK;
  float* f_bqk  = wf + F_BQK;
  float* f_cw   = wf + F_CW;
  float* f_pew  = wf + F_PEW;
  float* f_peb  = wf + F_PEB;
  u16*   gi_bf  = (u16*)(wf + F_A);
  u16*   no_bf  = (u16*)(wf + F_NODE);
  int* wi = (int*)(wf + F_END);
  int* i_rowp = wi + I_ROWP;
  int* i_cur  = wi + I_CUR;
  int* i_col  = wi + I_COL;
  int* i_grp  = wi + I_GRP;
  int* i_inv  = wi + I_INV;
  int* i_pos  = wi + I_POS;
  int* i_gn   = wi + I_GN;
  int* i_cnt  = wi + I_CNT;
  int* i_ch   = wi + I_CH;
  int* i_bs   = wi + I_BS;
  u32* i_wt   = (u32*)(wi + I_WT);

  const int* esrc = tei;
  const int* edst = tei + EE;

  // CSR build
  k_zero<<<NN/256, 256, 0, stream>>>(i_cur);
  k_hist<<<EE/256, 256, 0, stream>>>(edst, i_cur);
  k_s1<<<NCHUNK, 256, 0, stream>>>(i_cur, i_bs);
  k_s2<<<1, 512, 0, stream>>>(i_bs);
  k_s3<<<NCHUNK, 256, 0, stream>>>(i_bs, i_rowp, i_cur);
  k_scatter<<<EE/256, 256, 0, stream>>>(esrc, edst, i_cur, i_col);

  // centers, PE tables, folded conv weights, packed f16 Whh rows
  k_setup<<<1, 128, 0, stream>>>(centers, f_cn, out + NN);
  k_pe<<<1000, 128, 0, stream>>>(projb, f_peb);
  k_pew<<<dim3(1000, 3), 128, 0, stream>>>(f_peb, Wih, bih, f_pew);
  k_tr<<<dim3(128, 3), 128, 0, stream>>>(Wk, f_wkt);
  for (int i = 0; i < 3; ++i)
    k_gemm<<<dim3(1, 1), 256, 0, stream>>>(Wq + (size_t)i*16384, f_wkt + (size_t)i*16384,
        128, nullptr, nullptr, nullptr, nullptr, nullptr, f_wqk + (size_t)i*16384,
        nullptr, 128, nullptr, nullptr, nullptr, nullptr);   // Wqk = Wq@Wk^T
  k_mv<<<3, 128, 0, stream>>>(Wk, bq, f_bqk);                // bqk = Wk@bq
  k_combw<<<dim3(128, 3), 128, 0, stream>>>(projW, Wih, f_cw);
  k_packwhh16<<<dim3(64, 3), 128, 0, stream>>>(Whh, i_wt);

  // 3x TransformerConv + relu(LN)
  for (int i = 0; i < 3; ++i){
    const float* xin = i ? f_h : x;
    size_t wo = (size_t)i * 128 * 128, bo = (size_t)i * 128;
    // qt = xin@Wqk + bqk -> B   (q.bk softmax shift cancels; no qb needed)
    k_gemm<<<dim3(NN/128, 1), 256, 0, stream>>>(xin, f_wqk + (size_t)i*16384, 128,
        nullptr, nullptr, f_bqk + bo, nullptr, nullptr, f_b, nullptr, 128,
        nullptr, nullptr, nullptr, nullptr);
    // fused edge: xagg -> A
    k_edge<<<NN/8, 256, 0, stream>>>(f_b, xin, i_rowp, i_col, f_a);
    // h2 = xagg@Wv + xin@Wsk + bsk; convs 1-2 fuse LN+ReLU into epilogue -> f_h
    if (i < 2){
      k_gemm<<<dim3(NN/128, 1), 256, 0, stream>>>(f_a, Wv + wo, 128, xin, Wsk + wo,
          bsk + bo, nullptr, nullptr, f_h, nullptr, 128,
          lng + bo, lnb + bo, bv + bo, i_rowp);
    } else {
      k_gemm<<<dim3(NN/128, 1), 256, 0, stream>>>(f_a, Wv + wo, 128, xin, Wsk + wo,
          bsk + bo, nullptr, nullptr, f_b, nullptr, 128,
          nullptr, nullptr, nullptr, nullptr);
      k_lnrelu_cls<<<NN/4, 256, 0, stream>>>(f_b, lng + bo, lnb + bo, bv + bo, i_rowp,
          f_h, f_cn, batch, callsq, i_grp, i_inv);
    }
  }

  // grouping
  k_g1<<<NCHUNK, 256, 0, stream>>>(i_inv, i_grp, i_ch);
  k_g2<<<GG, 512, 0, stream>>>(i_ch, i_cnt);
  k_g3<<<NCHUNK, 256, 0, stream>>>(i_inv, i_grp, i_ch, i_pos, i_gn);

  // gi = h @ (projW@Wih^T) + PEW[pos] -> bf16 overlay
  k_gemm<<<dim3(NN/128, 3), 256, 0, stream>>>(f_h, f_cw, 384, nullptr, nullptr,
      nullptr, f_pew, i_pos, nullptr, gi_bf, 384, nullptr, nullptr, nullptr, nullptr);

  // GRU (raw h out); LN+ReLU deferred into head
  k_gru<<<GG, 256, 0, stream>>>(gi_bf, i_wt, bhh, i_gn, i_cnt, no_bf);

  // head (fused post-LN)
  k_head<<<NN/4, 256, 0, stream>>>(f_h, no_bf, i_grp, i_cnt, sqg, sqb,
                                   l1W, l1b, l2W, l2b, out);
}

// Round 14
// 2083.459 us; speedup vs baseline: 3.2271x; 1.0167x over previous
//
#include <hip/hip_runtime.h>

#define NN 128000
#define EE 1024000
#define HH 128
#define GG 512
#define SMAX 1000
#define NCHUNK 500   // 500 * 256 = 128000

typedef unsigned int u32;
typedef unsigned short u16;

// ---------------- workspace layout (floats, then ints) ----------------
constexpr size_t NH     = (size_t)NN*HH;              // 16,384,000
constexpr size_t F_H    = 0;                          // h (persist, f32)
constexpr size_t F_A    = NH;                         // work A: xagg / gi overlay
constexpr size_t F_B    = 2*NH;                       // work B: qt / h2
constexpr size_t F_NODE = F_A + (size_t)NN*192;       // bf16 node_out overlay
constexpr size_t F_CN   = 3*NH;                       // 4*128 normalized centers
constexpr size_t F_WKT  = F_CN   + 512;               // 3*128*128 Wk^T
constexpr size_t F_WQK  = F_WKT  + 3*16384;           // 3*128*128 Wq@Wk^T
constexpr size_t F_BQK  = F_WQK  + 3*16384;           // 3*128  Wk@bq
constexpr size_t F_CW   = F_BQK  + 3*128;             // 128*384 projW@Wih^T
constexpr size_t F_PEW  = F_CW   + 128*384;           // 1000*384
constexpr size_t F_PEB  = F_PEW  + 1000*384;          // 1000*128
constexpr size_t F_END  = F_PEB  + 1000*128;

constexpr size_t I_ROWP = 0;                          // N+8 CSR row ptr
constexpr size_t I_CUR  = I_ROWP + NN + 8;
constexpr size_t I_COL  = I_CUR  + NN;                // E
constexpr size_t I_GRP  = I_COL  + EE;
constexpr size_t I_INV  = I_GRP  + NN;
constexpr size_t I_POS  = I_INV  + NN;
constexpr size_t I_GN   = I_POS  + NN;                // 512*1000
constexpr size_t I_CNT  = I_GN   + (size_t)GG*SMAX;
constexpr size_t I_CH   = I_CNT  + GG;                // 500*512
constexpr size_t I_BS   = I_CH   + (size_t)NCHUNK*GG;
constexpr size_t I_WT   = I_BS   + 512;               // 384*64 packed f16 Whh^T rows
constexpr size_t I_END  = I_WT   + 64*384;

constexpr size_t WS_NEEDED = F_END*4 + I_END*4;

__device__ inline float wredf(float v){
  #pragma unroll
  for (int o = 32; o; o >>= 1) v += __shfl_xor(v, o);
  return v;
}
__device__ inline u32 bf16rne(float f){
  u32 u = __float_as_uint(f);
  return (u + 0x7fffu + ((u >> 16) & 1u)) >> 16;
}
__device__ inline float bf2f(u16 u){
  return __uint_as_float(((u32)u) << 16);
}
__device__ inline float frcp(float x){
#if __has_builtin(__builtin_amdgcn_rcpf)
  return __builtin_amdgcn_rcpf(x);
#else
  return 1.f / x;
#endif
}

typedef _Float16 h2_t __attribute__((ext_vector_type(2)));
__device__ inline float dot2f(u32 w, u32 h, float acc){
#if __has_builtin(__builtin_amdgcn_fdot2)
  return __builtin_amdgcn_fdot2(__builtin_bit_cast(h2_t, w),
                                __builtin_bit_cast(h2_t, h), acc, false);
#else
  float r;
  asm("v_dot2_f32_f16 %0, %1, %2, %3" : "=v"(r) : "v"(w), "v"(h), "v"(acc));
  return r;
#endif
}
#define PIN4(v) asm volatile("" : "+v"((v).x), "+v"((v).y), "+v"((v).z), "+v"((v).w))

// ---------------- ws-size diagnostic sentinel ----------------
__global__ void k_sentinel(float* __restrict__ out, int n, float val){
  int i = blockIdx.x * 256 + threadIdx.x;
  if (i < n) out[i] = val;
}

// ---------------- CSR build ----------------
__global__ void k_zero(int* __restrict__ p){
  p[blockIdx.x * 256 + threadIdx.x] = 0;
}
__global__ void k_hist(const int* __restrict__ dst, int* __restrict__ deg){
  int e = blockIdx.x * 256 + threadIdx.x;
  atomicAdd(&deg[dst[e]], 1);
}
__global__ void k_s1(const int* __restrict__ deg, int* __restrict__ bsum){
  __shared__ int red[256];
  int t = threadIdx.x;
  red[t] = deg[blockIdx.x * 256 + t];
  __syncthreads();
  for (int s = 128; s; s >>= 1){ if (t < s) red[t] += red[t + s]; __syncthreads(); }
  if (!t) bsum[blockIdx.x] = red[0];
}
__global__ void k_s2(int* __restrict__ bsum){
  __shared__ int arr[512];
  int t = threadIdx.x;
  int v0 = (t < NCHUNK) ? bsum[t] : 0;
  arr[t] = v0; __syncthreads();
  for (int off = 1; off < 512; off <<= 1){
    int v = (t >= off) ? arr[t - off] : 0;
    __syncthreads();
    arr[t] += v;
    __syncthreads();
  }
  if (t < NCHUNK) bsum[t] = arr[t] - v0;   // exclusive
}
__global__ void k_s3(const int* __restrict__ bsum, int* __restrict__ row_ptr,
                     int* __restrict__ cursor){
  __shared__ int arr[256];
  int t = threadIdx.x;
  int i = blockIdx.x * 256 + t;
  int v0 = cursor[i];
  arr[t] = v0; __syncthreads();
  for (int off = 1; off < 256; off <<= 1){
    int v = (t >= off) ? arr[t - off] : 0;
    __syncthreads();
    arr[t] += v;
    __syncthreads();
  }
  int exc = arr[t] - v0 + bsum[blockIdx.x];
  row_ptr[i] = exc;
  cursor[i]  = exc;
  if (i == 0) row_ptr[NN] = EE;
}
__global__ void k_scatter(const int* __restrict__ src, const int* __restrict__ dst,
                          int* __restrict__ cursor, int* __restrict__ col){
  int e = blockIdx.x * 256 + threadIdx.x;
  int idx = atomicAdd(&cursor[dst[e]], 1);
  col[idx] = src[e];
}

// ---------------- centers: normalize + distance ----------------
__global__ void k_setup(const float* __restrict__ centers, float* __restrict__ cn,
                        float* __restrict__ dist_out){
  __shared__ float red[128];
  int t = threadIdx.x;
  for (int l = 0; l < 4; ++l){
    float v = centers[l*128 + t];
    red[t] = v * v; __syncthreads();
    for (int s = 64; s; s >>= 1){ if (t < s) red[t] += red[t + s]; __syncthreads(); }
    float nrm = sqrtf(red[0]);
    __syncthreads();
    cn[l*128 + t] = v / fmaxf(nrm, 1e-8f);
  }
  const int iu0[6] = {0,0,0,1,1,2}, iu1[6] = {1,2,3,2,3,3};
  __shared__ float dv[6];
  for (int p = 0; p < 6; ++p){
    float d = centers[iu0[p]*128 + t] - centers[iu1[p]*128 + t];
    red[t] = d * d; __syncthreads();
    for (int s = 64; s; s >>= 1){ if (t < s) red[t] += red[t + s]; __syncthreads(); }
    if (!t) dv[p] = sqrtf(red[0]);
    __syncthreads();
  }
  if (!t){
    float mean = 0.f;
    for (int p = 0; p < 6; ++p) mean += dv[p];
    mean /= 6.f;
    float var = 0.f;
    for (int p = 0; p < 6; ++p){ float d = dv[p] - mean; var += d * d; }
    var /= 5.f;                              // ddof=1
    dist_out[0] = -var;
  }
}

// ---------------- pos-enc tables + weight transforms ----------------
__global__ void k_pe(const float* __restrict__ projb, float* __restrict__ peb){
  int p = blockIdx.x, t = threadIdx.x;     // 1000 x 128
  float ex  = (float)(t >> 1) * (-2.0f * 9.210340371976184f / 128.0f);
  float ang = (float)p * expf(ex);
  float v = (t & 1) ? cosf(ang) : sinf(ang);
  peb[p*128 + t] = v + projb[t];
}
__global__ void k_pew(const float* __restrict__ peb, const float* __restrict__ Wih,
                      const float* __restrict__ bih, float* __restrict__ pew){
  int p = blockIdx.x;                       // 1000
  int j = blockIdx.y * 128 + threadIdx.x;   // 384
  const float* pb = peb + p*128;
  const float* wr = Wih + (size_t)j*128;
  float acc = bih[j];
  #pragma unroll 4
  for (int m = 0; m < 128; ++m) acc += pb[m] * wr[m];
  pew[(size_t)p*384 + j] = acc;
}
__global__ void k_combw(const float* __restrict__ projW, const float* __restrict__ Wih,
                        float* __restrict__ cw){
  int kk = blockIdx.x;                      // 128
  int j  = blockIdx.y * 128 + threadIdx.x;  // 384
  const float* pr = projW + (size_t)kk*128;
  const float* wr = Wih + (size_t)j*128;
  float acc = 0.f;
  #pragma unroll 4
  for (int m = 0; m < 128; ++m) acc += pr[m] * wr[m];
  cw[(size_t)kk*384 + j] = acc;
}
// Wk^T per layer
__global__ void k_tr(const float* __restrict__ Wk, float* __restrict__ wkt){
  int kk = blockIdx.x, l = blockIdx.y, c = threadIdx.x;
  wkt[(size_t)l*16384 + kk*128 + c] = Wk[(size_t)l*16384 + c*128 + kk];
}
// out[l][i] = row_i(M_l) . v_l
__global__ void k_mv(const float* __restrict__ M, const float* __restrict__ v,
                     float* __restrict__ out){
  int l = blockIdx.x, i = threadIdx.x;
  const float* row = M + (size_t)l*16384 + (size_t)i*128;
  const float* vv = v + l*128;
  float acc = 0.f;
  #pragma unroll 4
  for (int j = 0; j < 128; ++j) acc += row[j] * vv[j];
  out[l*128 + i] = acc;
}
// pack Whh rows as f16x2 along k
__global__ void k_packwhh16(const float* __restrict__ Whh, u32* __restrict__ wt){
  int kp = blockIdx.x;                      // 64
  int j  = blockIdx.y * 128 + threadIdx.x;  // 384
  _Float16 a = (_Float16)Whh[(size_t)j*128 + 2*kp];
  _Float16 b = (_Float16)Whh[(size_t)j*128 + 2*kp + 1];
  u32 lo = (u32)__builtin_bit_cast(u16, a);
  u32 hi = (u32)__builtin_bit_cast(u16, b);
  wt[(size_t)j*64 + kp] = (hi << 16) | lo;
}

// ---------------- GEMM v5: 128x128 tile, 8x8 acc; optional K=256; optional LN ----
__global__ __launch_bounds__(256, 2) void k_gemm(
    const float* __restrict__ X, const float* __restrict__ W, int ldw,
    const float* __restrict__ X2, const float* __restrict__ W2,
    const float* __restrict__ bias, const float* __restrict__ pew,
    const int* __restrict__ pos, float* __restrict__ out,
    u16* __restrict__ outb, int ldo,
    const float* __restrict__ lng, const float* __restrict__ lnb,
    const float* __restrict__ bvv, const int* __restrict__ rowp){
  __shared__ __align__(16) float Wl[64*132];
  __shared__ __align__(16) float Xl[64*132];
  int tid = threadIdx.x;
  int rb = blockIdx.x * 128;
  int cb = blockIdx.y * 128;
  int rg = tid >> 4;
  int cg = tid & 15;
  int kxor = (cg >> 2) & 3;
  float acc[8][8];
  #pragma unroll
  for (int a = 0; a < 8; ++a)
    #pragma unroll
    for (int b = 0; b < 8; ++b) acc[a][b] = 0.f;
  int nhalf = X2 ? 4 : 2;
  for (int half = 0; half < nhalf; ++half){
    const float* Xs = (half < 2) ? X : X2;
    const float* Ws = (half < 2) ? W : W2;
    int ldws = (half < 2) ? ldw : 128;
    int hk = half & 1;
    __syncthreads();
    #pragma unroll
    for (int it = 0; it < 8; ++it){
      int idx = it*256 + tid;
      int kk = idx >> 5, c4 = idx & 31;
      *(float4*)&Wl[kk*132 + c4*4] =
          *(const float4*)&Ws[(size_t)(hk*64 + kk)*ldws + cb + c4*4];
    }
    #pragma unroll
    for (int it = 0; it < 8; ++it){
      int idx = it*256 + tid;
      int r = idx >> 4, c4 = idx & 15;
      float4 xv = *(const float4*)&Xs[(size_t)(rb + r)*128 + hk*64 + c4*4];
      Xl[(c4*4+0)*132 + r] = xv.x;
      Xl[(c4*4+1)*132 + r] = xv.y;
      Xl[(c4*4+2)*132 + r] = xv.z;
      Xl[(c4*4+3)*132 + r] = xv.w;
    }
    __syncthreads();
    #pragma unroll 2
    for (int kk = 0; kk < 64; ++kk){
      int kx = kk ^ kxor;
      float4 wa = *(const float4*)&Wl[kx*132 + cg*8];
      float4 wb = *(const float4*)&Wl[kx*132 + cg*8 + 4];
      float4 xa = *(const float4*)&Xl[kx*132 + rg*8];
      float4 xb = *(const float4*)&Xl[kx*132 + rg*8 + 4];
      float xs[8] = {xa.x, xa.y, xa.z, xa.w, xb.x, xb.y, xb.z, xb.w};
      float ws[8] = {wa.x, wa.y, wa.z, wa.w, wb.x, wb.y, wb.z, wb.w};
      #pragma unroll
      for (int rr = 0; rr < 8; ++rr)
        #pragma unroll
        for (int j = 0; j < 8; ++j) acc[rr][j] += xs[rr] * ws[j];
    }
  }
  if (lng){
    float gv[8], bl[8], bb[8], vv[8];
    #pragma unroll
    for (int j = 0; j < 8; ++j){
      int c = cg*8 + j;
      gv[j] = lng[c]; bl[j] = lnb[c]; bb[j] = bias[c]; vv[j] = bvv[c];
    }
    #pragma unroll
    for (int rr = 0; rr < 8; ++rr){
      int r = rb + rg*8 + rr;
      bool deg = rowp[r+1] > rowp[r];
      float rs = 0.f, rq = 0.f;
      #pragma unroll
      for (int j = 0; j < 8; ++j){
        float v = acc[rr][j] + bb[j] + (deg ? vv[j] : 0.f);
        acc[rr][j] = v;
        rs += v; rq += v*v;
      }
      #pragma unroll
      for (int o = 8; o; o >>= 1){ rs += __shfl_xor(rs, o); rq += __shfl_xor(rq, o); }
      float mu = rs * 0.0078125f;
      float var = rq * 0.0078125f - mu*mu;
      float rstd = rsqrtf(var + 1e-5f);
      float ov[8];
      #pragma unroll
      for (int j = 0; j < 8; ++j)
        ov[j] = fmaxf((acc[rr][j] - mu)*rstd*gv[j] + bl[j], 0.f);
      float* op = out + (size_t)r*128 + cg*8;
      *(float4*)op       = *(const float4*)&ov[0];
      *(float4*)(op + 4) = *(const float4*)&ov[4];
    }
    return;
  }
  #pragma unroll
  for (int rr = 0; rr < 8; ++rr){
    int r = rb + rg*8 + rr;
    float bv[8];
    if (pos){
      const float* pw = pew + (size_t)pos[r]*384 + cb + cg*8;
      #pragma unroll
      for (int j = 0; j < 8; ++j) bv[j] = pw[j];
    } else if (bias){
      #pragma unroll
      for (int j = 0; j < 8; ++j) bv[j] = bias[cb + cg*8 + j];
    } else {
      #pragma unroll
      for (int j = 0; j < 8; ++j) bv[j] = 0.f;
    }
    if (outb){
      u16 ob[8];
      #pragma unroll
      for (int j = 0; j < 8; ++j) ob[j] = (u16)bf16rne(acc[rr][j] + bv[j]);
      *(uint4*)(outb + (size_t)r*ldo + cb + cg*8) = *(const uint4*)ob;
    } else {
      float ov[8];
      #pragma unroll
      for (int j = 0; j < 8; ++j) ov[j] = acc[rr][j] + bv[j];
      float* op = out + (size_t)r*ldo + cb + cg*8;
      *(float4*)op       = *(const float4*)&ov[0];
      *(float4*)(op + 4) = *(const float4*)&ov[4];
    }
  }
}

// ---------------- fused edge v4: no qb, pair-unrolled ----------------
__global__ __launch_bounds__(256) void k_edge(
    const float* __restrict__ qt, const float* __restrict__ xsrc,
    const int* __restrict__ row_ptr, const int* __restrict__ col,
    float* __restrict__ xagg){
  int d = blockIdx.x * 8 + (threadIdx.x >> 5);
  int lane = threadIdx.x & 31;
  int e0 = row_ptr[d], e1 = row_ptr[d+1];
  if (e0 == e1){
    *(float4*)&xagg[(size_t)d*128 + lane*4] = make_float4(0.f, 0.f, 0.f, 0.f);
    return;
  }
  const float S = 0.08838834764831845f;   // 1/sqrt(128)
  float4 qv = *(const float4*)&qt[(size_t)d*128 + lane*4];
  float ss0 = 0.f, ss1 = 0.f;
  float4 A0 = make_float4(0.f,0.f,0.f,0.f), A1 = make_float4(0.f,0.f,0.f,0.f);
  int e = e0;
  for (; e + 1 < e1; e += 2){
    float4 x0 = *(const float4*)&xsrc[(size_t)col[e]  *128 + lane*4];
    float4 x1 = *(const float4*)&xsrc[(size_t)col[e+1]*128 + lane*4];
    float p0 = qv.x*x0.x + qv.y*x0.y + qv.z*x0.z + qv.w*x0.w;
    float p1 = qv.x*x1.x + qv.y*x1.y + qv.z*x1.z + qv.w*x1.w;
    #pragma unroll
    for (int o = 16; o; o >>= 1){ p0 += __shfl_xor(p0, o); p1 += __shfl_xor(p1, o); }
    float el0 = __expf(p0 * S);
    float el1 = __expf(p1 * S);
    ss0 += el0; ss1 += el1;
    A0.x += el0*x0.x; A0.y += el0*x0.y; A0.z += el0*x0.z; A0.w += el0*x0.w;
    A1.x += el1*x1.x; A1.y += el1*x1.y; A1.z += el1*x1.z; A1.w += el1*x1.w;
  }
  if (e < e1){
    float4 x0 = *(const float4*)&xsrc[(size_t)col[e]*128 + lane*4];
    float p0 = qv.x*x0.x + qv.y*x0.y + qv.z*x0.z + qv.w*x0.w;
    #pragma unroll
    for (int o = 16; o; o >>= 1) p0 += __shfl_xor(p0, o);
    float el0 = __expf(p0 * S);
    ss0 += el0;
    A0.x += el0*x0.x; A0.y += el0*x0.y; A0.z += el0*x0.z; A0.w += el0*x0.w;
  }
  float inv = 1.f / (ss0 + ss1);
  *(float4*)&xagg[(size_t)d*128 + lane*4] =
      make_float4((A0.x+A1.x)*inv, (A0.y+A1.y)*inv, (A0.z+A1.z)*inv, (A0.w+A1.w)*inv);
}

// ---------------- conv-3 lnrelu fused with cluster assignment ----------------
__global__ __launch_bounds__(256) void k_lnrelu_cls(
    const float* __restrict__ in, const float* __restrict__ g,
    const float* __restrict__ b, const float* __restrict__ bvv,
    const int* __restrict__ rowp, float* __restrict__ outp,
    const float* __restrict__ cn, const int* __restrict__ batch,
    const int* __restrict__ callsq, int* __restrict__ grp, int* __restrict__ inv){
  int node = blockIdx.x * 4 + (threadIdx.x >> 6);
  int lane = threadIdx.x & 63;
  float x0 = in[(size_t)node*128 + 2*lane], x1 = in[(size_t)node*128 + 2*lane + 1];
  if (rowp[node+1] > rowp[node]){
    x0 += bvv[2*lane];
    x1 += bvv[2*lane + 1];
  }
  float s = wredf(x0 + x1);
  float qq = wredf(x0*x0 + x1*x1);
  float mu = s * 0.0078125f;
  float var = qq * 0.0078125f - mu*mu;
  float rstd = rsqrtf(var + 1e-5f);
  float y0 = fmaxf((x0 - mu)*rstd*g[2*lane]   + b[2*lane],   0.f);
  float y1 = fmaxf((x1 - mu)*rstd*g[2*lane+1] + b[2*lane+1], 0.f);
  outp[(size_t)node*128 + 2*lane]     = y0;
  outp[(size_t)node*128 + 2*lane + 1] = y1;
  float p0 = y0*cn[      2*lane] + y1*cn[      2*lane+1];
  float p1 = y0*cn[128 + 2*lane] + y1*cn[128 + 2*lane+1];
  float p2 = y0*cn[256 + 2*lane] + y1*cn[256 + 2*lane+1];
  float p3 = y0*cn[384 + 2*lane] + y1*cn[384 + 2*lane+1];
  p0 = wredf(p0); p1 = wredf(p1); p2 = wredf(p2); p3 = wredf(p3);
  if (lane == 0){
    float best = p0; int bi = 0;
    if (p1 > best){ best = p1; bi = 1; }
    if (p2 > best){ best = p2; bi = 2; }
    if (p3 > best){ best = p3; bi = 3; }
    grp[node] = batch[node]*4 + bi;
    inv[callsq[node]] = node;
  }
}

// ---------------- grouping: chunked multisplit ----------------
__global__ __launch_bounds__(256) void k_g1(const int* __restrict__ inv,
                                            const int* __restrict__ grp,
                                            int* __restrict__ ch){
  __shared__ int hist[GG];
  int c = blockIdx.x, t = threadIdx.x;
  hist[t] = 0; hist[t + 256] = 0;
  __syncthreads();
  int g = grp[inv[c*256 + t]];
  atomicAdd(&hist[g], 1);
  __syncthreads();
  ch[c*GG + t] = hist[t];
  ch[c*GG + 256 + t] = hist[256 + t];
}
__global__ void k_g2(int* __restrict__ ch, int* __restrict__ cnt){
  __shared__ int arr[512];
  int g = blockIdx.x, t = threadIdx.x;
  int v0 = (t < NCHUNK) ? ch[(size_t)t*GG + g] : 0;
  arr[t] = v0; __syncthreads();
  for (int off = 1; off < 512; off <<= 1){
    int v = (t >= off) ? arr[t - off] : 0;
    __syncthreads();
    arr[t] += v;
    __syncthreads();
  }
  if (t < NCHUNK) ch[(size_t)t*GG + g] = arr[t] - v0;
  if (t == 511) cnt[g] = arr[511];
}
__global__ __launch_bounds__(256) void k_g3(
    const int* __restrict__ inv, const int* __restrict__ grp,
    const int* __restrict__ ch, int* __restrict__ pos, int* __restrict__ gn){
  __shared__ int hist[GG];
  int c = blockIdx.x, t = threadIdx.x;
  hist[t] = 0; hist[t + 256] = 0;
  __syncthreads();
  int node = inv[c*256 + t];
  int g = grp[node];
  int lane = t & 63, w = t >> 6;
  int before = 0, total = 0;
  for (int j = 0; j < 64; ++j){
    int gj = __shfl(g, j);
    if (gj == g){ total++; if (j < lane) before++; }
  }
  int base = 0;
  for (int wv = 0; wv < 4; ++wv){
    if (w == wv){
      base = hist[g];
      if (before == total - 1) hist[g] = base + total;
    }
    __syncthreads();
  }
  int p = ch[c*GG + g] + base + before;
  pos[node] = p;
  gn[(size_t)g*SMAX + p] = node;
}

// ---------------- GRU v9: lgkmcnt-only barrier (prefetch stays in flight) --------
// __syncthreads drains vmcnt(0) per step, putting the gi prefetch gather latency on
// the serial path. The only per-step hazard is the hb16 ds_write -> next-step
// ds_read; lgkmcnt(0)+s_barrier orders exactly that. Global loads keep flowing.
__global__ __launch_bounds__(256)
__attribute__((amdgpu_waves_per_eu(2, 2)))
void k_gru(
    const u16* __restrict__ gi, const u32* __restrict__ wt,
    const float* __restrict__ bhh, const int* __restrict__ gn,
    const int* __restrict__ cnt, u16* __restrict__ node_out){
  __shared__ __align__(16) u16 hb16[2][128];
  int t = threadIdx.x;
  int j = t >> 1;
  int kh = t & 1;
  int g = blockIdx.x;
  int my = cnt[g];
  if (my <= 1) return;
  uint4 wr_[8], wz_[8], wn_[8];
  {
    const uint4* wt4 = (const uint4*)wt;
    size_t b0 = (size_t)(0*128 + j)*16 + kh*8;
    size_t b1 = (size_t)(1*128 + j)*16 + kh*8;
    size_t b2 = (size_t)(2*128 + j)*16 + kh*8;
    #pragma unroll
    for (int s = 0; s < 8; ++s){
      wr_[s] = wt4[b0 + s];
      wz_[s] = wt4[b1 + s];
      wn_[s] = wt4[b2 + s];
    }
    #pragma unroll
    for (int s = 0; s < 8; ++s){
      PIN4(wr_[s]); PIN4(wz_[s]); PIN4(wn_[s]);
    }
  }
  if (t < 128) hb16[0][t] = 0;
  float br = bhh[j], bz = bhh[128 + j], bn = bhh[256 + j];
  const int* gnr = gn + (size_t)g*SMAX;
  float hprev = 0.f;
  int nA = gnr[0];
  int nB = gnr[min(1, my - 1)];
  int nC = gnr[min(2, my - 1)];
  const u16* gA = gi + (size_t)nA*384;
  const u16* gB = gi + (size_t)nB*384;
  const u16* gC = gi + (size_t)nC*384;
  float axr = bf2f(gA[j]), axz = bf2f(gA[128 + j]), axn = bf2f(gA[256 + j]);
  float bxr = bf2f(gB[j]), bxz = bf2f(gB[128 + j]), bxn = bf2f(gB[256 + j]);
  float cxr = bf2f(gC[j]), cxz = bf2f(gC[128 + j]), cxn = bf2f(gC[256 + j]);
  __syncthreads();                       // init barrier (full drain OK, once)
  for (int p = 0; p < my; ++p){
    int cur = p & 1, nxt = cur ^ 1;
    float xr = axr, xz = axz, xn = axn;
    int node = nA;
    axr = bxr; axz = bxz; axn = bxn; nA = nB;
    bxr = cxr; bxz = cxz; bxn = cxn; nB = nC;
    nC = gnr[min(p + 3, my - 1)];
    const u16* gN = gi + (size_t)nC*384;
    cxr = bf2f(gN[j]); cxz = bf2f(gN[128 + j]); cxn = bf2f(gN[256 + j]);
    const uint4* HB = (const uint4*)&hb16[cur][0];
    uint4 hh[8];
    #pragma unroll
    for (int s = 0; s < 8; ++s) hh[s] = HB[kh*8 + s];
    __builtin_amdgcn_s_setprio(1);
    float ar = 0.f, az = 0.f, an = 0.f;
    #pragma unroll
    for (int s = 0; s < 8; ++s){
      ar = dot2f(wr_[s].x, hh[s].x, ar); az = dot2f(wz_[s].x, hh[s].x, az); an = dot2f(wn_[s].x, hh[s].x, an);
      ar = dot2f(wr_[s].y, hh[s].y, ar); az = dot2f(wz_[s].y, hh[s].y, az); an = dot2f(wn_[s].y, hh[s].y, an);
      ar = dot2f(wr_[s].z, hh[s].z, ar); az = dot2f(wz_[s].z, hh[s].z, az); an = dot2f(wn_[s].z, hh[s].z, an);
      ar = dot2f(wr_[s].w, hh[s].w, ar); az = dot2f(wz_[s].w, hh[s].w, az); an = dot2f(wn_[s].w, hh[s].w, an);
    }
    ar += __shfl_xor(ar, 1); az += __shfl_xor(az, 1); an += __shfl_xor(an, 1);
    ar += br; az += bz; an += bn;
    float er = __expf(-(xr + ar));
    float r  = frcp(1.f + er);
    float ez = __expf(-(xz + az));
    float z  = frcp(1.f + ez);
    float y  = xn + r * an;
    float e2 = __expf(-2.f * y);
    float n  = (1.f - e2) * frcp(1.f + e2);
    float hnew = n + z * (hprev - n);
    __builtin_amdgcn_s_setprio(0);
    hprev = hnew;
    if (!kh){
      _Float16 hf = (_Float16)hnew;
      hb16[nxt][j] = __builtin_bit_cast(u16, hf);
      node_out[(size_t)node*128 + j] = (u16)bf16rne(hnew);
    }
    // lgkmcnt-only barrier: retire this wave's LDS ops (incl. hb16 write),
    // then sync; do NOT drain vmcnt (gi prefetch stays in flight).
    asm volatile("s_waitcnt lgkmcnt(0)" ::: "memory");
    __builtin_amdgcn_s_barrier();
    asm volatile("" ::: "memory");       // fence: no hoisting reads above barrier
  }
}

// ---------------- head fused with post-GRU LN+ReLU ----------------
__global__ __launch_bounds__(256) void k_head(
    const float* __restrict__ h, const u16* __restrict__ node_out,
    const int* __restrict__ grp, const int* __restrict__ cnt,
    const float* __restrict__ sqg, const float* __restrict__ sqb,
    const float* __restrict__ l1W, const float* __restrict__ l1b,
    const float* __restrict__ l2W, const float* __restrict__ l2b,
    float* __restrict__ out){
  int node = blockIdx.x * 4 + (threadIdx.x >> 6);
  int lane = threadIdx.x & 63;
  bool single = (cnt[grp[node]] == 1);   // wave-uniform
  float x0, x1;
  if (single){
    x0 = h[(size_t)node*128 + 2*lane];
    x1 = h[(size_t)node*128 + 2*lane + 1];
  } else {
    float r0 = bf2f(node_out[(size_t)node*128 + 2*lane]);
    float r1 = bf2f(node_out[(size_t)node*128 + 2*lane + 1]);
    float s = wredf(r0 + r1);
    float qq = wredf(r0*r0 + r1*r1);
    float mu = s * 0.0078125f;
    float var = qq * 0.0078125f - mu*mu;
    float rstd = rsqrtf(var + 1e-5f);
    x0 = fmaxf((r0 - mu)*rstd*sqg[2*lane]   + sqb[2*lane],   0.f);
    x1 = fmaxf((r1 - mu)*rstd*sqg[2*lane+1] + sqb[2*lane+1], 0.f);
  }
  float acc[8];
  #pragma unroll
  for (int j = 0; j < 8; ++j)
    acc[j] = x0 * l1W[(2*lane)*8 + j] + x1 * l1W[(2*lane + 1)*8 + j];
  #pragma unroll
  for (int o = 32; o; o >>= 1)
    #pragma unroll
    for (int j = 0; j < 8; ++j) acc[j] += __shfl_xor(acc[j], o);
  if (lane == 0){
    float zz = l2b[0];
    #pragma unroll
    for (int j = 0; j < 8; ++j){
      float xx = acc[j] + l1b[j];
      float ge = 0.5f * xx * (1.f + erff(xx * 0.7071067811865476f));
      zz += ge * l2W[j];
    }
    out[node] = 1.f / (1.f + expf(-zz));
  }
}

extern "C" void kernel_launch(void* const* d_in, const int* in_sizes, int n_in,
                              void* d_out, int out_size, void* d_ws, size_t ws_size,
                              hipStream_t stream){
  float* out = (float*)d_out;

  // ---- ws-size guard ----
  if (ws_size < WS_NEEDED){
    float code = -(float)(ws_size >> 20);
    k_sentinel<<<(out_size + 255)/256, 256, 0, stream>>>(out, out_size, code);
    return;
  }

  const float* x       = (const float*)d_in[0];
  const int*   tei     = (const int*)d_in[1];
  const int*   callsq  = (const int*)d_in[2];
  const int*   batch   = (const int*)d_in[3];
  const float* Wq      = (const float*)d_in[4];
  const float* bq      = (const float*)d_in[5];
  const float* Wk      = (const float*)d_in[6];
  const float* bk      = (const float*)d_in[7];
  const float* Wv      = (const float*)d_in[8];
  const float* bv      = (const float*)d_in[9];
  const float* Wsk     = (const float*)d_in[10];
  const float* bsk     = (const float*)d_in[11];
  const float* lng     = (const float*)d_in[12];
  const float* lnb     = (const float*)d_in[13];
  const float* centers = (const float*)d_in[14];
  const float* projW   = (const float*)d_in[15];
  const float* projb   = (const float*)d_in[16];
  const float* Wih     = (const float*)d_in[17];
  const float* Whh     = (const float*)d_in[18];
  const float* bih     = (const float*)d_in[19];
  const float* bhh     = (const float*)d_in[20];
  const float* sqg     = (const float*)d_in[21];
  const float* sqb     = (const float*)d_in[22];
  const float* l1W     = (const float*)d_in[23];
  const float* l1b     = (const float*)d_in[24];
  const float* l2W     = (const float*)d_in[25];
  const float* l2b     = (const float*)d_in[26];

  float* wf = (float*)d_ws;
  float* f_h    = wf + F_H;
  float* f_a    = wf + F_A;
  float* f_b    = wf + F_B;
  float* f_cn   = wf + F_CN;
  float* f_wkt  = wf + F_WKT;
  float* f_wqk  = wf + F_WQK;
  float* f_bqk  = wf + F_BQK;
  float* f_cw   = wf + F_CW;
  float* f_pew  = wf + F_PEW;
  float* f_peb  = wf + F_PEB;
  u16*   gi_bf  = (u16*)(wf + F_A);
  u16*   no_bf  = (u16*)(wf + F_NODE);
  int* wi = (int*)(wf + F_END);
  int* i_rowp = wi + I_ROWP;
  int* i_cur  = wi + I_CUR;
  int* i_col  = wi + I_COL;
  int* i_grp  = wi + I_GRP;
  int* i_inv  = wi + I_INV;
  int* i_pos  = wi + I_POS;
  int* i_gn   = wi + I_GN;
  int* i_cnt  = wi + I_CNT;
  int* i_ch   = wi + I_CH;
  int* i_bs   = wi + I_BS;
  u32* i_wt   = (u32*)(wi + I_WT);

  const int* esrc = tei;
  const int* edst = tei + EE;

  // CSR build
  k_zero<<<NN/256, 256, 0, stream>>>(i_cur);
  k_hist<<<EE/256, 256, 0, stream>>>(edst, i_cur);
  k_s1<<<NCHUNK, 256, 0, stream>>>(i_cur, i_bs);
  k_s2<<<1, 512, 0, stream>>>(i_bs);
  k_s3<<<NCHUNK, 256, 0, stream>>>(i_bs, i_rowp, i_cur);
  k_scatter<<<EE/256, 256, 0, stream>>>(esrc, edst, i_cur, i_col);

  // centers, PE tables, folded conv weights, packed f16 Whh rows
  k_setup<<<1, 128, 0, stream>>>(centers, f_cn, out + NN);
  k_pe<<<1000, 128, 0, stream>>>(projb, f_peb);
  k_pew<<<dim3(1000, 3), 128, 0, stream>>>(f_peb, Wih, bih, f_pew);
  k_tr<<<dim3(128, 3), 128, 0, stream>>>(Wk, f_wkt);
  for (int i = 0; i < 3; ++i)
    k_gemm<<<dim3(1, 1), 256, 0, stream>>>(Wq + (size_t)i*16384, f_wkt + (size_t)i*16384,
        128, nullptr, nullptr, nullptr, nullptr, nullptr, f_wqk + (size_t)i*16384,
        nullptr, 128, nullptr, nullptr, nullptr, nullptr);   // Wqk = Wq@Wk^T
  k_mv<<<3, 128, 0, stream>>>(Wk, bq, f_bqk);                // bqk = Wk@bq
  k_combw<<<dim3(128, 3), 128, 0, stream>>>(projW, Wih, f_cw);
  k_packwhh16<<<dim3(64, 3), 128, 0, stream>>>(Whh, i_wt);

  // 3x TransformerConv + relu(LN)
  for (int i = 0; i < 3; ++i){
    const float* xin = i ? f_h : x;
    size_t wo = (size_t)i * 128 * 128, bo = (size_t)i * 128;
    // qt = xin@Wqk + bqk -> B
    k_gemm<<<dim3(NN/128, 1), 256, 0, stream>>>(xin, f_wqk + (size_t)i*16384, 128,
        nullptr, nullptr, f_bqk + bo, nullptr, nullptr, f_b, nullptr, 128,
        nullptr, nullptr, nullptr, nullptr);
    // fused edge: xagg -> A
    k_edge<<<NN/8, 256, 0, stream>>>(f_b, xin, i_rowp, i_col, f_a);
    // h2 = xagg@Wv + xin@Wsk + bsk; convs 1-2 fuse LN+ReLU into epilogue -> f_h
    if (i < 2){
      k_gemm<<<dim3(NN/128, 1), 256, 0, stream>>>(f_a, Wv + wo, 128, xin, Wsk + wo,
          bsk + bo, nullptr, nullptr, f_h, nullptr, 128,
          lng + bo, lnb + bo, bv + bo, i_rowp);
    } else {
      k_gemm<<<dim3(NN/128, 1), 256, 0, stream>>>(f_a, Wv + wo, 128, xin, Wsk + wo,
          bsk + bo, nullptr, nullptr, f_b, nullptr, 128,
          nullptr, nullptr, nullptr, nullptr);
      k_lnrelu_cls<<<NN/4, 256, 0, stream>>>(f_b, lng + bo, lnb + bo, bv + bo, i_rowp,
          f_h, f_cn, batch, callsq, i_grp, i_inv);
    }
  }

  // grouping
  k_g1<<<NCHUNK, 256, 0, stream>>>(i_inv, i_grp, i_ch);
  k_g2<<<GG, 512, 0, stream>>>(i_ch, i_cnt);
  k_g3<<<NCHUNK, 256, 0, stream>>>(i_inv, i_grp, i_ch, i_pos, i_gn);

  // gi = h @ (projW@Wih^T) + PEW[pos] -> bf16 overlay
  k_gemm<<<dim3(NN/128, 3), 256, 0, stream>>>(f_h, f_cw, 384, nullptr, nullptr,
      nullptr, f_pew, i_pos, nullptr, gi_bf, 384, nullptr, nullptr, nullptr, nullptr);

  // GRU (raw h out); LN+ReLU deferred into head
  k_gru<<<GG, 256, 0, stream>>>(gi_bf, i_wt, bhh, i_gn, i_cnt, no_bf);

  // head (fused post-LN)
  k_head<<<NN/4, 256, 0, stream>>>(f_h, no_bf, i_grp, i_cnt, sqg, sqb,
                                   l1W, l1b, l2W, l2b, out);
}